// Round 11
// baseline (2810.360 us; speedup 1.0000x reference)
//
#include <hip/hip_runtime.h>
#include <math.h>

#define ACT_NONE 0
#define ACT_RELU 1
#define ACT_LEAKY 2

#define EPI_F32 0
#define EPI_PAIR_RELU 1
#define EPI_F32_BIAS 2

typedef __attribute__((ext_vector_type(8))) short short8;
typedef __attribute__((ext_vector_type(8))) __bf16 bf16x8;
typedef __attribute__((ext_vector_type(4))) float f32x4;
typedef __attribute__((ext_vector_type(4))) unsigned uint4v;

__device__ __forceinline__ float actf(float y, int act) {
    if (act == ACT_RELU)  return y > 0.f ? y : 0.f;
    if (act == ACT_LEAKY) return y >= 0.f ? y : 0.2f * y;
    return y;
}

// ---- bf16 split helpers ----
__device__ __forceinline__ unsigned f2bf_rne(float f) {
    unsigned u = __float_as_uint(f);
    return (u + 0x7FFFu + ((u >> 16) & 1u)) >> 16;
}
__device__ __forceinline__ float bf2f(unsigned h) { return __uint_as_float(h << 16); }
__device__ __forceinline__ unsigned splitpack(float f) {
    unsigned hi = f2bf_rne(f);
    float r = f - bf2f(hi);
    unsigned lo = f2bf_rne(r);
    return (hi & 0xFFFFu) | (lo << 16);
}

__device__ __forceinline__ f32x4 mfma16(short8 a, short8 b, f32x4 c) {
    return __builtin_amdgcn_mfma_f32_16x16x32_bf16(
        __builtin_bit_cast(bf16x8, a), __builtin_bit_cast(bf16x8, b), c, 0, 0, 0);
}

// blocked-plane address (u16 units): [img][c/32][HW pix][c%32]
__device__ __forceinline__ size_t paddr(int img, int KBc, size_t HW, size_t pix) {
    return ((size_t)img * KBc * HW + pix) * 32;
}

// ---------------------------------------------------------------------------
// Mask convolution
// ---------------------------------------------------------------------------
template<int K, int S, bool MHALF>
__global__ void maskconv_kernel(const float* __restrict__ M, int HM, int WM,
                                float* __restrict__ mc, float* __restrict__ nm,
                                int N, int Hin, int Win, int Hout, int Wout) {
    constexpr int P = (K - 1) / 2;
    int idx = blockIdx.x * blockDim.x + threadIdx.x;
    int total = N * Hout * Wout;
    if (idx >= total) return;
    int wo = idx % Wout;
    int t  = idx / Wout;
    int ho = t % Hout;
    int n  = t / Hout;
    float s = 0.f;
    for (int kh = 0; kh < K; ++kh) {
        int ih = ho * S - P + kh;
        if ((unsigned)ih >= (unsigned)Hin) continue;
        const float* mrow = M + ((size_t)n * HM + (MHALF ? (ih >> 1) : ih)) * WM;
        for (int kw = 0; kw < K; ++kw) {
            int iw = wo * S - P + kw;
            if ((unsigned)iw < (unsigned)Win)
                s += mrow[MHALF ? (iw >> 1) : iw];
        }
    }
    mc[idx] = s;
    nm[idx] = (s == 0.f) ? 0.f : 1.f;
}

// ---------------------------------------------------------------------------
// Weight transform (A-fragment layout bf16 hi/lo)
// ---------------------------------------------------------------------------
__global__ void wtransform(const float* __restrict__ W, short* __restrict__ Whi,
                           short* __restrict__ Wlo, int Cout, int Cin, int Ksz,
                           size_t total) {
    size_t idx = (size_t)blockIdx.x * blockDim.x + threadIdx.x;
    if (idx >= total) return;
    int j = (int)(idx & 7);
    int lane = (int)((idx >> 3) & 63);
    size_t r = idx >> 9;
    int COB = Cout >> 4, KB = Cin >> 5;
    int cob = (int)(r % COB); r /= COB;
    int kb = (int)(r % KB);
    int tap = (int)(r / KB);
    int co = cob * 16 + (lane & 15);
    int ci = kb * 32 + (lane >> 4) * 8 + j;
    float f = W[((size_t)co * Cin + ci) * Ksz + tap];
    unsigned hi = f2bf_rne(f);
    float rr = f - bf2f(hi);
    unsigned lo = f2bf_rne(rr);
    Whi[idx] = (short)hi;
    Wlo[idx] = (short)lo;
}

// ---------------------------------------------------------------------------
// f32 NCHW -> blocked hi/lo planes (LDS-tiled transpose, both sides coalesced)
// grid: (cdiv(HW,64), C/32, N), 256 threads
// ---------------------------------------------------------------------------
__global__ __launch_bounds__(256) void split_planes(
    const float* __restrict__ x, short* __restrict__ hi, short* __restrict__ lo,
    int C, int HW) {
    __shared__ float tile[32][65];
    const int img = blockIdx.z, kb = blockIdx.y;
    const int px0 = blockIdx.x * 64;
    const int tid = threadIdx.x;
    const int KBc = C >> 5;
    for (int i = tid; i < 32 * 64; i += 256) {
        const int ch = i >> 6, px = i & 63;
        float v = 0.f;
        if (px0 + px < HW)
            v = x[((size_t)img * C + kb * 32 + ch) * HW + px0 + px];
        tile[ch][px] = v;
    }
    __syncthreads();
    const int px = tid >> 2, sg = tid & 3;
    if (px0 + px < HW) {
        short8 h8, l8;
#pragma unroll
        for (int j = 0; j < 8; ++j) {
            float v = tile[sg * 8 + j][px];
            unsigned h16 = f2bf_rne(v);
            float rr = v - bf2f(h16);
            h8[j] = (short)h16;
            l8[j] = (short)f2bf_rne(rr);
        }
        const size_t a = (((size_t)img * KBc + kb) * HW + px0 + px) * 32 + sg * 8;
        *(short8*)&hi[a] = h8;
        *(short8*)&lo[a] = l8;
    }
}

// ---------------------------------------------------------------------------
// enc1 special: 7x7 s2 p3, Cin=128 -> Cout=256, 144^2 -> 72^2.
//   Big tile TH=8 x TW=16 (BN=128, NFW=4) to halve A-L1 traffic per FLOP.
//   MFW=2 (BM=128, y-grid 2). Dynamic LDS 102,656 B (1 block/CU).
//   Parity halo layout; direct stage (stage << 49-tap compute).
// ---------------------------------------------------------------------------
#define E1_HH 21
#define E1_HWC 37
#define E1_PXC 777
#define E1_PW 19
#define E1_PXC2P 802               // 21*19*2=798 padded so %8==2
#define E1_PLANE (4 * E1_PXC2P * 8)  // shorts per plane = 25664
#define E1_LDS_BYTES (2 * E1_PLANE * 2)  // 102,656

__global__ __launch_bounds__(512) void conv_enc1(
    const short* __restrict__ Ahi, const short* __restrict__ Alo,
    const float* __restrict__ M,
    const short* __restrict__ Whi, const short* __restrict__ Wlo,
    const float* __restrict__ mc,
    short* __restrict__ outHi, short* __restrict__ outLo)
{
    extern __shared__ short smem[];
    short* BHs = smem;
    short* BLs = smem + E1_PLANE;

    constexpr int Cin = 128, Cout = 256, Hin = 144, Win = 144, Hout = 72, Wout = 72;
    constexpr int KB = 4, COB = 16, NFW = 4;
    const int t = threadIdx.x;
    const int lane = t & 63;
    const int wv = t >> 6;
    const int wm = wv >> 1;   // 0..3 : 32-co slice (2 frags)
    const int wn = wv & 1;    // 0..1 : 64-px half
    const int img = blockIdx.z;
    const int coB = blockIdx.y * 128;
    const int tile = blockIdx.x;           // 45 tiles, TX=5
    const int ty = tile / 5, tx = tile - ty * 5;
    const int oy0 = ty * 8, ox0 = tx * 16;
    const size_t HW = (size_t)Hin * Win;
    const int g = lane >> 4, pl = lane & 15;

    // staging descriptors: thread handles halo px q = t and t+512
    bool sel[2]; size_t basep[2]; int qq[2];
#pragma unroll
    for (int i = 0; i < 2; ++i) {
        sel[i] = false; basep[i] = 0; qq[i] = 0;
        const int q = t + i * 512;
        if (q < E1_PXC) {
            const int r = q / E1_HWC, c = q - r * E1_HWC;
            qq[i] = r * E1_PW + (c >> 1) + (c & 1) * (E1_HH * E1_PW);
            const int iy = oy0 * 2 - 3 + r;
            const int ix = ox0 * 2 - 3 + c;
            if ((unsigned)iy < (unsigned)Hin && (unsigned)ix < (unsigned)Win) {
                const size_t pix = (size_t)iy * Win + ix;
                if (M[(size_t)img * HW + pix] != 0.f) {
                    sel[i] = true;
                    basep[i] = paddr(img, KB, HW, pix);
                }
            }
        }
    }

    f32x4 acc[2][NFW] = {};

#pragma unroll 1
    for (int kb = 0; kb < KB; ++kb) {
        // ---- direct stage ----
#pragma unroll
        for (int i = 0; i < 2; ++i) {
            const int q = t + i * 512;
            if (q < E1_PXC) {
#pragma unroll
                for (int gg = 0; gg < 4; ++gg) {
                    short8 h8, l8;
                    if (sel[i]) {
                        const size_t a = basep[i] + (size_t)kb * HW * 32 + gg * 8;
                        h8 = *(const short8*)(Ahi + a);
                        l8 = *(const short8*)(Alo + a);
                    } else {
#pragma unroll
                        for (int j = 0; j < 8; ++j) { h8[j] = 0; l8[j] = 0; }
                    }
                    *(short8*)&BHs[((size_t)gg * E1_PXC2P + qq[i]) * 8] = h8;
                    *(short8*)&BLs[((size_t)gg * E1_PXC2P + qq[i]) * 8] = l8;
                }
            }
        }
        __syncthreads();

        // ---- 49 taps from LDS ----
#pragma unroll 1
        for (int kh = 0; kh < 7; ++kh)
#pragma unroll 1
        for (int kw = 0; kw < 7; ++kw) {
            const int tap = kh * 7 + kw;
            const size_t wb = (((size_t)tap * KB + kb) * COB + (coB >> 4) + wm * 2) * 512
                            + (size_t)lane * 8;
            short8 ah0 = *(const short8*)(Whi + wb);
            short8 ah1 = *(const short8*)(Whi + wb + 512);
            short8 al0 = *(const short8*)(Wlo + wb);
            short8 al1 = *(const short8*)(Wlo + wb + 512);
#pragma unroll
            for (int fn = 0; fn < NFW; ++fn) {
                const int pxf = (wn * NFW + fn) * 16 + pl;
                const int oy = pxf >> 4, ox = pxf & 15;
                const int q2 = (oy * 2 + kh) * E1_PW + ox + (kw >> 1)
                             + (kw & 1) * (E1_HH * E1_PW);
                short8 bh = *(const short8*)&BHs[((size_t)g * E1_PXC2P + q2) * 8];
                short8 bl = *(const short8*)&BLs[((size_t)g * E1_PXC2P + q2) * 8];
                acc[0][fn] = mfma16(ah0, bh, acc[0][fn]);
                acc[1][fn] = mfma16(ah1, bh, acc[1][fn]);
                acc[0][fn] = mfma16(al0, bh, acc[0][fn]);
                acc[1][fn] = mfma16(al1, bh, acc[1][fn]);
                acc[0][fn] = mfma16(ah0, bl, acc[0][fn]);
                acc[1][fn] = mfma16(ah1, bl, acc[1][fn]);
            }
        }
        __syncthreads();
    }

    // ---- epilogue: renorm + relu -> blocked planes ----
    constexpr int Npix = Hout * Wout;
    const float* mcb = mc + (size_t)img * Npix;
#pragma unroll
    for (int fm = 0; fm < 2; ++fm)
#pragma unroll
    for (int fn = 0; fn < NFW; ++fn) {
        const int co = coB + (wm * 2 + fm) * 16 + (lane >> 4) * 4;
        const int pxf = (wn * NFW + fn) * 16 + (lane & 15);
        const int oy = pxf >> 4, ox = pxf & 15;
        const int gy = oy0 + oy, gx = ox0 + ox;
        if (gy >= Hout || gx >= Wout) continue;
        const size_t pix = (size_t)gy * Wout + gx;
        const float m = mcb[pix];
        f32x4 a = acc[fm][fn];
#pragma unroll
        for (int r = 0; r < 4; ++r) {
            float y = (m == 0.f) ? 0.f : a[r] / m;
            y = y > 0.f ? y : 0.f;
            const size_t pa = paddr(img, Cout >> 5, Npix, pix)
                            + (size_t)((co + r) >> 5) * Npix * 32 + ((co + r) & 31);
            unsigned h16 = f2bf_rne(y);
            float rr = y - bf2f(h16);
            outHi[pa] = (short)h16;
            outLo[pa] = (short)f2bf_rne(rr);
        }
    }
}

// ---------------------------------------------------------------------------
// Encoder halo-staged stride-2 conv (enc2/3/4). A-source: blocked planes.
// ---------------------------------------------------------------------------
template<int K, int S, int TH, int TW, int NFW, bool AF32, int EPI>
__global__ __launch_bounds__(512) void conv_enc(
    const void* __restrict__ Ahi, const void* __restrict__ Alo,
    int Cin, int Hin, int Win,
    const float* __restrict__ M,
    const short* __restrict__ Whi, const short* __restrict__ Wlo,
    const float* __restrict__ mc, const float* __restrict__ bias,
    void* __restrict__ outp, void* __restrict__ outp2,
    int Hout, int Wout, int Cout, int TX)
{
    static_assert(S == 2, "parity layout assumes stride 2");
    constexpr int P = (K - 1) / 2;
    constexpr int HH  = (TH - 1) * S + K;
    constexpr int HWC = (TW - 1) * S + K;
    constexpr int PXC = HH * HWC;
    static_assert(PXC <= 512, "one halo pixel per thread");
    constexpr int PW  = (HWC + 1) / 2;
    constexpr int PXC2 = HH * PW * 2;
    constexpr int PXC2P = PXC2 + ((2 - (PXC2 % 8) + 8) % 8);
    __shared__ __align__(16) short BHs[4 * PXC2P * 8];
    __shared__ __align__(16) short BLs[4 * PXC2P * 8];

    const int t    = threadIdx.x;
    const int lane = t & 63;
    const int wv   = t >> 6;
    const int wm   = wv >> 1;
    const int wn   = wv & 1;
    const int img  = blockIdx.z;
    const int coB  = blockIdx.y * 256;
    const int tile = blockIdx.x;
    const int ty   = tile / TX, tx = tile - ty * TX;
    const int oy0  = ty * TH, ox0 = tx * TW;
    const int KB   = Cin >> 5;
    const int COB  = Cout >> 4;
    const size_t HW = (size_t)Hin * Win;
    const int g  = lane >> 4;
    const int pl = lane & 15;

    bool sel = false;
    size_t basef = 0, basep = 0;
    int qq = 0;
    if (t < PXC) {
        const int r = t / HWC, c = t - r * HWC;
        qq = r * PW + (c >> 1) + (c & 1) * (HH * PW);
        const int iy = oy0 * S - P + r;
        const int ix = ox0 * S - P + c;
        if ((unsigned)iy < (unsigned)Hin && (unsigned)ix < (unsigned)Win) {
            const size_t pix = (size_t)iy * Win + ix;
            if (M[(size_t)img * HW + pix] != 0.f) {
                sel = true;
                basef = (size_t)img * Cin * HW + pix;
                basep = paddr(img, KB, HW, pix);
            }
        }
    }

    short8 hv[4], lv[4];
    auto prefetch = [&](int kb) {
#pragma unroll
        for (int gg = 0; gg < 4; ++gg) {
            if (sel) {
                if (AF32) {
                    const float* s = (const float*)Ahi + basef + (size_t)(kb * 32 + gg * 8) * HW;
#pragma unroll
                    for (int j = 0; j < 8; ++j) {
                        float f = s[(size_t)j * HW];
                        unsigned h16 = f2bf_rne(f);
                        float rr = f - bf2f(h16);
                        hv[gg][j] = (short)h16;
                        lv[gg][j] = (short)f2bf_rne(rr);
                    }
                } else {
                    const size_t a = basep + (size_t)kb * HW * 32 + gg * 8;
                    hv[gg] = *(const short8*)((const short*)Ahi + a);
                    lv[gg] = *(const short8*)((const short*)Alo + a);
                }
            } else {
#pragma unroll
                for (int j = 0; j < 8; ++j) { hv[gg][j] = 0; lv[gg][j] = 0; }
            }
        }
    };

    f32x4 acc[4][NFW] = {};
    if (t < PXC) prefetch(0);

#pragma unroll 1
    for (int kb = 0; kb < KB; ++kb) {
        if (t < PXC) {
#pragma unroll
            for (int gg = 0; gg < 4; ++gg) {
                *(short8*)&BHs[(gg * PXC2P + qq) * 8] = hv[gg];
                *(short8*)&BLs[(gg * PXC2P + qq) * 8] = lv[gg];
            }
        }
        __syncthreads();
        if (t < PXC && kb + 1 < KB) prefetch(kb + 1);

#pragma unroll 1
        for (int kh = 0; kh < K; ++kh)
#pragma unroll 1
        for (int kw = 0; kw < K; ++kw) {
            const int tap = kh * K + kw;
            const size_t wb = (((size_t)tap * KB + kb) * COB + (coB >> 4) + wm * 4) * 512
                            + (size_t)lane * 8;
            short8 ah[4], al[4];
#pragma unroll
            for (int fm = 0; fm < 4; ++fm) {
                ah[fm] = *(const short8*)(Whi + wb + (size_t)fm * 512);
                al[fm] = *(const short8*)(Wlo + wb + (size_t)fm * 512);
            }
#pragma unroll
            for (int fn = 0; fn < NFW; ++fn) {
                const int pxf = (wn * NFW + fn) * 16 + pl;
                const int oy = pxf / TW, ox = pxf - oy * TW;
                const int q2 = (oy * S + kh) * PW + ox + (kw >> 1) + (kw & 1) * (HH * PW);
                short8 bh = *(const short8*)&BHs[(g * PXC2P + q2) * 8];
                short8 bl = *(const short8*)&BLs[(g * PXC2P + q2) * 8];
#pragma unroll
                for (int fm = 0; fm < 4; ++fm) {
                    acc[fm][fn] = mfma16(ah[fm], bh, acc[fm][fn]);
                    acc[fm][fn] = mfma16(al[fm], bh, acc[fm][fn]);
                    acc[fm][fn] = mfma16(ah[fm], bl, acc[fm][fn]);
                }
            }
        }
        __syncthreads();
    }

    const int Npix = Hout * Wout;
    const float* mcb = mc + (size_t)img * Npix;
#pragma unroll
    for (int fm = 0; fm < 4; ++fm)
#pragma unroll
    for (int fn = 0; fn < NFW; ++fn) {
        const int co = coB + (wm * 4 + fm) * 16 + (lane >> 4) * 4;
        const int pxf = (wn * NFW + fn) * 16 + (lane & 15);
        const int oy = pxf / TW, ox = pxf - oy * TW;
        const int gy = oy0 + oy, gx = ox0 + ox;
        if (gy >= Hout || gx >= Wout) continue;
        const size_t pix = (size_t)gy * Wout + gx;
        const float m = mcb[pix];
        f32x4 a = acc[fm][fn];
#pragma unroll
        for (int r = 0; r < 4; ++r) {
            float y = a[r];
            if (EPI == EPI_F32_BIAS) {
                const float bv = bias[co + r];
                y = (m == 0.f) ? 0.f : (y - bv) / m + bv;
            } else {
                y = (m == 0.f) ? 0.f : y / m;
            }
            if (EPI == EPI_PAIR_RELU) {
                y = y > 0.f ? y : 0.f;
                const size_t pa = paddr(img, Cout >> 5, Npix, pix)
                                + (size_t)(co >> 5) * Npix * 32 + (co & 31) + r;
                unsigned h16 = f2bf_rne(y);
                float rr = y - bf2f(h16);
                ((short*)outp)[pa]  = (short)h16;
                ((short*)outp2)[pa] = (short)f2bf_rne(rr);
            } else {
                ((float*)outp)[((size_t)img * Cout + co + r) * Npix + pix] = y;
            }
        }
    }
}

// ---------------------------------------------------------------------------
// Decoder 3x3 s1 p1: 8 waves, MFW=2 (4m x 2n), NPIX=32*NFW, blocked-plane IO.
// ---------------------------------------------------------------------------
template<int TH, int TW, int NFW, bool BF32, int EPI>
__global__ __launch_bounds__(512) void conv3x3(
    const void* __restrict__ Ahi, const void* __restrict__ Alo,
    int CA, int HA, int WA,
    const void* __restrict__ Bhi, const void* __restrict__ Blo, int CB,
    const float* __restrict__ M,
    const short* __restrict__ Whi, const short* __restrict__ Wlo,
    const float* __restrict__ mc, const float* __restrict__ bias,
    void* __restrict__ outp,
    int Hout, int Wout, int Cout, int TX)
{
    constexpr int HALO_H = TH + 2, HALO_W = TW + 2, HALO = HALO_H * HALO_W;
    constexpr int HALOP = HALO + ((2 - (HALO % 8) + 8) % 8);
    constexpr int NPIX = TH * TW;
    constexpr int SITER = (HALO + 127) / 128;
    static_assert(NPIX == 32 * NFW, "tile must be exactly 32*NFW pixels");
    __shared__ __align__(16) short BHs[4 * HALOP * 8];
    __shared__ __align__(16) short BLs[4 * HALOP * 8];

    const int t    = threadIdx.x;
    const int lane = t & 63;
    const int wv   = t >> 6;
    const int wm   = wv >> 1;
    const int wn   = wv & 1;
    const int img  = blockIdx.z;
    const int coB  = blockIdx.y * 128;
    const int tile = blockIdx.x;
    const int ty   = tile / TX;
    const int tx   = tile - ty * TX;
    const int oy0  = ty * TH, ox0 = tx * TW;
    const int Cin  = CA + CB;
    const int KB   = Cin >> 5;
    const int KBA  = CA >> 5;
    const int KBB  = CB >> 5;
    const int COB  = Cout >> 4;
    const int WM   = Wout >> 1;
    const size_t HWA = (size_t)HA * WA;
    const size_t HWB = (size_t)Hout * Wout;

    const int sg = t >> 7;
    const int st = t & 127;
    const int g  = lane >> 4;
    const int pl = lane & 15;

    bool ssel[SITER];
    size_t aoff[SITER], boff[SITER];
#pragma unroll
    for (int i = 0; i < SITER; ++i) {
        ssel[i] = false; aoff[i] = 0; boff[i] = 0;
        const int q = st + i * 128;
        if (q < HALO) {
            const int hy = q / HALO_W, hx = q - hy * HALO_W;
            const int iy = oy0 - 1 + hy, ix = ox0 - 1 + hx;
            if ((unsigned)iy < (unsigned)Hout && (unsigned)ix < (unsigned)Wout) {
                if (M[((size_t)img * (Hout >> 1) + (iy >> 1)) * WM + (ix >> 1)] != 0.f) {
                    ssel[i] = true;
                    const size_t pixA = (size_t)(iy >> 1) * WA + (ix >> 1);
                    const size_t pixB = (size_t)iy * Wout + ix;
                    aoff[i] = paddr(img, KBA, HWA, pixA) + sg * 8;
                    if (BF32) boff[i] = (size_t)img * CB * HWB + pixB;
                    else      boff[i] = paddr(img, KBB, HWB, pixB) + sg * 8;
                }
            }
        }
    }

    short8 hv[SITER], lv[SITER];
    auto prefetch = [&](int kb) {
        const int c = kb * 32 + sg * 8;
#pragma unroll
        for (int i = 0; i < SITER; ++i) {
            const int q = st + i * 128;
            bool ok = (q < HALO) && ssel[i];
            if (ok) {
                if (c < CA) {
                    const size_t a = aoff[i] + (size_t)kb * HWA * 32;
                    hv[i] = *(const short8*)((const short*)Ahi + a);
                    lv[i] = *(const short8*)((const short*)Alo + a);
                } else {
                    if (BF32) {
                        const float* s = (const float*)Bhi + boff[i] + (size_t)(c - CA) * HWB;
#pragma unroll
                        for (int j = 0; j < 8; ++j) {
                            float f = s[(size_t)j * HWB];
                            unsigned h16 = f2bf_rne(f);
                            float rr = f - bf2f(h16);
                            hv[i][j] = (short)h16;
                            lv[i][j] = (short)f2bf_rne(rr);
                        }
                    } else {
                        const size_t a = boff[i] + (size_t)(kb - KBA) * HWB * 32;
                        hv[i] = *(const short8*)((const short*)Bhi + a);
                        lv[i] = *(const short8*)((const short*)Blo + a);
                    }
                }
            } else {
#pragma unroll
                for (int j = 0; j < 8; ++j) { hv[i][j] = 0; lv[i][j] = 0; }
            }
        }
    };

    f32x4 acc[2][NFW] = {};
    const size_t wstride = (size_t)KB * COB * 512;
    prefetch(0);

#pragma unroll 1
    for (int kb = 0; kb < KB; ++kb) {
#pragma unroll
        for (int i = 0; i < SITER; ++i) {
            const int q = st + i * 128;
            if (q < HALO) {
                *(short8*)&BHs[(sg * HALOP + q) * 8] = hv[i];
                *(short8*)&BLs[(sg * HALOP + q) * 8] = lv[i];
            }
        }
        __syncthreads();
        if (kb + 1 < KB) prefetch(kb + 1);

        size_t wb = ((size_t)kb * COB + (coB >> 4) + wm * 2) * 512 + lane * 8;
#pragma unroll 1
        for (int tap = 0; tap < 9; ++tap) {
            const int dh = tap / 3, dw = tap - dh * 3;
            short8 ah0 = *(const short8*)(Whi + wb);
            short8 ah1 = *(const short8*)(Whi + wb + 512);
            short8 al0 = *(const short8*)(Wlo + wb);
            short8 al1 = *(const short8*)(Wlo + wb + 512);
#pragma unroll
            for (int fn = 0; fn < NFW; ++fn) {
                const int pxf = (wn * NFW + fn) * 16 + pl;
                const int oy = pxf / TW, ox = pxf - oy * TW;
                const int hpx = (oy + dh) * HALO_W + (ox + dw);
                short8 bh = *(const short8*)&BHs[(g * HALOP + hpx) * 8];
                short8 bl = *(const short8*)&BLs[(g * HALOP + hpx) * 8];
                acc[0][fn] = mfma16(ah0, bh, acc[0][fn]);
                acc[1][fn] = mfma16(ah1, bh, acc[1][fn]);
                acc[0][fn] = mfma16(al0, bh, acc[0][fn]);
                acc[1][fn] = mfma16(al1, bh, acc[1][fn]);
                acc[0][fn] = mfma16(ah0, bl, acc[0][fn]);
                acc[1][fn] = mfma16(ah1, bl, acc[1][fn]);
            }
            wb += wstride;
        }
        __syncthreads();
    }

    const float* mcb = mc + (size_t)img * HWB;
#pragma unroll
    for (int fm = 0; fm < 2; ++fm)
#pragma unroll
    for (int fn = 0; fn < NFW; ++fn) {
        const int co = coB + (wm * 2 + fm) * 16 + (lane >> 4) * 4;
        const int pxf = (wn * NFW + fn) * 16 + (lane & 15);
        const int oy = pxf / TW, ox = pxf - oy * TW;
        const int gy = oy0 + oy, gx = ox0 + ox;
        if (gy >= Hout || gx >= Wout) continue;
        const float m = mcb[(size_t)gy * Wout + gx];
        f32x4 a = acc[fm][fn];
#pragma unroll
        for (int r = 0; r < 4; ++r) {
            float y = a[r];
            if (EPI == EPI_F32_BIAS) {
                const float bv = bias[co + r];
                y = (m == 0.f) ? 0.f : (y - bv) / m + bv;
            } else {
                y = (m == 0.f) ? 0.f : y / m;
            }
            ((float*)outp)[((size_t)img * Cout + co + r) * HWB + (size_t)gy * Wout + gx] = y;
        }
    }
}

// ---------------------------------------------------------------------------
// BatchNorm stats
// ---------------------------------------------------------------------------
__global__ __launch_bounds__(256) void bn_stats_kernel(const float* __restrict__ y,
                                                       int N, int C, int HW,
                                                       float* __restrict__ mean,
                                                       float* __restrict__ istd) {
    const int c = blockIdx.x;
    double s = 0.0, s2 = 0.0;
    const int tot = N * HW;
    for (int i = threadIdx.x; i < tot; i += blockDim.x) {
        int n = i / HW, hw = i - n * HW;
        float v = y[((size_t)n * C + c) * HW + hw];
        s += v;
        s2 += (double)v * v;
    }
    __shared__ double sh[256], sh2[256];
    sh[threadIdx.x] = s; sh2[threadIdx.x] = s2;
    __syncthreads();
    for (int o = 128; o > 0; o >>= 1) {
        if (threadIdx.x < o) { sh[threadIdx.x] += sh[threadIdx.x + o]; sh2[threadIdx.x] += sh2[threadIdx.x + o]; }
        __syncthreads();
    }
    if (threadIdx.x == 0) {
        double mu = sh[0] / tot;
        double var = sh2[0] / tot - mu * mu;
        mean[c] = (float)mu;
        istd[c] = (float)(1.0 / sqrt(var + 1e-5));
    }
}

// ---------------------------------------------------------------------------
// BN apply + act -> blocked hi/lo planes
// ---------------------------------------------------------------------------
__global__ __launch_bounds__(256) void bn_apply_blk(
    const float* __restrict__ y,
    const float* __restrict__ mean, const float* __restrict__ istd,
    const float* __restrict__ g, const float* __restrict__ b,
    short* __restrict__ hi, short* __restrict__ lo, float* __restrict__ fout,
    int C, int HW, int act) {
    __shared__ float tile[32][65];
    const int img = blockIdx.z, kb = blockIdx.y;
    const int px0 = blockIdx.x * 64;
    const int tid = threadIdx.x;
    const int KBc = C >> 5;

    for (int i = tid; i < 32 * 64; i += 256) {
        const int ch = i >> 6, px = i & 63;
        float v = 0.f;
        if (px0 + px < HW)
            v = y[((size_t)img * C + kb * 32 + ch) * HW + px0 + px];
        tile[ch][px] = v;
    }
    __syncthreads();

    const int px = tid >> 2, sg = tid & 3;
    if (px0 + px < HW) {
        short8 h8, l8;
        float f8[8];
#pragma unroll
        for (int j = 0; j < 8; ++j) {
            const int c = kb * 32 + sg * 8 + j;
            float v = tile[sg * 8 + j][px];
            v = (v - mean[c]) * istd[c] * g[c] + b[c];
            v = actf(v, act);
            f8[j] = v;
            unsigned h16 = f2bf_rne(v);
            float rr = v - bf2f(h16);
            h8[j] = (short)h16;
            l8[j] = (short)f2bf_rne(rr);
        }
        const size_t a = (((size_t)img * KBc + kb) * HW + px0 + px) * 32 + sg * 8;
        *(short8*)&hi[a] = h8;
        *(short8*)&lo[a] = l8;
        if (fout) {
#pragma unroll
            for (int j = 0; j < 8; ++j)
                fout[((size_t)img * C + kb * 32 + sg * 8 + j) * HW + px0 + px] = f8[j];
        }
    }
}

// ---------------------------------------------------------------------------
// NLM (MFMA formulation)
// ---------------------------------------------------------------------------
#define NLM_C 512
#define NLM_N 1296
#define NLM_MAXM 256
#define NLM_RT 16
#define NLM_KB1 16
#define NLM_KB2 41
#define NLM_PFRAG (NLM_KB1 * NLM_RT * 512)
#define NLM_WFRAG (NLM_KB2 * NLM_RT * 512)

__global__ __launch_bounds__(256) void nlm_trans(const float* __restrict__ h2f,
                                                 unsigned* __restrict__ xTp) {
    __shared__ float tile[32][33];
    const int b = blockIdx.z;
    const int j0 = blockIdx.x * 32, c0 = blockIdx.y * 32;
    const int tx = threadIdx.x & 31, ty = threadIdx.x >> 5;
    for (int cc = ty; cc < 32; cc += 8) {
        const int j = j0 + tx;
        tile[cc][tx] = (j < NLM_N) ? h2f[((size_t)b * NLM_C + c0 + cc) * NLM_N + j] : 0.f;
    }
    __syncthreads();
    for (int jj = ty; jj < 32; jj += 8) {
        const int j = j0 + jj;
        if (j < NLM_N)
            xTp[((size_t)b * NLM_N + j) * NLM_C + c0 + tx] = splitpack(tile[tx][jj]);
    }
}

__global__ void nlm_sq2(const float* __restrict__ h2f, float* __restrict__ sq) {
    const int b = blockIdx.y;
    const int j = blockIdx.x * 256 + threadIdx.x;
    if (j >= NLM_N) return;
    const float* p = h2f + (size_t)b * NLM_C * NLM_N + j;
    float s0 = 0.f, s1 = 0.f, s2 = 0.f, s3 = 0.f;
    for (int c = 0; c < NLM_C; c += 4) {
        float v0 = p[(size_t)c * NLM_N];
        float v1 = p[(size_t)(c + 1) * NLM_N];
        float v2 = p[(size_t)(c + 2) * NLM_N];
        float v3 = p[(size_t)(c + 3) * NLM_N];
        s0 = fmaf(v0, v0, s0); s1 = fmaf(v1, v1, s1);
        s2 = fmaf(v2, v2, s2); s3 = fmaf(v3, v3, s3);
    }
    sq[b * NLM_N + j] = (s0 + s1) + (s2 + s3);
}

__global__ void nlm_compact(const float* __restrict__ nm2, int* __restrict__ list,
                            int* __restrict__ cnt) {
    const int b = blockIdx.x;
    for (int j = threadIdx.x; j < NLM_N; j += 256) {
        if (nm2[(size_t)b * NLM_N + j] == 0.f) {
            int pos = atomicAdd(&cnt[b], 1);
            if (pos < NLM_MAXM) list[b * NLM_MAXM + pos] = j;
        }
    }
}

__global__ void nlm_gather(const unsigned* __restrict__ xTp, const int* __restrict__ list,
                           const int* __restrict__ cnt,
                           short* __restrict__ Phi, short* __restrict__ Plo) {
    const int b = blockIdx.y;
    const int id = blockIdx.x * 256 + threadIdx.x;
    const int i  = id >> 6;
    const int rem = id & 63;
    const int kb = rem >> 2, kg = rem & 3;
    const int lane = kg * 16 + (i & 15), rt = i >> 4;
    const size_t f = (size_t)b * NLM_PFRAG + ((size_t)(kb * NLM_RT + rt) * 64 + lane) * 8;
    if (i < cnt[b]) {
        const int pix = list[b * NLM_MAXM + i];
        const unsigned* s = xTp + ((size_t)b * NLM_N + pix) * NLM_C + kb * 32 + kg * 8;
#pragma unroll
        for (int jj = 0; jj < 8; ++jj) {
            unsigned v = s[jj];
            Phi[f + jj] = (short)(v & 0xFFFFu);
            Plo[f + jj] = (short)(v >> 16);
        }
    } else {
#pragma unroll
        for (int jj = 0; jj < 8; ++jj) { Phi[f + jj] = 0; Plo[f + jj] = 0; }
    }
}

__global__ __launch_bounds__(512) void nlm_gemm1(
    const unsigned* __restrict__ xTp, const short* __restrict__ Phi,
    const short* __restrict__ Plo, const int* __restrict__ cnt,
    float* __restrict__ S) {
    const int img = blockIdx.z, mt = blockIdx.y, nt = blockIdx.x;
    if (mt * 128 >= cnt[img]) return;
    __shared__ __align__(16) unsigned BH[4 * 128 * 4];
    __shared__ __align__(16) unsigned BL[4 * 128 * 4];
    const int t = threadIdx.x, lane = t & 63, wv = t >> 6, wm = wv >> 1, wn = wv & 1;
    const int j0 = nt * 128;
    const int spx = t & 127, sg = t >> 7;
    f32x4 acc[2][4] = {};
#pragma unroll 1
    for (int kb = 0; kb < NLM_KB1; ++kb) {
        unsigned v[8];
#pragma unroll
        for (int jj = 0; jj < 8; ++jj) v[jj] = 0u;
        const int j = j0 + spx;
        if (j < NLM_N) {
            const unsigned* s = xTp + ((size_t)img * NLM_N + j) * NLM_C + kb * 32 + sg * 8;
#pragma unroll
            for (int jj = 0; jj < 8; ++jj) v[jj] = s[jj];
        }
        uint4v hd, ld;
#pragma unroll
        for (int jj = 0; jj < 4; ++jj) {
            hd[jj] = (v[2 * jj] & 0xFFFFu) | (v[2 * jj + 1] << 16);
            ld[jj] = (v[2 * jj] >> 16) | (v[2 * jj + 1] & 0xFFFF0000u);
        }
        *(uint4v*)&BH[(sg * 128 + spx) * 4] = hd;
        *(uint4v*)&BL[(sg * 128 + spx) * 4] = ld;
        __syncthreads();
        const size_t ab = (size_t)img * NLM_PFRAG
                        + (size_t)(kb * NLM_RT + mt * 8 + wm * 2) * 512 + (size_t)lane * 8;
        short8 ah0 = *(const short8*)(Phi + ab);
        short8 ah1 = *(const short8*)(Phi + ab + 512);
        short8 al0 = *(const short8*)(Plo + ab);
        short8 al1 = *(const short8*)(Plo + ab + 512);
        const int g = lane >> 4, pl = lane & 15;
#pragma unroll
        for (int fn = 0; fn < 4; ++fn) {
            const int px = wn * 64 + fn * 16 + pl;
            short8 bh = *(const short8*)&BH[(g * 128 + px) * 4];
            short8 bl = *(const short8*)&BL[(g * 128 + px) * 4];
            acc[0][fn] = mfma16(ah0, bh, acc[0][fn]);
            acc[1][fn] = mfma16(ah1, bh, acc[1][fn]);
            acc[0][fn] = mfma16(al0, bh, acc[0][fn]);
            acc[1][fn] = mfma16(al1, bh, acc[1][fn]);
            acc[0][fn] = mfma16(ah0, bl, acc[0][fn]);
            acc[1][fn] = mfma16(ah1, bl, acc[1][fn]);
        }
        __syncthreads();
    }
#pragma unroll
    for (int fm = 0; fm < 2; ++fm)
#pragma unroll
    for (int fn = 0; fn < 4; ++fn) {
        const int row = mt * 128 + (wm * 2 + fm) * 16 + (lane >> 4) * 4;
        const int j = j0 + wn * 64 + fn * 16 + (lane & 15);
        if (j >= NLM_N) continue;
        f32x4 a = acc[fm][fn];
#pragma unroll
        for (int r = 0; r < 4; ++r)
            S[((size_t)img * NLM_MAXM + row + r) * NLM_N + j] = a[r];
    }
}

__global__ __launch_bounds__(256) void nlm_row(
    const float* __restrict__ S, const float* __restrict__ sq,
    const float* __restrict__ nm2, const int* __restrict__ list,
    const int* __restrict__ cnt,
    short* __restrict__ W2hi, short* __restrict__ W2lo,
    float* __restrict__ sumw, float inv_h2) {
    const int img = blockIdx.y, i = blockIdx.x;
    if (i >= cnt[img] || i >= NLM_MAXM) return;
    __shared__ float Drow[NLM_N];
    __shared__ float red[256];
    const int tid = threadIdx.x;
    const int pix = list[img * NLM_MAXM + i];
    const float sqi = sq[img * NLM_N + pix];
    const float BIG = 3.4e38f;
    float lmin = BIG;
    for (int j = tid; j < NLM_N; j += 256) {
        float d = BIG;
        if (nm2[(size_t)img * NLM_N + j] != 0.f) {
            float dot = S[((size_t)img * NLM_MAXM + i) * NLM_N + j];
            d = sqi + sq[img * NLM_N + j] - 2.f * dot;
            d = d > 0.f ? d : 0.f;
            lmin = d < lmin ? d : lmin;
        }
        Drow[j] = d;
    }
    red[tid] = lmin;
    __syncthreads();
    for (int o = 128; o > 0; o >>= 1) {
        if (tid < o) red[tid] = fminf(red[tid], red[tid + o]);
        __syncthreads();
    }
    const float dmin = red[0];
    __syncthreads();

    const int rt = i >> 4, lr = i & 15;
    float lsum = 0.f;
    for (int j = tid; j < NLM_KB2 * 32; j += 256) {
        float w = 0.f;
        if (j < NLM_N && Drow[j] < 3.3e38f) {
            w = expf(-(Drow[j] - dmin) * inv_h2);
            lsum += w;
        }
        const unsigned u = splitpack(w);
        const int kb = j >> 5, kg = (j & 31) >> 3, jj = j & 7;
        const int lane = kg * 16 + lr;
        const size_t f = (size_t)img * NLM_WFRAG
                       + ((size_t)(kb * NLM_RT + rt) * 64 + lane) * 8 + jj;
        W2hi[f] = (short)(u & 0xFFFFu);
        W2lo[f] = (short)(u >> 16);
    }
    red[tid] = lsum;
    __syncthreads();
    for (int o = 128; o > 0; o >>= 1) {
        if (tid < o) red[tid] += red[tid + o];
        __syncthreads();
    }
    if (tid == 0) sumw[img * NLM_MAXM + i] = red[0];
}

__global__ __launch_bounds__(512) void nlm_gemm2(
    const unsigned* __restrict__ xTp, const short* __restrict__ W2hi,
    const short* __restrict__ W2lo, const int* __restrict__ cnt,
    const float* __restrict__ sumw, const int* __restrict__ list,
    short* __restrict__ outHi, short* __restrict__ outLo) {
    const int img = blockIdx.z, mt = blockIdx.y, ct = blockIdx.x;
    const int cN = cnt[img] < NLM_MAXM ? cnt[img] : NLM_MAXM;
    if (mt * 128 >= cN) return;
    __shared__ __align__(16) unsigned BH[4 * 128 * 4];
    __shared__ __align__(16) unsigned BL[4 * 128 * 4];
    const int t = threadIdx.x, lane = t & 63, wv = t >> 6, wm = wv >> 1, wn = wv & 1;
    const int c0 = ct * 128;
    const int sc = t & 127, sg = t >> 7;
    f32x4 acc[2][4] = {};
#pragma unroll 1
    for (int kb = 0; kb < NLM_KB2; ++kb) {
        unsigned v[8];
#pragma unroll
        for (int jj = 0; jj < 8; ++jj) {
            const int j = kb * 32 + sg * 8 + jj;
            v[jj] = (j < NLM_N)
                  ? xTp[((size_t)img * NLM_N + j) * NLM_C + c0 + sc] : 0u;
        }
        uint4v hd, ld;
#pragma unroll
        for (int jj = 0; jj < 4; ++jj) {
            hd[jj] = (v[2 * jj] & 0xFFFFu) | (v[2 * jj + 1] << 16);
            ld[jj] = (v[2 * jj] >> 16) | (v[2 * jj + 1] & 0xFFFF0000u);
        }
        *(uint4v*)&BH[(sg * 128 + sc) * 4] = hd;
        *(uint4v*)&BL[(sg * 128 + sc) * 4] = ld;
        __syncthreads();
        const size_t ab = (size_t)img * NLM_WFRAG
                        + (size_t)(kb * NLM_RT + mt * 8 + wm * 2) * 512 + (size_t)lane * 8;
        short8 ah0 = *(const short8*)(W2hi + ab);
        short8 ah1 = *(const short8*)(W2hi + ab + 512);
        short8 al0 = *(const short8*)(W2lo + ab);
        short8 al1 = *(const short8*)(W2lo + ab + 512);
        const int g = lane >> 4, pl = lane & 15;
#pragma unroll
        for (int fn = 0; fn < 4; ++fn) {
            const int px = wn * 64 + fn * 16 + pl;
            short8 bh = *(const short8*)&BH[(g * 128 + px) * 4];
            short8 bl = *(const short8*)&BL[(g * 128 + px) * 4];
            acc[0][fn] = mfma16(ah0, bh, acc[0][fn]);
            acc[1][fn] = mfma16(ah1, bh, acc[1][fn]);
            acc[0][fn] = mfma16(al0, bh, acc[0][fn]);
            acc[1][fn] = mfma16(al1, bh, acc[1][fn]);
            acc[0][fn] = mfma16(ah0, bl, acc[0][fn]);
            acc[1][fn] = mfma16(ah1, bl, acc[1][fn]);
        }
        __syncthreads();
    }
#pragma unroll
    for (int fm = 0; fm < 2; ++fm)
#pragma unroll
    for (int fn = 0; fn < 4; ++fn) {
        const int row = mt * 128 + (wm * 2 + fm) * 16 + (lane >> 4) * 4;
        const int c = c0 + wn * 64 + fn * 16 + (lane & 15);
        f32x4 a = acc[fm][fn];
#pragma unroll
        for (int r = 0; r < 4; ++r) {
            const int ri = row + r;
            if (ri < cN) {
                const float y = a[r] / sumw[img * NLM_MAXM + ri];
                const int pix = list[img * NLM_MAXM + ri];
                const size_t pa = (((size_t)img * (NLM_C >> 5) + (c >> 5)) * NLM_N + pix) * 32
                                + (c & 31);
                unsigned h16 = f2bf_rne(y);
                float rr = y - bf2f(h16);
                outHi[pa] = (short)h16;
                outLo[pa] = (short)f2bf_rne(rr);
            }
        }
    }
}

// ---------------------------------------------------------------------------
// Driver
// ---------------------------------------------------------------------------
extern "C" void kernel_launch(void* const* d_in, const int* in_sizes, int n_in,
                              void* d_out, int out_size, void* d_ws, size_t ws_size,
                              hipStream_t stream) {
    const float* x0    = (const float*)d_in[0];
    const float* m0    = (const float*)d_in[1];
    const float* Wsrc[8] = {
        (const float*)d_in[2], (const float*)d_in[3], (const float*)d_in[4],
        (const float*)d_in[5], (const float*)d_in[6], (const float*)d_in[7],
        (const float*)d_in[8], (const float*)d_in[9]
    };
    const float* dec1b = (const float*)d_in[10];
    const float* enc2g = (const float*)d_in[11];
    const float* enc2b = (const float*)d_in[12];
    const float* enc3g = (const float*)d_in[13];
    const float* enc3b = (const float*)d_in[14];
    const float* enc4g = (const float*)d_in[15];
    const float* enc4b = (const float*)d_in[16];
    const float* dec4g = (const float*)d_in[17];
    const float* dec4b = (const float*)d_in[18];
    const float* dec3g = (const float*)d_in[19];
    const float* dec3b = (const float*)d_in[20];
    const float* dec2g = (const float*)d_in[21];
    const float* dec2b = (const float*)d_in[22];
    float* outp = (float*)d_out;

    const int N = 8;
    float* ws = (float*)d_ws;
    size_t off = 0;
    auto alloc = [&](size_t nf) {
        size_t o = off;
        off += ((nf + 63) / 64) * 64;
        return ws + o;
    };
    auto allocPair = [&](size_t E, short** hi, short** lo) {
        float* p = alloc(E);
        *hi = (short*)p;
        *lo = (short*)p + E;
    };

    short *h1hi, *h1lo, *h2shi, *h2slo, *h3hi, *h3lo, *h4hi, *h4lo, *d4hi, *d4lo;
    allocPair(10616832, &h1hi, &h1lo);   // 8x256x72x72  (later d2 planes)
    allocPair(5308416, &h2shi, &h2slo);  // 8x512x36x36  (later d3 planes)
    allocPair(1327104, &h3hi, &h3lo);    // 8x512x18x18
    allocPair(331776, &h4hi, &h4lo);     // 8x512x9x9
    allocPair(1327104, &d4hi, &d4lo);
    float* ybuf = alloc(10616832);
    float* h2f  = alloc(5308416);
    unsigned* xTp = (unsigned*)alloc(5308416);
    float* sqb  = alloc(10368);
    float* mc   = alloc(165888);
    float* nm1  = alloc(41472);
    float* nm2  = alloc(10368);
    float* nm3  = alloc(2592);
    float* nm4  = alloc(648);
    float* nmd4 = alloc(2592);
    float* nmd3 = alloc(10368);
    float* nmd2 = alloc(41472);
    float* nmx  = alloc(165888);
    float* bmean = alloc(512);
    float* bistd = alloc(512);
    short* Whi = (short*)alloc(10625024);
    short* Wlo = (short*)alloc(10625024);
    float* Smat = alloc((size_t)8 * NLM_MAXM * NLM_N);
    float* Phi_  = alloc((size_t)8 * NLM_PFRAG / 2);
    float* Plo_  = alloc((size_t)8 * NLM_PFRAG / 2);
    float* W2hi_ = alloc((size_t)8 * NLM_WFRAG / 2);
    float* W2lo_ = alloc((size_t)8 * NLM_WFRAG / 2);
    short* Phi = (short*)Phi_;  short* Plo = (short*)Plo_;
    short* W2hi = (short*)W2hi_; short* W2lo = (short*)W2lo_;
    int*   mlist = (int*)alloc(8 * NLM_MAXM);
    int*   mcnt  = (int*)alloc(64);
    float* sumw  = alloc(8 * NLM_MAXM);
    short* d3hi = h2shi; short* d3lo = h2slo;
    short* d2hi = h1hi;  short* d2lo = h1lo;

    if (ws_size < off * sizeof(float)) return;

    auto cdiv = [](size_t a, size_t b) { return (int)((a + b - 1) / b); };

    // ---- weight transforms ----
    struct WLay { int Cout, Cin, K; size_t ofs; };
    const WLay WL[8] = {
        {256, 128, 7, 0},         // enc1
        {512, 256, 5, 1605632},   // enc2
        {512, 512, 3, 4882432},   // enc3
        {512, 512, 3, 7241728},   // enc4
        {512, 1024, 3, 9601024},  // dec4
        {512, 1024, 3, 14319616}, // dec3
        {256, 768, 3, 19038208},  // dec2
        {128, 384, 3, 20807680},  // dec1
    };
    for (int i = 0; i < 8; ++i) {
        size_t tot = (size_t)WL[i].Cout * WL[i].Cin * WL[i].K * WL[i].K;
        wtransform<<<cdiv(tot, 256), 256, 0, stream>>>(
            Wsrc[i], Whi + WL[i].ofs, Wlo + WL[i].ofs, WL[i].Cout, WL[i].Cin,
            WL[i].K * WL[i].K, tot);
    }

    // ---- x0 planes live in d_out (free scratch until dec1 overwrites it) ----
    short* x0hi = (short*)d_out;
    short* x0lo = x0hi + 21233664;
    split_planes<<<dim3(324, 4, N), 256, 0, stream>>>(x0, x0hi, x0lo, 128, 20736);

    // ---------------- enc1: x0 planes -> h1 planes, relu (big-tile, dyn LDS) ----------------
    maskconv_kernel<7, 2, false><<<cdiv(N * 72 * 72, 256), 256, 0, stream>>>(
        m0, 144, 144, mc, nm1, N, 144, 144, 72, 72);
    (void)hipFuncSetAttribute((const void*)conv_enc1,
                              hipFuncAttributeMaxDynamicSharedMemorySize, E1_LDS_BYTES);
    conv_enc1<<<dim3(45, 2, N), 512, E1_LDS_BYTES, stream>>>(
        x0hi, x0lo, m0, Whi + WL[0].ofs, Wlo + WL[0].ofs, mc, h1hi, h1lo);

    // ---------------- enc2 ----------------
    maskconv_kernel<5, 2, false><<<cdiv(N * 36 * 36, 256), 256, 0, stream>>>(
        nm1, 72, 72, mc, nm2, N, 72, 72, 36, 36);
    conv_enc<5, 2, 8, 8, 2, false, EPI_F32><<<dim3(25, 2, N), 512, 0, stream>>>(
        h1hi, h1lo, 256, 72, 72, nm1,
        Whi + WL[1].ofs, Wlo + WL[1].ofs, mc, nullptr, ybuf, nullptr,
        36, 36, 512, 5);
    bn_stats_kernel<<<512, 256, 0, stream>>>(ybuf, N, 512, 1296, bmean, bistd);
    bn_apply_blk<<<dim3(cdiv(1296, 64), 16, N), 256, 0, stream>>>(
        ybuf, bmean, bistd, enc2g, enc2b, h2shi, h2slo, h2f, 512, 1296, ACT_RELU);

    // ---------------- NLM swap ----------------
    nlm_trans<<<dim3(41, 16, N), 256, 0, stream>>>(h2f, xTp);
    nlm_sq2<<<dim3(6, N), 256, 0, stream>>>(h2f, sqb);
    hipMemsetAsync(mcnt, 0, 8 * sizeof(int), stream);
    nlm_compact<<<N, 256, 0, stream>>>(nm2, mlist, mcnt);
    nlm_gather<<<dim3(64, N), 256, 0, stream>>>(xTp, mlist, mcnt, Phi, Plo);
    nlm_gemm1<<<dim3(11, 2, N), 512, 0, stream>>>(xTp, Phi, Plo, mcnt, Smat);
    nlm_row<<<dim3(NLM_MAXM, N), 256, 0, stream>>>(Smat, sqb, nm2, mlist, mcnt,
                                                   W2hi, W2lo, sumw, 1.f / 25.f);
    nlm_gemm2<<<dim3(4, 2, N), 512, 0, stream>>>(xTp, W2hi, W2lo, mcnt, sumw,
                                                 mlist, h2shi, h2slo);

    // ---------------- enc3 ----------------
    maskconv_kernel<3, 2, false><<<cdiv(N * 18 * 18, 256), 256, 0, stream>>>(
        nm2, 36, 36, mc, nm3, N, 36, 36, 18, 18);
    conv_enc<3, 2, 4, 8, 1, false, EPI_F32><<<dim3(15, 2, N), 512, 0, stream>>>(
        h2shi, h2slo, 512, 36, 36, nm2,
        Whi + WL[2].ofs, Wlo + WL[2].ofs, mc, nullptr, ybuf, nullptr,
        18, 18, 512, 3);
    bn_stats_kernel<<<512, 256, 0, stream>>>(ybuf, N, 512, 324, bmean, bistd);
    bn_apply_blk<<<dim3(cdiv(324, 64), 16, N), 256, 0, stream>>>(
        ybuf, bmean, bistd, enc3g, enc3b, h3hi, h3lo, nullptr, 512, 324, ACT_RELU);

    // ---------------- enc4 ----------------
    maskconv_kernel<3, 2, false><<<cdiv(N * 9 * 9, 256), 256, 0, stream>>>(
        nm3, 18, 18, mc, nm4, N, 18, 18, 9, 9);
    conv_enc<3, 2, 4, 8, 1, false, EPI_F32><<<dim3(6, 2, N), 512, 0, stream>>>(
        h3hi, h3lo, 512, 18, 18, nm3,
        Whi + WL[3].ofs, Wlo + WL[3].ofs, mc, nullptr, ybuf, nullptr,
        9, 9, 512, 2);
    bn_stats_kernel<<<512, 256, 0, stream>>>(ybuf, N, 512, 81, bmean, bistd);
    bn_apply_blk<<<dim3(cdiv(81, 64), 16, N), 256, 0, stream>>>(
        ybuf, bmean, bistd, enc4g, enc4b, h4hi, h4lo, nullptr, 512, 81, ACT_RELU);

    // ---------------- dec4 ----------------
    maskconv_kernel<3, 1, true><<<cdiv(N * 18 * 18, 256), 256, 0, stream>>>(
        nm4, 9, 9, mc, nmd4, N, 18, 18, 18, 18);
    conv3x3<8, 8, 2, false, EPI_F32><<<dim3(9, 4, N), 512, 0, stream>>>(
        h4hi, h4lo, 512, 9, 9, h3hi, h3lo, 512, nm4,
        Whi + WL[4].ofs, Wlo + WL[4].ofs, mc, nullptr, ybuf,
        18, 18, 512, 3);
    bn_stats_kernel<<<512, 256, 0, stream>>>(ybuf, N, 512, 324, bmean, bistd);
    bn_apply_blk<<<dim3(cdiv(324, 64), 16, N), 256, 0, stream>>>(
        ybuf, bmean, bistd, dec4g, dec4b, d4hi, d4lo, nullptr, 512, 324, ACT_LEAKY);

    // ---------------- dec3 ----------------
    maskconv_kernel<3, 1, true><<<cdiv(N * 36 * 36, 256), 256, 0, stream>>>(
        nmd4, 18, 18, mc, nmd3, N, 36, 36, 36, 36);
    conv3x3<8, 12, 3, false, EPI_F32><<<dim3(15, 4, N), 512, 0, stream>>>(
        d4hi, d4lo, 512, 18, 18, h2shi, h2slo, 512, nmd4,
        Whi + WL[5].ofs, Wlo + WL[5].ofs, mc, nullptr, ybuf,
        36, 36, 512, 3);
    bn_stats_kernel<<<512, 256, 0, stream>>>(ybuf, N, 512, 1296, bmean, bistd);
    bn_apply_blk<<<dim3(cdiv(1296, 64), 16, N), 256, 0, stream>>>(
        ybuf, bmean, bistd, dec3g, dec3b, d3hi, d3lo, nullptr, 512, 1296, ACT_LEAKY);

    // ---------------- dec2 ----------------
    maskconv_kernel<3, 1, true><<<cdiv(N * 72 * 72, 256), 256, 0, stream>>>(
        nmd3, 36, 36, mc, nmd2, N, 72, 72, 72, 72);
    conv3x3<8, 16, 4, false, EPI_F32><<<dim3(45, 2, N), 512, 0, stream>>>(
        d3hi, d3lo, 512, 36, 36, h1hi, h1lo, 256, nmd3,
        Whi + WL[6].ofs, Wlo + WL[6].ofs, mc, nullptr, ybuf,
        72, 72, 256, 5);
    bn_stats_kernel<<<256, 256, 0, stream>>>(ybuf, N, 256, 5184, bmean, bistd);
    bn_apply_blk<<<dim3(cdiv(5184, 64), 8, N), 256, 0, stream>>>(
        ybuf, bmean, bistd, dec2g, dec2b, d2hi, d2lo, nullptr, 256, 5184, ACT_LEAKY);

    // ---------------- dec1: cat[up2(d2), x0] -> d_out (x0 planes now dead) ----------------
    maskconv_kernel<3, 1, true><<<cdiv(N * 144 * 144, 256), 256, 0, stream>>>(
        nmd2, 72, 72, mc, nmx, N, 144, 144, 144, 144);
    conv3x3<8, 16, 4, true, EPI_F32_BIAS><<<dim3(162, 1, N), 512, 0, stream>>>(
        d2hi, d2lo, 256, 72, 72, x0, nullptr, 128, nmd2,
        Whi + WL[7].ofs, Wlo + WL[7].ofs, mc, dec1b, outp,
        144, 144, 128, 9);
}

// Round 12
// 2764.619 us; speedup vs baseline: 1.0165x; 1.0165x over previous
//
#include <hip/hip_runtime.h>
#include <math.h>

#define ACT_NONE 0
#define ACT_RELU 1
#define ACT_LEAKY 2

#define EPI_F32 0
#define EPI_PAIR_RELU 1
#define EPI_F32_BIAS 2

typedef __attribute__((ext_vector_type(8))) short short8;
typedef __attribute__((ext_vector_type(8))) __bf16 bf16x8;
typedef __attribute__((ext_vector_type(4))) float f32x4;
typedef __attribute__((ext_vector_type(4))) unsigned uint4v;

__device__ __forceinline__ float actf(float y, int act) {
    if (act == ACT_RELU)  return y > 0.f ? y : 0.f;
    if (act == ACT_LEAKY) return y >= 0.f ? y : 0.2f * y;
    return y;
}

// ---- bf16 split helpers ----
__device__ __forceinline__ unsigned f2bf_rne(float f) {
    unsigned u = __float_as_uint(f);
    return (u + 0x7FFFu + ((u >> 16) & 1u)) >> 16;
}
__device__ __forceinline__ float bf2f(unsigned h) { return __uint_as_float(h << 16); }
__device__ __forceinline__ unsigned splitpack(float f) {
    unsigned hi = f2bf_rne(f);
    float r = f - bf2f(hi);
    unsigned lo = f2bf_rne(r);
    return (hi & 0xFFFFu) | (lo << 16);
}

__device__ __forceinline__ f32x4 mfma16(short8 a, short8 b, f32x4 c) {
    return __builtin_amdgcn_mfma_f32_16x16x32_bf16(
        __builtin_bit_cast(bf16x8, a), __builtin_bit_cast(bf16x8, b), c, 0, 0, 0);
}

// blocked-plane address (u16 units): [img][c/32][HW pix][c%32]
__device__ __forceinline__ size_t paddr(int img, int KBc, size_t HW, size_t pix) {
    return ((size_t)img * KBc * HW + pix) * 32;
}

// ---------------------------------------------------------------------------
// Mask convolution
// ---------------------------------------------------------------------------
template<int K, int S, bool MHALF>
__global__ void maskconv_kernel(const float* __restrict__ M, int HM, int WM,
                                float* __restrict__ mc, float* __restrict__ nm,
                                int N, int Hin, int Win, int Hout, int Wout) {
    constexpr int P = (K - 1) / 2;
    int idx = blockIdx.x * blockDim.x + threadIdx.x;
    int total = N * Hout * Wout;
    if (idx >= total) return;
    int wo = idx % Wout;
    int t  = idx / Wout;
    int ho = t % Hout;
    int n  = t / Hout;
    float s = 0.f;
    for (int kh = 0; kh < K; ++kh) {
        int ih = ho * S - P + kh;
        if ((unsigned)ih >= (unsigned)Hin) continue;
        const float* mrow = M + ((size_t)n * HM + (MHALF ? (ih >> 1) : ih)) * WM;
        for (int kw = 0; kw < K; ++kw) {
            int iw = wo * S - P + kw;
            if ((unsigned)iw < (unsigned)Win)
                s += mrow[MHALF ? (iw >> 1) : iw];
        }
    }
    mc[idx] = s;
    nm[idx] = (s == 0.f) ? 0.f : 1.f;
}

// ---------------------------------------------------------------------------
// Weight transform (A-fragment layout bf16 hi/lo)
// ---------------------------------------------------------------------------
__global__ void wtransform(const float* __restrict__ W, short* __restrict__ Whi,
                           short* __restrict__ Wlo, int Cout, int Cin, int Ksz,
                           size_t total) {
    size_t idx = (size_t)blockIdx.x * blockDim.x + threadIdx.x;
    if (idx >= total) return;
    int j = (int)(idx & 7);
    int lane = (int)((idx >> 3) & 63);
    size_t r = idx >> 9;
    int COB = Cout >> 4, KB = Cin >> 5;
    int cob = (int)(r % COB); r /= COB;
    int kb = (int)(r % KB);
    int tap = (int)(r / KB);
    int co = cob * 16 + (lane & 15);
    int ci = kb * 32 + (lane >> 4) * 8 + j;
    float f = W[((size_t)co * Cin + ci) * Ksz + tap];
    unsigned hi = f2bf_rne(f);
    float rr = f - bf2f(hi);
    unsigned lo = f2bf_rne(rr);
    Whi[idx] = (short)hi;
    Wlo[idx] = (short)lo;
}

// ---------------------------------------------------------------------------
// f32 NCHW -> blocked hi/lo planes (LDS-tiled transpose, both sides coalesced)
// grid: (cdiv(HW,64), C/32, N), 256 threads
// ---------------------------------------------------------------------------
__global__ __launch_bounds__(256) void split_planes(
    const float* __restrict__ x, short* __restrict__ hi, short* __restrict__ lo,
    int C, int HW) {
    __shared__ float tile[32][65];
    const int img = blockIdx.z, kb = blockIdx.y;
    const int px0 = blockIdx.x * 64;
    const int tid = threadIdx.x;
    const int KBc = C >> 5;
    for (int i = tid; i < 32 * 64; i += 256) {
        const int ch = i >> 6, px = i & 63;
        float v = 0.f;
        if (px0 + px < HW)
            v = x[((size_t)img * C + kb * 32 + ch) * HW + px0 + px];
        tile[ch][px] = v;
    }
    __syncthreads();
    const int px = tid >> 2, sg = tid & 3;
    if (px0 + px < HW) {
        short8 h8, l8;
#pragma unroll
        for (int j = 0; j < 8; ++j) {
            float v = tile[sg * 8 + j][px];
            unsigned h16 = f2bf_rne(v);
            float rr = v - bf2f(h16);
            h8[j] = (short)h16;
            l8[j] = (short)f2bf_rne(rr);
        }
        const size_t a = (((size_t)img * KBc + kb) * HW + px0 + px) * 32 + sg * 8;
        *(short8*)&hi[a] = h8;
        *(short8*)&lo[a] = l8;
    }
}

// ---------------------------------------------------------------------------
// Encoder halo-staged stride-2 conv. A-source: blocked planes (or f32 if AF32).
// ---------------------------------------------------------------------------
template<int K, int S, int TH, int TW, int NFW, bool AF32, int EPI>
__global__ __launch_bounds__(512) void conv_enc(
    const void* __restrict__ Ahi, const void* __restrict__ Alo,
    int Cin, int Hin, int Win,
    const float* __restrict__ M,
    const short* __restrict__ Whi, const short* __restrict__ Wlo,
    const float* __restrict__ mc, const float* __restrict__ bias,
    void* __restrict__ outp, void* __restrict__ outp2,
    int Hout, int Wout, int Cout, int TX)
{
    static_assert(S == 2, "parity layout assumes stride 2");
    constexpr int P = (K - 1) / 2;
    constexpr int HH  = (TH - 1) * S + K;
    constexpr int HWC = (TW - 1) * S + K;
    constexpr int PXC = HH * HWC;
    static_assert(PXC <= 512, "one halo pixel per thread");
    constexpr int PW  = (HWC + 1) / 2;
    constexpr int PXC2 = HH * PW * 2;
    constexpr int PXC2P = PXC2 + ((2 - (PXC2 % 8) + 8) % 8);   // bank-phase pad
    __shared__ __align__(16) short BHs[4 * PXC2P * 8];
    __shared__ __align__(16) short BLs[4 * PXC2P * 8];

    const int t    = threadIdx.x;
    const int lane = t & 63;
    const int wv   = t >> 6;
    const int wm   = wv >> 1;
    const int wn   = wv & 1;
    const int img  = blockIdx.z;
    const int coB  = blockIdx.y * 256;
    const int tile = blockIdx.x;
    const int ty   = tile / TX, tx = tile - ty * TX;
    const int oy0  = ty * TH, ox0 = tx * TW;
    const int KB   = Cin >> 5;
    const int COB  = Cout >> 4;
    const size_t HW = (size_t)Hin * Win;
    const int g  = lane >> 4;
    const int pl = lane & 15;

    // staging descriptor (once)
    bool sel = false;
    size_t basef = 0, basep = 0;
    int qq = 0;
    if (t < PXC) {
        const int r = t / HWC, c = t - r * HWC;
        qq = r * PW + (c >> 1) + (c & 1) * (HH * PW);
        const int iy = oy0 * S - P + r;
        const int ix = ox0 * S - P + c;
        if ((unsigned)iy < (unsigned)Hin && (unsigned)ix < (unsigned)Win) {
            const size_t pix = (size_t)iy * Win + ix;
            if (M[(size_t)img * HW + pix] != 0.f) {
                sel = true;
                basef = (size_t)img * Cin * HW + pix;
                basep = paddr(img, KB, HW, pix);
            }
        }
    }

    short8 hv[4], lv[4];
    auto prefetch = [&](int kb) {
#pragma unroll
        for (int gg = 0; gg < 4; ++gg) {
            if (sel) {
                if (AF32) {
                    const float* s = (const float*)Ahi + basef + (size_t)(kb * 32 + gg * 8) * HW;
#pragma unroll
                    for (int j = 0; j < 8; ++j) {
                        float f = s[(size_t)j * HW];
                        unsigned h16 = f2bf_rne(f);
                        float rr = f - bf2f(h16);
                        hv[gg][j] = (short)h16;
                        lv[gg][j] = (short)f2bf_rne(rr);
                    }
                } else {
                    const size_t a = basep + (size_t)kb * HW * 32 + gg * 8;
                    hv[gg] = *(const short8*)((const short*)Ahi + a);
                    lv[gg] = *(const short8*)((const short*)Alo + a);
                }
            } else {
#pragma unroll
                for (int j = 0; j < 8; ++j) { hv[gg][j] = 0; lv[gg][j] = 0; }
            }
        }
    };

    f32x4 acc[4][NFW] = {};
    if (t < PXC) prefetch(0);

#pragma unroll 1
    for (int kb = 0; kb < KB; ++kb) {
        if (t < PXC) {
#pragma unroll
            for (int gg = 0; gg < 4; ++gg) {
                *(short8*)&BHs[(gg * PXC2P + qq) * 8] = hv[gg];
                *(short8*)&BLs[(gg * PXC2P + qq) * 8] = lv[gg];
            }
        }
        __syncthreads();
        if (t < PXC && kb + 1 < KB) prefetch(kb + 1);

#pragma unroll 1
        for (int kh = 0; kh < K; ++kh)
#pragma unroll 1
        for (int kw = 0; kw < K; ++kw) {
            const int tap = kh * K + kw;
            const size_t wb = (((size_t)tap * KB + kb) * COB + (coB >> 4) + wm * 4) * 512
                            + (size_t)lane * 8;
            short8 ah[4], al[4];
#pragma unroll
            for (int fm = 0; fm < 4; ++fm) {
                ah[fm] = *(const short8*)(Whi + wb + (size_t)fm * 512);
                al[fm] = *(const short8*)(Wlo + wb + (size_t)fm * 512);
            }
            __builtin_amdgcn_s_setprio(1);
#pragma unroll
            for (int fn = 0; fn < NFW; ++fn) {
                const int pxf = (wn * NFW + fn) * 16 + pl;
                const int oy = pxf / TW, ox = pxf - oy * TW;
                const int q2 = (oy * S + kh) * PW + ox + (kw >> 1) + (kw & 1) * (HH * PW);
                short8 bh = *(const short8*)&BHs[(g * PXC2P + q2) * 8];
                short8 bl = *(const short8*)&BLs[(g * PXC2P + q2) * 8];
#pragma unroll
                for (int fm = 0; fm < 4; ++fm) {
                    acc[fm][fn] = mfma16(ah[fm], bh, acc[fm][fn]);
                    acc[fm][fn] = mfma16(al[fm], bh, acc[fm][fn]);
                    acc[fm][fn] = mfma16(ah[fm], bl, acc[fm][fn]);
                }
            }
            __builtin_amdgcn_s_setprio(0);
        }
        __syncthreads();
    }

    const int Npix = Hout * Wout;
    const float* mcb = mc + (size_t)img * Npix;
#pragma unroll
    for (int fm = 0; fm < 4; ++fm)
#pragma unroll
    for (int fn = 0; fn < NFW; ++fn) {
        const int co = coB + (wm * 4 + fm) * 16 + (lane >> 4) * 4;
        const int pxf = (wn * NFW + fn) * 16 + (lane & 15);
        const int oy = pxf / TW, ox = pxf - oy * TW;
        const int gy = oy0 + oy, gx = ox0 + ox;
        if (gy >= Hout || gx >= Wout) continue;
        const size_t pix = (size_t)gy * Wout + gx;
        const float m = mcb[pix];
        f32x4 a = acc[fm][fn];
#pragma unroll
        for (int r = 0; r < 4; ++r) {
            float y = a[r];
            if (EPI == EPI_F32_BIAS) {
                const float bv = bias[co + r];
                y = (m == 0.f) ? 0.f : (y - bv) / m + bv;
            } else {
                y = (m == 0.f) ? 0.f : y / m;
            }
            if (EPI == EPI_PAIR_RELU) {
                y = y > 0.f ? y : 0.f;
                const size_t pa = paddr(img, Cout >> 5, Npix, pix)
                                + (size_t)(co >> 5) * Npix * 32 + (co & 31) + r;
                unsigned h16 = f2bf_rne(y);
                float rr = y - bf2f(h16);
                ((short*)outp)[pa]  = (short)h16;
                ((short*)outp2)[pa] = (short)f2bf_rne(rr);
            } else {
                ((float*)outp)[((size_t)img * Cout + co + r) * Npix + pix] = y;
            }
        }
    }
}

// ---------------------------------------------------------------------------
// Decoder 3x3 s1 p1: 8 waves, MFW=2 (4m x 2n), NPIX=32*NFW, blocked-plane IO.
// ---------------------------------------------------------------------------
template<int TH, int TW, int NFW, bool BF32, int EPI>
__global__ __launch_bounds__(512) void conv3x3(
    const void* __restrict__ Ahi, const void* __restrict__ Alo,
    int CA, int HA, int WA,
    const void* __restrict__ Bhi, const void* __restrict__ Blo, int CB,
    const float* __restrict__ M,
    const short* __restrict__ Whi, const short* __restrict__ Wlo,
    const float* __restrict__ mc, const float* __restrict__ bias,
    void* __restrict__ outp,
    int Hout, int Wout, int Cout, int TX)
{
    constexpr int HALO_H = TH + 2, HALO_W = TW + 2, HALO = HALO_H * HALO_W;
    constexpr int HALOP = HALO + ((2 - (HALO % 8) + 8) % 8);   // bank-phase pad
    constexpr int NPIX = TH * TW;
    constexpr int SITER = (HALO + 127) / 128;
    static_assert(NPIX == 32 * NFW, "tile must be exactly 32*NFW pixels");
    __shared__ __align__(16) short BHs[4 * HALOP * 8];
    __shared__ __align__(16) short BLs[4 * HALOP * 8];

    const int t    = threadIdx.x;
    const int lane = t & 63;
    const int wv   = t >> 6;
    const int wm   = wv >> 1;
    const int wn   = wv & 1;
    const int img  = blockIdx.z;
    const int coB  = blockIdx.y * 128;
    const int tile = blockIdx.x;
    const int ty   = tile / TX;
    const int tx   = tile - ty * TX;
    const int oy0  = ty * TH, ox0 = tx * TW;
    const int Cin  = CA + CB;
    const int KB   = Cin >> 5;
    const int KBA  = CA >> 5;
    const int KBB  = CB >> 5;
    const int COB  = Cout >> 4;
    const int WM   = Wout >> 1;
    const size_t HWA = (size_t)HA * WA;
    const size_t HWB = (size_t)Hout * Wout;

    const int sg = t >> 7;
    const int st = t & 127;
    const int g  = lane >> 4;
    const int pl = lane & 15;

    // staging descriptors (once)
    bool ssel[SITER];
    size_t aoff[SITER], boff[SITER];
#pragma unroll
    for (int i = 0; i < SITER; ++i) {
        ssel[i] = false; aoff[i] = 0; boff[i] = 0;
        const int q = st + i * 128;
        if (q < HALO) {
            const int hy = q / HALO_W, hx = q - hy * HALO_W;
            const int iy = oy0 - 1 + hy, ix = ox0 - 1 + hx;
            if ((unsigned)iy < (unsigned)Hout && (unsigned)ix < (unsigned)Wout) {
                if (M[((size_t)img * (Hout >> 1) + (iy >> 1)) * WM + (ix >> 1)] != 0.f) {
                    ssel[i] = true;
                    const size_t pixA = (size_t)(iy >> 1) * WA + (ix >> 1);
                    const size_t pixB = (size_t)iy * Wout + ix;
                    aoff[i] = paddr(img, KBA, HWA, pixA) + sg * 8;
                    if (BF32) boff[i] = (size_t)img * CB * HWB + pixB;     // f32 elem base
                    else      boff[i] = paddr(img, KBB, HWB, pixB) + sg * 8;
                }
            }
        }
    }

    short8 hv[SITER], lv[SITER];
    auto prefetch = [&](int kb) {
        const int c = kb * 32 + sg * 8;
#pragma unroll
        for (int i = 0; i < SITER; ++i) {
            const int q = st + i * 128;
            bool ok = (q < HALO) && ssel[i];
            if (ok) {
                if (c < CA) {
                    const size_t a = aoff[i] + (size_t)kb * HWA * 32;
                    hv[i] = *(const short8*)((const short*)Ahi + a);
                    lv[i] = *(const short8*)((const short*)Alo + a);
                } else {
                    if (BF32) {
                        const float* s = (const float*)Bhi + boff[i] + (size_t)(c - CA) * HWB;
#pragma unroll
                        for (int j = 0; j < 8; ++j) {
                            float f = s[(size_t)j * HWB];
                            unsigned h16 = f2bf_rne(f);
                            float rr = f - bf2f(h16);
                            hv[i][j] = (short)h16;
                            lv[i][j] = (short)f2bf_rne(rr);
                        }
                    } else {
                        const size_t a = boff[i] + (size_t)(kb - KBA) * HWB * 32;
                        hv[i] = *(const short8*)((const short*)Bhi + a);
                        lv[i] = *(const short8*)((const short*)Blo + a);
                    }
                }
            } else {
#pragma unroll
                for (int j = 0; j < 8; ++j) { hv[i][j] = 0; lv[i][j] = 0; }
            }
        }
    };

    f32x4 acc[2][NFW] = {};
    const size_t wstride = (size_t)KB * COB * 512;
    prefetch(0);

#pragma unroll 1
    for (int kb = 0; kb < KB; ++kb) {
#pragma unroll
        for (int i = 0; i < SITER; ++i) {
            const int q = st + i * 128;
            if (q < HALO) {
                *(short8*)&BHs[(sg * HALOP + q) * 8] = hv[i];
                *(short8*)&BLs[(sg * HALOP + q) * 8] = lv[i];
            }
        }
        __syncthreads();
        if (kb + 1 < KB) prefetch(kb + 1);

        size_t wb = ((size_t)kb * COB + (coB >> 4) + wm * 2) * 512 + lane * 8;
#pragma unroll 1
        for (int tap = 0; tap < 9; ++tap) {
            const int dh = tap / 3, dw = tap - dh * 3;
            short8 ah0 = *(const short8*)(Whi + wb);
            short8 ah1 = *(const short8*)(Whi + wb + 512);
            short8 al0 = *(const short8*)(Wlo + wb);
            short8 al1 = *(const short8*)(Wlo + wb + 512);
            __builtin_amdgcn_s_setprio(1);
#pragma unroll
            for (int fn = 0; fn < NFW; ++fn) {
                const int pxf = (wn * NFW + fn) * 16 + pl;
                const int oy = pxf / TW, ox = pxf - oy * TW;
                const int hpx = (oy + dh) * HALO_W + (ox + dw);
                short8 bh = *(const short8*)&BHs[(g * HALOP + hpx) * 8];
                short8 bl = *(const short8*)&BLs[(g * HALOP + hpx) * 8];
                acc[0][fn] = mfma16(ah0, bh, acc[0][fn]);
                acc[1][fn] = mfma16(ah1, bh, acc[1][fn]);
                acc[0][fn] = mfma16(al0, bh, acc[0][fn]);
                acc[1][fn] = mfma16(al1, bh, acc[1][fn]);
                acc[0][fn] = mfma16(ah0, bl, acc[0][fn]);
                acc[1][fn] = mfma16(ah1, bl, acc[1][fn]);
            }
            __builtin_amdgcn_s_setprio(0);
            wb += wstride;
        }
        __syncthreads();
    }

    const float* mcb = mc + (size_t)img * HWB;
#pragma unroll
    for (int fm = 0; fm < 2; ++fm)
#pragma unroll
    for (int fn = 0; fn < NFW; ++fn) {
        const int co = coB + (wm * 2 + fm) * 16 + (lane >> 4) * 4;
        const int pxf = (wn * NFW + fn) * 16 + (lane & 15);
        const int oy = pxf / TW, ox = pxf - oy * TW;
        const int gy = oy0 + oy, gx = ox0 + ox;
        if (gy >= Hout || gx >= Wout) continue;
        const float m = mcb[(size_t)gy * Wout + gx];
        f32x4 a = acc[fm][fn];
#pragma unroll
        for (int r = 0; r < 4; ++r) {
            float y = a[r];
            if (EPI == EPI_F32_BIAS) {
                const float bv = bias[co + r];
                y = (m == 0.f) ? 0.f : (y - bv) / m + bv;
            } else {
                y = (m == 0.f) ? 0.f : y / m;
            }
            ((float*)outp)[((size_t)img * Cout + co + r) * HWB + (size_t)gy * Wout + gx] = y;
        }
    }
}

// ---------------------------------------------------------------------------
// BatchNorm stats
// ---------------------------------------------------------------------------
__global__ __launch_bounds__(256) void bn_stats_kernel(const float* __restrict__ y,
                                                       int N, int C, int HW,
                                                       float* __restrict__ mean,
                                                       float* __restrict__ istd) {
    const int c = blockIdx.x;
    double s = 0.0, s2 = 0.0;
    const int tot = N * HW;
    for (int i = threadIdx.x; i < tot; i += blockDim.x) {
        int n = i / HW, hw = i - n * HW;
        float v = y[((size_t)n * C + c) * HW + hw];
        s += v;
        s2 += (double)v * v;
    }
    __shared__ double sh[256], sh2[256];
    sh[threadIdx.x] = s; sh2[threadIdx.x] = s2;
    __syncthreads();
    for (int o = 128; o > 0; o >>= 1) {
        if (threadIdx.x < o) { sh[threadIdx.x] += sh[threadIdx.x + o]; sh2[threadIdx.x] += sh2[threadIdx.x + o]; }
        __syncthreads();
    }
    if (threadIdx.x == 0) {
        double mu = sh[0] / tot;
        double var = sh2[0] / tot - mu * mu;
        mean[c] = (float)mu;
        istd[c] = (float)(1.0 / sqrt(var + 1e-5));
    }
}

// ---------------------------------------------------------------------------
// BN apply + act -> blocked hi/lo planes (LDS-tiled transpose)
// ---------------------------------------------------------------------------
__global__ __launch_bounds__(256) void bn_apply_blk(
    const float* __restrict__ y,
    const float* __restrict__ mean, const float* __restrict__ istd,
    const float* __restrict__ g, const float* __restrict__ b,
    short* __restrict__ hi, short* __restrict__ lo, float* __restrict__ fout,
    int C, int HW, int act) {
    __shared__ float tile[32][65];
    const int img = blockIdx.z, kb = blockIdx.y;
    const int px0 = blockIdx.x * 64;
    const int tid = threadIdx.x;
    const int KBc = C >> 5;

    for (int i = tid; i < 32 * 64; i += 256) {
        const int ch = i >> 6, px = i & 63;
        float v = 0.f;
        if (px0 + px < HW)
            v = y[((size_t)img * C + kb * 32 + ch) * HW + px0 + px];
        tile[ch][px] = v;
    }
    __syncthreads();

    const int px = tid >> 2, sg = tid & 3;
    if (px0 + px < HW) {
        short8 h8, l8;
        float f8[8];
#pragma unroll
        for (int j = 0; j < 8; ++j) {
            const int c = kb * 32 + sg * 8 + j;
            float v = tile[sg * 8 + j][px];
            v = (v - mean[c]) * istd[c] * g[c] + b[c];
            v = actf(v, act);
            f8[j] = v;
            unsigned h16 = f2bf_rne(v);
            float rr = v - bf2f(h16);
            h8[j] = (short)h16;
            l8[j] = (short)f2bf_rne(rr);
        }
        const size_t a = (((size_t)img * KBc + kb) * HW + px0 + px) * 32 + sg * 8;
        *(short8*)&hi[a] = h8;
        *(short8*)&lo[a] = l8;
        if (fout) {
#pragma unroll
            for (int j = 0; j < 8; ++j)
                fout[((size_t)img * C + kb * 32 + sg * 8 + j) * HW + px0 + px] = f8[j];
        }
    }
}

// ---------------------------------------------------------------------------
// NLM (MFMA formulation; xTp stays packed-u32; gemm2 writes blocked planes)
// ---------------------------------------------------------------------------
#define NLM_C 512
#define NLM_N 1296
#define NLM_MAXM 256
#define NLM_RT 16
#define NLM_KB1 16
#define NLM_KB2 41
#define NLM_PFRAG (NLM_KB1 * NLM_RT * 512)
#define NLM_WFRAG (NLM_KB2 * NLM_RT * 512)

__global__ __launch_bounds__(256) void nlm_trans(const float* __restrict__ h2f,
                                                 unsigned* __restrict__ xTp) {
    __shared__ float tile[32][33];
    const int b = blockIdx.z;
    const int j0 = blockIdx.x * 32, c0 = blockIdx.y * 32;
    const int tx = threadIdx.x & 31, ty = threadIdx.x >> 5;
    for (int cc = ty; cc < 32; cc += 8) {
        const int j = j0 + tx;
        tile[cc][tx] = (j < NLM_N) ? h2f[((size_t)b * NLM_C + c0 + cc) * NLM_N + j] : 0.f;
    }
    __syncthreads();
    for (int jj = ty; jj < 32; jj += 8) {
        const int j = j0 + jj;
        if (j < NLM_N)
            xTp[((size_t)b * NLM_N + j) * NLM_C + c0 + tx] = splitpack(tile[tx][jj]);
    }
}

__global__ void nlm_sq2(const float* __restrict__ h2f, float* __restrict__ sq) {
    const int b = blockIdx.y;
    const int j = blockIdx.x * 256 + threadIdx.x;
    if (j >= NLM_N) return;
    const float* p = h2f + (size_t)b * NLM_C * NLM_N + j;
    float s0 = 0.f, s1 = 0.f, s2 = 0.f, s3 = 0.f;
    for (int c = 0; c < NLM_C; c += 4) {
        float v0 = p[(size_t)c * NLM_N];
        float v1 = p[(size_t)(c + 1) * NLM_N];
        float v2 = p[(size_t)(c + 2) * NLM_N];
        float v3 = p[(size_t)(c + 3) * NLM_N];
        s0 = fmaf(v0, v0, s0); s1 = fmaf(v1, v1, s1);
        s2 = fmaf(v2, v2, s2); s3 = fmaf(v3, v3, s3);
    }
    sq[b * NLM_N + j] = (s0 + s1) + (s2 + s3);
}

__global__ void nlm_compact(const float* __restrict__ nm2, int* __restrict__ list,
                            int* __restrict__ cnt) {
    const int b = blockIdx.x;
    for (int j = threadIdx.x; j < NLM_N; j += 256) {
        if (nm2[(size_t)b * NLM_N + j] == 0.f) {
            int pos = atomicAdd(&cnt[b], 1);
            if (pos < NLM_MAXM) list[b * NLM_MAXM + pos] = j;
        }
    }
}

__global__ void nlm_gather(const unsigned* __restrict__ xTp, const int* __restrict__ list,
                           const int* __restrict__ cnt,
                           short* __restrict__ Phi, short* __restrict__ Plo) {
    const int b = blockIdx.y;
    const int id = blockIdx.x * 256 + threadIdx.x;
    const int i  = id >> 6;
    const int rem = id & 63;
    const int kb = rem >> 2, kg = rem & 3;
    const int lane = kg * 16 + (i & 15), rt = i >> 4;
    const size_t f = (size_t)b * NLM_PFRAG + ((size_t)(kb * NLM_RT + rt) * 64 + lane) * 8;
    if (i < cnt[b]) {
        const int pix = list[b * NLM_MAXM + i];
        const unsigned* s = xTp + ((size_t)b * NLM_N + pix) * NLM_C + kb * 32 + kg * 8;
#pragma unroll
        for (int jj = 0; jj < 8; ++jj) {
            unsigned v = s[jj];
            Phi[f + jj] = (short)(v & 0xFFFFu);
            Plo[f + jj] = (short)(v >> 16);
        }
    } else {
#pragma unroll
        for (int jj = 0; jj < 8; ++jj) { Phi[f + jj] = 0; Plo[f + jj] = 0; }
    }
}

__global__ __launch_bounds__(512) void nlm_gemm1(
    const unsigned* __restrict__ xTp, const short* __restrict__ Phi,
    const short* __restrict__ Plo, const int* __restrict__ cnt,
    float* __restrict__ S) {
    const int img = blockIdx.z, mt = blockIdx.y, nt = blockIdx.x;
    if (mt * 128 >= cnt[img]) return;
    __shared__ __align__(16) unsigned BH[4 * 128 * 4];
    __shared__ __align__(16) unsigned BL[4 * 128 * 4];
    const int t = threadIdx.x, lane = t & 63, wv = t >> 6, wm = wv >> 1, wn = wv & 1;
    const int j0 = nt * 128;
    const int spx = t & 127, sg = t >> 7;
    f32x4 acc[2][4] = {};
#pragma unroll 1
    for (int kb = 0; kb < NLM_KB1; ++kb) {
        unsigned v[8];
#pragma unroll
        for (int jj = 0; jj < 8; ++jj) v[jj] = 0u;
        const int j = j0 + spx;
        if (j < NLM_N) {
            const unsigned* s = xTp + ((size_t)img * NLM_N + j) * NLM_C + kb * 32 + sg * 8;
#pragma unroll
            for (int jj = 0; jj < 8; ++jj) v[jj] = s[jj];
        }
        uint4v hd, ld;
#pragma unroll
        for (int jj = 0; jj < 4; ++jj) {
            hd[jj] = (v[2 * jj] & 0xFFFFu) | (v[2 * jj + 1] << 16);
            ld[jj] = (v[2 * jj] >> 16) | (v[2 * jj + 1] & 0xFFFF0000u);
        }
        *(uint4v*)&BH[(sg * 128 + spx) * 4] = hd;
        *(uint4v*)&BL[(sg * 128 + spx) * 4] = ld;
        __syncthreads();
        const size_t ab = (size_t)img * NLM_PFRAG
                        + (size_t)(kb * NLM_RT + mt * 8 + wm * 2) * 512 + (size_t)lane * 8;
        short8 ah0 = *(const short8*)(Phi + ab);
        short8 ah1 = *(const short8*)(Phi + ab + 512);
        short8 al0 = *(const short8*)(Plo + ab);
        short8 al1 = *(const short8*)(Plo + ab + 512);
        const int g = lane >> 4, pl = lane & 15;
#pragma unroll
        for (int fn = 0; fn < 4; ++fn) {
            const int px = wn * 64 + fn * 16 + pl;
            short8 bh = *(const short8*)&BH[(g * 128 + px) * 4];
            short8 bl = *(const short8*)&BL[(g * 128 + px) * 4];
            acc[0][fn] = mfma16(ah0, bh, acc[0][fn]);
            acc[1][fn] = mfma16(ah1, bh, acc[1][fn]);
            acc[0][fn] = mfma16(al0, bh, acc[0][fn]);
            acc[1][fn] = mfma16(al1, bh, acc[1][fn]);
            acc[0][fn] = mfma16(ah0, bl, acc[0][fn]);
            acc[1][fn] = mfma16(ah1, bl, acc[1][fn]);
        }
        __syncthreads();
    }
#pragma unroll
    for (int fm = 0; fm < 2; ++fm)
#pragma unroll
    for (int fn = 0; fn < 4; ++fn) {
        const int row = mt * 128 + (wm * 2 + fm) * 16 + (lane >> 4) * 4;
        const int j = j0 + wn * 64 + fn * 16 + (lane & 15);
        if (j >= NLM_N) continue;
        f32x4 a = acc[fm][fn];
#pragma unroll
        for (int r = 0; r < 4; ++r)
            S[((size_t)img * NLM_MAXM + row + r) * NLM_N + j] = a[r];
    }
}

__global__ __launch_bounds__(256) void nlm_row(
    const float* __restrict__ S, const float* __restrict__ sq,
    const float* __restrict__ nm2, const int* __restrict__ list,
    const int* __restrict__ cnt,
    short* __restrict__ W2hi, short* __restrict__ W2lo,
    float* __restrict__ sumw, float inv_h2) {
    const int img = blockIdx.y, i = blockIdx.x;
    if (i >= cnt[img] || i >= NLM_MAXM) return;
    __shared__ float Drow[NLM_N];
    __shared__ float red[256];
    const int tid = threadIdx.x;
    const int pix = list[img * NLM_MAXM + i];
    const float sqi = sq[img * NLM_N + pix];
    const float BIG = 3.4e38f;
    float lmin = BIG;
    for (int j = tid; j < NLM_N; j += 256) {
        float d = BIG;
        if (nm2[(size_t)img * NLM_N + j] != 0.f) {
            float dot = S[((size_t)img * NLM_MAXM + i) * NLM_N + j];
            d = sqi + sq[img * NLM_N + j] - 2.f * dot;
            d = d > 0.f ? d : 0.f;
            lmin = d < lmin ? d : lmin;
        }
        Drow[j] = d;
    }
    red[tid] = lmin;
    __syncthreads();
    for (int o = 128; o > 0; o >>= 1) {
        if (tid < o) red[tid] = fminf(red[tid], red[tid + o]);
        __syncthreads();
    }
    const float dmin = red[0];
    __syncthreads();

    const int rt = i >> 4, lr = i & 15;
    float lsum = 0.f;
    for (int j = tid; j < NLM_KB2 * 32; j += 256) {
        float w = 0.f;
        if (j < NLM_N && Drow[j] < 3.3e38f) {
            w = expf(-(Drow[j] - dmin) * inv_h2);
            lsum += w;
        }
        const unsigned u = splitpack(w);
        const int kb = j >> 5, kg = (j & 31) >> 3, jj = j & 7;
        const int lane = kg * 16 + lr;
        const size_t f = (size_t)img * NLM_WFRAG
                       + ((size_t)(kb * NLM_RT + rt) * 64 + lane) * 8 + jj;
        W2hi[f] = (short)(u & 0xFFFFu);
        W2lo[f] = (short)(u >> 16);
    }
    red[tid] = lsum;
    __syncthreads();
    for (int o = 128; o > 0; o >>= 1) {
        if (tid < o) red[tid] += red[tid + o];
        __syncthreads();
    }
    if (tid == 0) sumw[img * NLM_MAXM + i] = red[0];
}

__global__ __launch_bounds__(512) void nlm_gemm2(
    const unsigned* __restrict__ xTp, const short* __restrict__ W2hi,
    const short* __restrict__ W2lo, const int* __restrict__ cnt,
    const float* __restrict__ sumw, const int* __restrict__ list,
    short* __restrict__ outHi, short* __restrict__ outLo) {
    const int img = blockIdx.z, mt = blockIdx.y, ct = blockIdx.x;
    const int cN = cnt[img] < NLM_MAXM ? cnt[img] : NLM_MAXM;
    if (mt * 128 >= cN) return;
    __shared__ __align__(16) unsigned BH[4 * 128 * 4];
    __shared__ __align__(16) unsigned BL[4 * 128 * 4];
    const int t = threadIdx.x, lane = t & 63, wv = t >> 6, wm = wv >> 1, wn = wv & 1;
    const int c0 = ct * 128;
    const int sc = t & 127, sg = t >> 7;
    f32x4 acc[2][4] = {};
#pragma unroll 1
    for (int kb = 0; kb < NLM_KB2; ++kb) {
        unsigned v[8];
#pragma unroll
        for (int jj = 0; jj < 8; ++jj) {
            const int j = kb * 32 + sg * 8 + jj;
            v[jj] = (j < NLM_N)
                  ? xTp[((size_t)img * NLM_N + j) * NLM_C + c0 + sc] : 0u;
        }
        uint4v hd, ld;
#pragma unroll
        for (int jj = 0; jj < 4; ++jj) {
            hd[jj] = (v[2 * jj] & 0xFFFFu) | (v[2 * jj + 1] << 16);
            ld[jj] = (v[2 * jj] >> 16) | (v[2 * jj + 1] & 0xFFFF0000u);
        }
        *(uint4v*)&BH[(sg * 128 + sc) * 4] = hd;
        *(uint4v*)&BL[(sg * 128 + sc) * 4] = ld;
        __syncthreads();
        const size_t ab = (size_t)img * NLM_WFRAG
                        + (size_t)(kb * NLM_RT + mt * 8 + wm * 2) * 512 + (size_t)lane * 8;
        short8 ah0 = *(const short8*)(W2hi + ab);
        short8 ah1 = *(const short8*)(W2hi + ab + 512);
        short8 al0 = *(const short8*)(W2lo + ab);
        short8 al1 = *(const short8*)(W2lo + ab + 512);
        const int g = lane >> 4, pl = lane & 15;
#pragma unroll
        for (int fn = 0; fn < 4; ++fn) {
            const int px = wn * 64 + fn * 16 + pl;
            short8 bh = *(const short8*)&BH[(g * 128 + px) * 4];
            short8 bl = *(const short8*)&BL[(g * 128 + px) * 4];
            acc[0][fn] = mfma16(ah0, bh, acc[0][fn]);
            acc[1][fn] = mfma16(ah1, bh, acc[1][fn]);
            acc[0][fn] = mfma16(al0, bh, acc[0][fn]);
            acc[1][fn] = mfma16(al1, bh, acc[1][fn]);
            acc[0][fn] = mfma16(ah0, bl, acc[0][fn]);
            acc[1][fn] = mfma16(ah1, bl, acc[1][fn]);
        }
        __syncthreads();
    }
#pragma unroll
    for (int fm = 0; fm < 2; ++fm)
#pragma unroll
    for (int fn = 0; fn < 4; ++fn) {
        const int row = mt * 128 + (wm * 2 + fm) * 16 + (lane >> 4) * 4;
        const int c = c0 + wn * 64 + fn * 16 + (lane & 15);
        f32x4 a = acc[fm][fn];
#pragma unroll
        for (int r = 0; r < 4; ++r) {
            const int ri = row + r;
            if (ri < cN) {
                const float y = a[r] / sumw[img * NLM_MAXM + ri];
                const int pix = list[img * NLM_MAXM + ri];
                const size_t pa = (((size_t)img * (NLM_C >> 5) + (c >> 5)) * NLM_N + pix) * 32
                                + (c & 31);
                unsigned h16 = f2bf_rne(y);
                float rr = y - bf2f(h16);
                outHi[pa] = (short)h16;
                outLo[pa] = (short)f2bf_rne(rr);
            }
        }
    }
}

// ---------------------------------------------------------------------------
// Driver
// ---------------------------------------------------------------------------
extern "C" void kernel_launch(void* const* d_in, const int* in_sizes, int n_in,
                              void* d_out, int out_size, void* d_ws, size_t ws_size,
                              hipStream_t stream) {
    const float* x0    = (const float*)d_in[0];
    const float* m0    = (const float*)d_in[1];
    const float* Wsrc[8] = {
        (const float*)d_in[2], (const float*)d_in[3], (const float*)d_in[4],
        (const float*)d_in[5], (const float*)d_in[6], (const float*)d_in[7],
        (const float*)d_in[8], (const float*)d_in[9]
    };
    const float* dec1b = (const float*)d_in[10];
    const float* enc2g = (const float*)d_in[11];
    const float* enc2b = (const float*)d_in[12];
    const float* enc3g = (const float*)d_in[13];
    const float* enc3b = (const float*)d_in[14];
    const float* enc4g = (const float*)d_in[15];
    const float* enc4b = (const float*)d_in[16];
    const float* dec4g = (const float*)d_in[17];
    const float* dec4b = (const float*)d_in[18];
    const float* dec3g = (const float*)d_in[19];
    const float* dec3b = (const float*)d_in[20];
    const float* dec2g = (const float*)d_in[21];
    const float* dec2b = (const float*)d_in[22];
    float* outp = (float*)d_out;

    const int N = 8;
    float* ws = (float*)d_ws;
    size_t off = 0;
    auto alloc = [&](size_t nf) {
        size_t o = off;
        off += ((nf + 63) / 64) * 64;
        return ws + o;
    };
    auto allocPair = [&](size_t E, short** hi, short** lo) {
        float* p = alloc(E);
        *hi = (short*)p;
        *lo = (short*)p + E;
    };

    short *h1hi, *h1lo, *h2shi, *h2slo, *h3hi, *h3lo, *h4hi, *h4lo, *d4hi, *d4lo;
    allocPair(10616832, &h1hi, &h1lo);   // 8x256x72x72  (later d2 planes)
    allocPair(5308416, &h2shi, &h2slo);  // 8x512x36x36  (later d3 planes)
    allocPair(1327104, &h3hi, &h3lo);    // 8x512x18x18
    allocPair(331776, &h4hi, &h4lo);     // 8x512x9x9
    allocPair(1327104, &d4hi, &d4lo);
    float* ybuf = alloc(10616832);
    float* h2f  = alloc(5308416);
    unsigned* xTp = (unsigned*)alloc(5308416);
    float* sqb  = alloc(10368);
    float* mc   = alloc(165888);
    float* nm1  = alloc(41472);
    float* nm2  = alloc(10368);
    float* nm3  = alloc(2592);
    float* nm4  = alloc(648);
    float* nmd4 = alloc(2592);
    float* nmd3 = alloc(10368);
    float* nmd2 = alloc(41472);
    float* nmx  = alloc(165888);
    float* bmean = alloc(512);
    float* bistd = alloc(512);
    short* Whi = (short*)alloc(10625024);
    short* Wlo = (short*)alloc(10625024);
    float* Smat = alloc((size_t)8 * NLM_MAXM * NLM_N);
    float* Phi_  = alloc((size_t)8 * NLM_PFRAG / 2);
    float* Plo_  = alloc((size_t)8 * NLM_PFRAG / 2);
    float* W2hi_ = alloc((size_t)8 * NLM_WFRAG / 2);
    float* W2lo_ = alloc((size_t)8 * NLM_WFRAG / 2);
    short* Phi = (short*)Phi_;  short* Plo = (short*)Plo_;
    short* W2hi = (short*)W2hi_; short* W2lo = (short*)W2lo_;
    int*   mlist = (int*)alloc(8 * NLM_MAXM);
    int*   mcnt  = (int*)alloc(64);
    float* sumw  = alloc(8 * NLM_MAXM);
    short* d3hi = h2shi; short* d3lo = h2slo;
    short* d2hi = h1hi;  short* d2lo = h1lo;

    if (ws_size < off * sizeof(float)) return;

    auto cdiv = [](size_t a, size_t b) { return (int)((a + b - 1) / b); };

    // ---- weight transforms ----
    struct WLay { int Cout, Cin, K; size_t ofs; };
    const WLay WL[8] = {
        {256, 128, 7, 0},         // enc1
        {512, 256, 5, 1605632},   // enc2
        {512, 512, 3, 4882432},   // enc3
        {512, 512, 3, 7241728},   // enc4
        {512, 1024, 3, 9601024},  // dec4
        {512, 1024, 3, 14319616}, // dec3
        {256, 768, 3, 19038208},  // dec2
        {128, 384, 3, 20807680},  // dec1
    };
    for (int i = 0; i < 8; ++i) {
        size_t tot = (size_t)WL[i].Cout * WL[i].Cin * WL[i].K * WL[i].K;
        wtransform<<<cdiv(tot, 256), 256, 0, stream>>>(
            Wsrc[i], Whi + WL[i].ofs, Wlo + WL[i].ofs, WL[i].Cout, WL[i].Cin,
            WL[i].K * WL[i].K, tot);
    }

    // ---- x0 planes live in d_out (free scratch until dec1 overwrites it) ----
    short* x0hi = (short*)d_out;
    short* x0lo = x0hi + 21233664;
    split_planes<<<dim3(324, 4, N), 256, 0, stream>>>(x0, x0hi, x0lo, 128, 20736);

    // ---------------- enc1: x0 planes -> h1 planes, relu ----------------
    maskconv_kernel<7, 2, false><<<cdiv(N * 72 * 72, 256), 256, 0, stream>>>(
        m0, 144, 144, mc, nm1, N, 144, 144, 72, 72);
    conv_enc<7, 2, 8, 8, 2, false, EPI_PAIR_RELU><<<dim3(81, 1, N), 512, 0, stream>>>(
        x0hi, x0lo, 128, 144, 144, m0,
        Whi + WL[0].ofs, Wlo + WL[0].ofs, mc, nullptr, h1hi, h1lo,
        72, 72, 256, 9);

    // ---------------- enc2 ----------------
    maskconv_kernel<5, 2, false><<<cdiv(N * 36 * 36, 256), 256, 0, stream>>>(
        nm1, 72, 72, mc, nm2, N, 72, 72, 36, 36);
    conv_enc<5, 2, 8, 8, 2, false, EPI_F32><<<dim3(25, 2, N), 512, 0, stream>>>(
        h1hi, h1lo, 256, 72, 72, nm1,
        Whi + WL[1].ofs, Wlo + WL[1].ofs, mc, nullptr, ybuf, nullptr,
        36, 36, 512, 5);
    bn_stats_kernel<<<512, 256, 0, stream>>>(ybuf, N, 512, 1296, bmean, bistd);
    bn_apply_blk<<<dim3(cdiv(1296, 64), 16, N), 256, 0, stream>>>(
        ybuf, bmean, bistd, enc2g, enc2b, h2shi, h2slo, h2f, 512, 1296, ACT_RELU);

    // ---------------- NLM swap ----------------
    nlm_trans<<<dim3(41, 16, N), 256, 0, stream>>>(h2f, xTp);
    nlm_sq2<<<dim3(6, N), 256, 0, stream>>>(h2f, sqb);
    hipMemsetAsync(mcnt, 0, 8 * sizeof(int), stream);
    nlm_compact<<<N, 256, 0, stream>>>(nm2, mlist, mcnt);
    nlm_gather<<<dim3(64, N), 256, 0, stream>>>(xTp, mlist, mcnt, Phi, Plo);
    nlm_gemm1<<<dim3(11, 2, N), 512, 0, stream>>>(xTp, Phi, Plo, mcnt, Smat);
    nlm_row<<<dim3(NLM_MAXM, N), 256, 0, stream>>>(Smat, sqb, nm2, mlist, mcnt,
                                                   W2hi, W2lo, sumw, 1.f / 25.f);
    nlm_gemm2<<<dim3(4, 2, N), 512, 0, stream>>>(xTp, W2hi, W2lo, mcnt, sumw,
                                                 mlist, h2shi, h2slo);

    // ---------------- enc3 ----------------
    maskconv_kernel<3, 2, false><<<cdiv(N * 18 * 18, 256), 256, 0, stream>>>(
        nm2, 36, 36, mc, nm3, N, 36, 36, 18, 18);
    conv_enc<3, 2, 4, 8, 1, false, EPI_F32><<<dim3(15, 2, N), 512, 0, stream>>>(
        h2shi, h2slo, 512, 36, 36, nm2,
        Whi + WL[2].ofs, Wlo + WL[2].ofs, mc, nullptr, ybuf, nullptr,
        18, 18, 512, 3);
    bn_stats_kernel<<<512, 256, 0, stream>>>(ybuf, N, 512, 324, bmean, bistd);
    bn_apply_blk<<<dim3(cdiv(324, 64), 16, N), 256, 0, stream>>>(
        ybuf, bmean, bistd, enc3g, enc3b, h3hi, h3lo, nullptr, 512, 324, ACT_RELU);

    // ---------------- enc4 ----------------
    maskconv_kernel<3, 2, false><<<cdiv(N * 9 * 9, 256), 256, 0, stream>>>(
        nm3, 18, 18, mc, nm4, N, 18, 18, 9, 9);
    conv_enc<3, 2, 4, 8, 1, false, EPI_F32><<<dim3(6, 2, N), 512, 0, stream>>>(
        h3hi, h3lo, 512, 18, 18, nm3,
        Whi + WL[3].ofs, Wlo + WL[3].ofs, mc, nullptr, ybuf, nullptr,
        9, 9, 512, 2);
    bn_stats_kernel<<<512, 256, 0, stream>>>(ybuf, N, 512, 81, bmean, bistd);
    bn_apply_blk<<<dim3(cdiv(81, 64), 16, N), 256, 0, stream>>>(
        ybuf, bmean, bistd, enc4g, enc4b, h4hi, h4lo, nullptr, 512, 81, ACT_RELU);

    // ---------------- dec4 ----------------
    maskconv_kernel<3, 1, true><<<cdiv(N * 18 * 18, 256), 256, 0, stream>>>(
        nm4, 9, 9, mc, nmd4, N, 18, 18, 18, 18);
    conv3x3<8, 8, 2, false, EPI_F32><<<dim3(9, 4, N), 512, 0, stream>>>(
        h4hi, h4lo, 512, 9, 9, h3hi, h3lo, 512, nm4,
        Whi + WL[4].ofs, Wlo + WL[4].ofs, mc, nullptr, ybuf,
        18, 18, 512, 3);
    bn_stats_kernel<<<512, 256, 0, stream>>>(ybuf, N, 512, 324, bmean, bistd);
    bn_apply_blk<<<dim3(cdiv(324, 64), 16, N), 256, 0, stream>>>(
        ybuf, bmean, bistd, dec4g, dec4b, d4hi, d4lo, nullptr, 512, 324, ACT_LEAKY);

    // ---------------- dec3 ----------------
    maskconv_kernel<3, 1, true><<<cdiv(N * 36 * 36, 256), 256, 0, stream>>>(
        nmd4, 18, 18, mc, nmd3, N, 36, 36, 36, 36);
    conv3x3<8, 12, 3, false, EPI_F32><<<dim3(15, 4, N), 512, 0, stream>>>(
        d4hi, d4lo, 512, 18, 18, h2shi, h2slo, 512, nmd4,
        Whi + WL[5].ofs, Wlo + WL[5].ofs, mc, nullptr, ybuf,
        36, 36, 512, 3);
    bn_stats_kernel<<<512, 256, 0, stream>>>(ybuf, N, 512, 1296, bmean, bistd);
    bn_apply_blk<<<dim3(cdiv(1296, 64), 16, N), 256, 0, stream>>>(
        ybuf, bmean, bistd, dec3g, dec3b, d3hi, d3lo, nullptr, 512, 1296, ACT_LEAKY);

    // ---------------- dec2 ----------------
    maskconv_kernel<3, 1, true><<<cdiv(N * 72 * 72, 256), 256, 0, stream>>>(
        nmd3, 36, 36, mc, nmd2, N, 72, 72, 72, 72);
    conv3x3<8, 16, 4, false, EPI_F32><<<dim3(45, 2, N), 512, 0, stream>>>(
        d3hi, d3lo, 512, 36, 36, h1hi, h1lo, 256, nmd3,
        Whi + WL[6].ofs, Wlo + WL[6].ofs, mc, nullptr, ybuf,
        72, 72, 256, 5);
    bn_stats_kernel<<<256, 256, 0, stream>>>(ybuf, N, 256, 5184, bmean, bistd);
    bn_apply_blk<<<dim3(cdiv(5184, 64), 8, N), 256, 0, stream>>>(
        ybuf, bmean, bistd, dec2g, dec2b, d2hi, d2lo, nullptr, 256, 5184, ACT_LEAKY);

    // ---------------- dec1: cat[up2(d2), x0] -> d_out (x0 planes now dead) ----------------
    maskconv_kernel<3, 1, true><<<cdiv(N * 144 * 144, 256), 256, 0, stream>>>(
        nmd2, 72, 72, mc, nmx, N, 144, 144, 144, 144);
    conv3x3<8, 16, 4, true, EPI_F32_BIAS><<<dim3(162, 1, N), 512, 0, stream>>>(
        d2hi, d2lo, 256, 72, 72, x0, nullptr, 128, nmd2,
        Whi + WL[7].ofs, Wlo + WL[7].ofs, mc, dec1b, outp,
        144, 144, 128, 9);
}

// Round 13
// 2756.747 us; speedup vs baseline: 1.0194x; 1.0029x over previous
//
#include <hip/hip_runtime.h>
#include <math.h>

#define ACT_NONE 0
#define ACT_RELU 1
#define ACT_LEAKY 2

#define EPI_F32 0
#define EPI_PAIR_RELU 1
#define EPI_F32_BIAS 2

typedef __attribute__((ext_vector_type(8))) short short8;
typedef __attribute__((ext_vector_type(8))) __bf16 bf16x8;
typedef __attribute__((ext_vector_type(4))) float f32x4;
typedef __attribute__((ext_vector_type(4))) unsigned uint4v;

__device__ __forceinline__ float actf(float y, int act) {
    if (act == ACT_RELU)  return y > 0.f ? y : 0.f;
    if (act == ACT_LEAKY) return y >= 0.f ? y : 0.2f * y;
    return y;
}

// ---- bf16 split helpers ----
__device__ __forceinline__ unsigned f2bf_rne(float f) {
    unsigned u = __float_as_uint(f);
    return (u + 0x7FFFu + ((u >> 16) & 1u)) >> 16;
}
__device__ __forceinline__ float bf2f(unsigned h) { return __uint_as_float(h << 16); }
__device__ __forceinline__ unsigned splitpack(float f) {
    unsigned hi = f2bf_rne(f);
    float r = f - bf2f(hi);
    unsigned lo = f2bf_rne(r);
    return (hi & 0xFFFFu) | (lo << 16);
}

__device__ __forceinline__ f32x4 mfma16(short8 a, short8 b, f32x4 c) {
    return __builtin_amdgcn_mfma_f32_16x16x32_bf16(
        __builtin_bit_cast(bf16x8, a), __builtin_bit_cast(bf16x8, b), c, 0, 0, 0);
}

// blocked-plane address (u16 units): [img][c/32][HW pix][c%32]
__device__ __forceinline__ size_t paddr(int img, int KBc, size_t HW, size_t pix) {
    return ((size_t)img * KBc * HW + pix) * 32;
}

// ---------------------------------------------------------------------------
// Mask convolution
// ---------------------------------------------------------------------------
template<int K, int S, bool MHALF>
__global__ void maskconv_kernel(const float* __restrict__ M, int HM, int WM,
                                float* __restrict__ mc, float* __restrict__ nm,
                                int N, int Hin, int Win, int Hout, int Wout) {
    constexpr int P = (K - 1) / 2;
    int idx = blockIdx.x * blockDim.x + threadIdx.x;
    int total = N * Hout * Wout;
    if (idx >= total) return;
    int wo = idx % Wout;
    int t  = idx / Wout;
    int ho = t % Hout;
    int n  = t / Hout;
    float s = 0.f;
    for (int kh = 0; kh < K; ++kh) {
        int ih = ho * S - P + kh;
        if ((unsigned)ih >= (unsigned)Hin) continue;
        const float* mrow = M + ((size_t)n * HM + (MHALF ? (ih >> 1) : ih)) * WM;
        for (int kw = 0; kw < K; ++kw) {
            int iw = wo * S - P + kw;
            if ((unsigned)iw < (unsigned)Win)
                s += mrow[MHALF ? (iw >> 1) : iw];
        }
    }
    mc[idx] = s;
    nm[idx] = (s == 0.f) ? 0.f : 1.f;
}

// ---------------------------------------------------------------------------
// Weight transform (A-fragment layout bf16 hi/lo)
// ---------------------------------------------------------------------------
__global__ void wtransform(const float* __restrict__ W, short* __restrict__ Whi,
                           short* __restrict__ Wlo, int Cout, int Cin, int Ksz,
                           size_t total) {
    size_t idx = (size_t)blockIdx.x * blockDim.x + threadIdx.x;
    if (idx >= total) return;
    int j = (int)(idx & 7);
    int lane = (int)((idx >> 3) & 63);
    size_t r = idx >> 9;
    int COB = Cout >> 4, KB = Cin >> 5;
    int cob = (int)(r % COB); r /= COB;
    int kb = (int)(r % KB);
    int tap = (int)(r / KB);
    int co = cob * 16 + (lane & 15);
    int ci = kb * 32 + (lane >> 4) * 8 + j;
    float f = W[((size_t)co * Cin + ci) * Ksz + tap];
    unsigned hi = f2bf_rne(f);
    float rr = f - bf2f(hi);
    unsigned lo = f2bf_rne(rr);
    Whi[idx] = (short)hi;
    Wlo[idx] = (short)lo;
}

// ---------------------------------------------------------------------------
// f32 NCHW -> blocked hi/lo planes (LDS-tiled transpose, both sides coalesced)
// grid: (cdiv(HW,64), C/32, N), 256 threads
// ---------------------------------------------------------------------------
__global__ __launch_bounds__(256) void split_planes(
    const float* __restrict__ x, short* __restrict__ hi, short* __restrict__ lo,
    int C, int HW) {
    __shared__ float tile[32][65];
    const int img = blockIdx.z, kb = blockIdx.y;
    const int px0 = blockIdx.x * 64;
    const int tid = threadIdx.x;
    const int KBc = C >> 5;
    for (int i = tid; i < 32 * 64; i += 256) {
        const int ch = i >> 6, px = i & 63;
        float v = 0.f;
        if (px0 + px < HW)
            v = x[((size_t)img * C + kb * 32 + ch) * HW + px0 + px];
        tile[ch][px] = v;
    }
    __syncthreads();
    const int px = tid >> 2, sg = tid & 3;
    if (px0 + px < HW) {
        short8 h8, l8;
#pragma unroll
        for (int j = 0; j < 8; ++j) {
            float v = tile[sg * 8 + j][px];
            unsigned h16 = f2bf_rne(v);
            float rr = v - bf2f(h16);
            h8[j] = (short)h16;
            l8[j] = (short)f2bf_rne(rr);
        }
        const size_t a = (((size_t)img * KBc + kb) * HW + px0 + px) * 32 + sg * 8;
        *(short8*)&hi[a] = h8;
        *(short8*)&lo[a] = l8;
    }
}

// ---------------------------------------------------------------------------
// Encoder halo-staged stride-2 conv. A-source: blocked planes (or f32 if AF32).
// ---------------------------------------------------------------------------
template<int K, int S, int TH, int TW, int NFW, bool AF32, int EPI>
__global__ __launch_bounds__(512) void conv_enc(
    const void* __restrict__ Ahi, const void* __restrict__ Alo,
    int Cin, int Hin, int Win,
    const float* __restrict__ M,
    const short* __restrict__ Whi, const short* __restrict__ Wlo,
    const float* __restrict__ mc, const float* __restrict__ bias,
    void* __restrict__ outp, void* __restrict__ outp2,
    int Hout, int Wout, int Cout, int TX)
{
    static_assert(S == 2, "parity layout assumes stride 2");
    constexpr int P = (K - 1) / 2;
    constexpr int HH  = (TH - 1) * S + K;
    constexpr int HWC = (TW - 1) * S + K;
    constexpr int PXC = HH * HWC;
    static_assert(PXC <= 512, "one halo pixel per thread");
    constexpr int PW  = (HWC + 1) / 2;
    constexpr int PXC2 = HH * PW * 2;
    constexpr int PXC2P = PXC2 + ((2 - (PXC2 % 8) + 8) % 8);   // bank-phase pad
    __shared__ __align__(16) short BHs[4 * PXC2P * 8];
    __shared__ __align__(16) short BLs[4 * PXC2P * 8];

    const int t    = threadIdx.x;
    const int lane = t & 63;
    const int wv   = t >> 6;
    const int wm   = wv >> 1;
    const int wn   = wv & 1;
    const int img  = blockIdx.z;
    const int coB  = blockIdx.y * 256;
    const int tile = blockIdx.x;
    const int ty   = tile / TX, tx = tile - ty * TX;
    const int oy0  = ty * TH, ox0 = tx * TW;
    const int KB   = Cin >> 5;
    const int COB  = Cout >> 4;
    const size_t HW = (size_t)Hin * Win;
    const int g  = lane >> 4;
    const int pl = lane & 15;

    // staging descriptor (once)
    bool sel = false;
    size_t basef = 0, basep = 0;
    int qq = 0;
    if (t < PXC) {
        const int r = t / HWC, c = t - r * HWC;
        qq = r * PW + (c >> 1) + (c & 1) * (HH * PW);
        const int iy = oy0 * S - P + r;
        const int ix = ox0 * S - P + c;
        if ((unsigned)iy < (unsigned)Hin && (unsigned)ix < (unsigned)Win) {
            const size_t pix = (size_t)iy * Win + ix;
            if (M[(size_t)img * HW + pix] != 0.f) {
                sel = true;
                basef = (size_t)img * Cin * HW + pix;
                basep = paddr(img, KB, HW, pix);
            }
        }
    }

    short8 hv[4], lv[4];
    auto prefetch = [&](int kb) {
#pragma unroll
        for (int gg = 0; gg < 4; ++gg) {
            if (sel) {
                if (AF32) {
                    const float* s = (const float*)Ahi + basef + (size_t)(kb * 32 + gg * 8) * HW;
#pragma unroll
                    for (int j = 0; j < 8; ++j) {
                        float f = s[(size_t)j * HW];
                        unsigned h16 = f2bf_rne(f);
                        float rr = f - bf2f(h16);
                        hv[gg][j] = (short)h16;
                        lv[gg][j] = (short)f2bf_rne(rr);
                    }
                } else {
                    const size_t a = basep + (size_t)kb * HW * 32 + gg * 8;
                    hv[gg] = *(const short8*)((const short*)Ahi + a);
                    lv[gg] = *(const short8*)((const short*)Alo + a);
                }
            } else {
#pragma unroll
                for (int j = 0; j < 8; ++j) { hv[gg][j] = 0; lv[gg][j] = 0; }
            }
        }
    };

    f32x4 acc[4][NFW] = {};
    if (t < PXC) prefetch(0);

#pragma unroll 1
    for (int kb = 0; kb < KB; ++kb) {
        if (t < PXC) {
#pragma unroll
            for (int gg = 0; gg < 4; ++gg) {
                *(short8*)&BHs[(gg * PXC2P + qq) * 8] = hv[gg];
                *(short8*)&BLs[(gg * PXC2P + qq) * 8] = lv[gg];
            }
        }
        __syncthreads();
        if (t < PXC && kb + 1 < KB) prefetch(kb + 1);

#pragma unroll 1
        for (int kh = 0; kh < K; ++kh)
#pragma unroll 1
        for (int kw = 0; kw < K; ++kw) {
            const int tap = kh * K + kw;
            const size_t wb = (((size_t)tap * KB + kb) * COB + (coB >> 4) + wm * 4) * 512
                            + (size_t)lane * 8;
            short8 ah[4], al[4];
#pragma unroll
            for (int fm = 0; fm < 4; ++fm) {
                ah[fm] = *(const short8*)(Whi + wb + (size_t)fm * 512);
                al[fm] = *(const short8*)(Wlo + wb + (size_t)fm * 512);
            }
            __builtin_amdgcn_s_setprio(1);
#pragma unroll
            for (int fn = 0; fn < NFW; ++fn) {
                const int pxf = (wn * NFW + fn) * 16 + pl;
                const int oy = pxf / TW, ox = pxf - oy * TW;
                const int q2 = (oy * S + kh) * PW + ox + (kw >> 1) + (kw & 1) * (HH * PW);
                short8 bh = *(const short8*)&BHs[(g * PXC2P + q2) * 8];
                short8 bl = *(const short8*)&BLs[(g * PXC2P + q2) * 8];
#pragma unroll
                for (int fm = 0; fm < 4; ++fm) {
                    acc[fm][fn] = mfma16(ah[fm], bh, acc[fm][fn]);
                    acc[fm][fn] = mfma16(al[fm], bh, acc[fm][fn]);
                    acc[fm][fn] = mfma16(ah[fm], bl, acc[fm][fn]);
                }
            }
            __builtin_amdgcn_s_setprio(0);
        }
        __syncthreads();
    }

    const int Npix = Hout * Wout;
    const float* mcb = mc + (size_t)img * Npix;
#pragma unroll
    for (int fm = 0; fm < 4; ++fm)
#pragma unroll
    for (int fn = 0; fn < NFW; ++fn) {
        const int co = coB + (wm * 4 + fm) * 16 + (lane >> 4) * 4;
        const int pxf = (wn * NFW + fn) * 16 + (lane & 15);
        const int oy = pxf / TW, ox = pxf - oy * TW;
        const int gy = oy0 + oy, gx = ox0 + ox;
        if (gy >= Hout || gx >= Wout) continue;
        const size_t pix = (size_t)gy * Wout + gx;
        const float m = mcb[pix];
        f32x4 a = acc[fm][fn];
#pragma unroll
        for (int r = 0; r < 4; ++r) {
            float y = a[r];
            if (EPI == EPI_F32_BIAS) {
                const float bv = bias[co + r];
                y = (m == 0.f) ? 0.f : (y - bv) / m + bv;
            } else {
                y = (m == 0.f) ? 0.f : y / m;
            }
            if (EPI == EPI_PAIR_RELU) {
                y = y > 0.f ? y : 0.f;
                const size_t pa = paddr(img, Cout >> 5, Npix, pix)
                                + (size_t)(co >> 5) * Npix * 32 + (co & 31) + r;
                unsigned h16 = f2bf_rne(y);
                float rr = y - bf2f(h16);
                ((short*)outp)[pa]  = (short)h16;
                ((short*)outp2)[pa] = (short)f2bf_rne(rr);
            } else {
                ((float*)outp)[((size_t)img * Cout + co + r) * Npix + pix] = y;
            }
        }
    }
}

// ---------------------------------------------------------------------------
// Decoder 3x3 s1 p1: 8 waves, MFW=2 (4m x 2n), NPIX=32*NFW, blocked-plane IO.
// ---------------------------------------------------------------------------
template<int TH, int TW, int NFW, bool BF32, int EPI>
__global__ __launch_bounds__(512) void conv3x3(
    const void* __restrict__ Ahi, const void* __restrict__ Alo,
    int CA, int HA, int WA,
    const void* __restrict__ Bhi, const void* __restrict__ Blo, int CB,
    const float* __restrict__ M,
    const short* __restrict__ Whi, const short* __restrict__ Wlo,
    const float* __restrict__ mc, const float* __restrict__ bias,
    void* __restrict__ outp,
    int Hout, int Wout, int Cout, int TX)
{
    constexpr int HALO_H = TH + 2, HALO_W = TW + 2, HALO = HALO_H * HALO_W;
    constexpr int HALOP = HALO + ((2 - (HALO % 8) + 8) % 8);   // bank-phase pad
    constexpr int NPIX = TH * TW;
    constexpr int SITER = (HALO + 127) / 128;
    static_assert(NPIX == 32 * NFW, "tile must be exactly 32*NFW pixels");
    __shared__ __align__(16) short BHs[4 * HALOP * 8];
    __shared__ __align__(16) short BLs[4 * HALOP * 8];

    const int t    = threadIdx.x;
    const int lane = t & 63;
    const int wv   = t >> 6;
    const int wm   = wv >> 1;
    const int wn   = wv & 1;
    const int img  = blockIdx.z;
    const int coB  = blockIdx.y * 128;
    const int tile = blockIdx.x;
    const int ty   = tile / TX;
    const int tx   = tile - ty * TX;
    const int oy0  = ty * TH, ox0 = tx * TW;
    const int Cin  = CA + CB;
    const int KB   = Cin >> 5;
    const int KBA  = CA >> 5;
    const int KBB  = CB >> 5;
    const int COB  = Cout >> 4;
    const int WM   = Wout >> 1;
    const size_t HWA = (size_t)HA * WA;
    const size_t HWB = (size_t)Hout * Wout;

    const int sg = t >> 7;
    const int st = t & 127;
    const int g  = lane >> 4;
    const int pl = lane & 15;

    // staging descriptors (once)
    bool ssel[SITER];
    size_t aoff[SITER], boff[SITER];
#pragma unroll
    for (int i = 0; i < SITER; ++i) {
        ssel[i] = false; aoff[i] = 0; boff[i] = 0;
        const int q = st + i * 128;
        if (q < HALO) {
            const int hy = q / HALO_W, hx = q - hy * HALO_W;
            const int iy = oy0 - 1 + hy, ix = ox0 - 1 + hx;
            if ((unsigned)iy < (unsigned)Hout && (unsigned)ix < (unsigned)Wout) {
                if (M[((size_t)img * (Hout >> 1) + (iy >> 1)) * WM + (ix >> 1)] != 0.f) {
                    ssel[i] = true;
                    const size_t pixA = (size_t)(iy >> 1) * WA + (ix >> 1);
                    const size_t pixB = (size_t)iy * Wout + ix;
                    aoff[i] = paddr(img, KBA, HWA, pixA) + sg * 8;
                    if (BF32) boff[i] = (size_t)img * CB * HWB + pixB;     // f32 elem base
                    else      boff[i] = paddr(img, KBB, HWB, pixB) + sg * 8;
                }
            }
        }
    }

    short8 hv[SITER], lv[SITER];
    auto prefetch = [&](int kb) {
        const int c = kb * 32 + sg * 8;
#pragma unroll
        for (int i = 0; i < SITER; ++i) {
            const int q = st + i * 128;
            bool ok = (q < HALO) && ssel[i];
            if (ok) {
                if (c < CA) {
                    const size_t a = aoff[i] + (size_t)kb * HWA * 32;
                    hv[i] = *(const short8*)((const short*)Ahi + a);
                    lv[i] = *(const short8*)((const short*)Alo + a);
                } else {
                    if (BF32) {
                        const float* s = (const float*)Bhi + boff[i] + (size_t)(c - CA) * HWB;
#pragma unroll
                        for (int j = 0; j < 8; ++j) {
                            float f = s[(size_t)j * HWB];
                            unsigned h16 = f2bf_rne(f);
                            float rr = f - bf2f(h16);
                            hv[i][j] = (short)h16;
                            lv[i][j] = (short)f2bf_rne(rr);
                        }
                    } else {
                        const size_t a = boff[i] + (size_t)(kb - KBA) * HWB * 32;
                        hv[i] = *(const short8*)((const short*)Bhi + a);
                        lv[i] = *(const short8*)((const short*)Blo + a);
                    }
                }
            } else {
#pragma unroll
                for (int j = 0; j < 8; ++j) { hv[i][j] = 0; lv[i][j] = 0; }
            }
        }
    };

    f32x4 acc[2][NFW] = {};
    const size_t wstride = (size_t)KB * COB * 512;
    prefetch(0);

#pragma unroll 1
    for (int kb = 0; kb < KB; ++kb) {
#pragma unroll
        for (int i = 0; i < SITER; ++i) {
            const int q = st + i * 128;
            if (q < HALO) {
                *(short8*)&BHs[(sg * HALOP + q) * 8] = hv[i];
                *(short8*)&BLs[(sg * HALOP + q) * 8] = lv[i];
            }
        }
        __syncthreads();
        if (kb + 1 < KB) prefetch(kb + 1);

        size_t wb = ((size_t)kb * COB + (coB >> 4) + wm * 2) * 512 + lane * 8;
#pragma unroll 1
        for (int tap = 0; tap < 9; ++tap) {
            const int dh = tap / 3, dw = tap - dh * 3;
            short8 ah0 = *(const short8*)(Whi + wb);
            short8 ah1 = *(const short8*)(Whi + wb + 512);
            short8 al0 = *(const short8*)(Wlo + wb);
            short8 al1 = *(const short8*)(Wlo + wb + 512);
            __builtin_amdgcn_s_setprio(1);
#pragma unroll
            for (int fn = 0; fn < NFW; ++fn) {
                const int pxf = (wn * NFW + fn) * 16 + pl;
                const int oy = pxf / TW, ox = pxf - oy * TW;
                const int hpx = (oy + dh) * HALO_W + (ox + dw);
                short8 bh = *(const short8*)&BHs[(g * HALOP + hpx) * 8];
                short8 bl = *(const short8*)&BLs[(g * HALOP + hpx) * 8];
                acc[0][fn] = mfma16(ah0, bh, acc[0][fn]);
                acc[1][fn] = mfma16(ah1, bh, acc[1][fn]);
                acc[0][fn] = mfma16(al0, bh, acc[0][fn]);
                acc[1][fn] = mfma16(al1, bh, acc[1][fn]);
                acc[0][fn] = mfma16(ah0, bl, acc[0][fn]);
                acc[1][fn] = mfma16(ah1, bl, acc[1][fn]);
            }
            __builtin_amdgcn_s_setprio(0);
            wb += wstride;
        }
        __syncthreads();
    }

    const float* mcb = mc + (size_t)img * HWB;
#pragma unroll
    for (int fm = 0; fm < 2; ++fm)
#pragma unroll
    for (int fn = 0; fn < NFW; ++fn) {
        const int co = coB + (wm * 2 + fm) * 16 + (lane >> 4) * 4;
        const int pxf = (wn * NFW + fn) * 16 + (lane & 15);
        const int oy = pxf / TW, ox = pxf - oy * TW;
        const int gy = oy0 + oy, gx = ox0 + ox;
        if (gy >= Hout || gx >= Wout) continue;
        const float m = mcb[(size_t)gy * Wout + gx];
        f32x4 a = acc[fm][fn];
#pragma unroll
        for (int r = 0; r < 4; ++r) {
            float y = a[r];
            if (EPI == EPI_F32_BIAS) {
                const float bv = bias[co + r];
                y = (m == 0.f) ? 0.f : (y - bv) / m + bv;
            } else {
                y = (m == 0.f) ? 0.f : y / m;
            }
            ((float*)outp)[((size_t)img * Cout + co + r) * HWB + (size_t)gy * Wout + gx] = y;
        }
    }
}

// ---------------------------------------------------------------------------
// BatchNorm stats
// ---------------------------------------------------------------------------
__global__ __launch_bounds__(256) void bn_stats_kernel(const float* __restrict__ y,
                                                       int N, int C, int HW,
                                                       float* __restrict__ mean,
                                                       float* __restrict__ istd) {
    const int c = blockIdx.x;
    double s = 0.0, s2 = 0.0;
    const int tot = N * HW;
    for (int i = threadIdx.x; i < tot; i += blockDim.x) {
        int n = i / HW, hw = i - n * HW;
        float v = y[((size_t)n * C + c) * HW + hw];
        s += v;
        s2 += (double)v * v;
    }
    __shared__ double sh[256], sh2[256];
    sh[threadIdx.x] = s; sh2[threadIdx.x] = s2;
    __syncthreads();
    for (int o = 128; o > 0; o >>= 1) {
        if (threadIdx.x < o) { sh[threadIdx.x] += sh[threadIdx.x + o]; sh2[threadIdx.x] += sh2[threadIdx.x + o]; }
        __syncthreads();
    }
    if (threadIdx.x == 0) {
        double mu = sh[0] / tot;
        double var = sh2[0] / tot - mu * mu;
        mean[c] = (float)mu;
        istd[c] = (float)(1.0 / sqrt(var + 1e-5));
    }
}

// ---------------------------------------------------------------------------
// BN apply + act -> blocked hi/lo planes (LDS-tiled transpose)
// ---------------------------------------------------------------------------
__global__ __launch_bounds__(256) void bn_apply_blk(
    const float* __restrict__ y,
    const float* __restrict__ mean, const float* __restrict__ istd,
    const float* __restrict__ g, const float* __restrict__ b,
    short* __restrict__ hi, short* __restrict__ lo, float* __restrict__ fout,
    int C, int HW, int act) {
    __shared__ float tile[32][65];
    const int img = blockIdx.z, kb = blockIdx.y;
    const int px0 = blockIdx.x * 64;
    const int tid = threadIdx.x;
    const int KBc = C >> 5;

    for (int i = tid; i < 32 * 64; i += 256) {
        const int ch = i >> 6, px = i & 63;
        float v = 0.f;
        if (px0 + px < HW)
            v = y[((size_t)img * C + kb * 32 + ch) * HW + px0 + px];
        tile[ch][px] = v;
    }
    __syncthreads();

    const int px = tid >> 2, sg = tid & 3;
    if (px0 + px < HW) {
        short8 h8, l8;
        float f8[8];
#pragma unroll
        for (int j = 0; j < 8; ++j) {
            const int c = kb * 32 + sg * 8 + j;
            float v = tile[sg * 8 + j][px];
            v = (v - mean[c]) * istd[c] * g[c] + b[c];
            v = actf(v, act);
            f8[j] = v;
            unsigned h16 = f2bf_rne(v);
            float rr = v - bf2f(h16);
            h8[j] = (short)h16;
            l8[j] = (short)f2bf_rne(rr);
        }
        const size_t a = (((size_t)img * KBc + kb) * HW + px0 + px) * 32 + sg * 8;
        *(short8*)&hi[a] = h8;
        *(short8*)&lo[a] = l8;
        if (fout) {
#pragma unroll
            for (int j = 0; j < 8; ++j)
                fout[((size_t)img * C + kb * 32 + sg * 8 + j) * HW + px0 + px] = f8[j];
        }
    }
}

// ---------------------------------------------------------------------------
// NLM (MFMA formulation; xTp stays packed-u32; gemm2 writes blocked planes)
// ---------------------------------------------------------------------------
#define NLM_C 512
#define NLM_N 1296
#define NLM_MAXM 256
#define NLM_RT 16
#define NLM_KB1 16
#define NLM_KB2 41
#define NLM_PFRAG (NLM_KB1 * NLM_RT * 512)
#define NLM_WFRAG (NLM_KB2 * NLM_RT * 512)

__global__ __launch_bounds__(256) void nlm_trans(const float* __restrict__ h2f,
                                                 unsigned* __restrict__ xTp) {
    __shared__ float tile[32][33];
    const int b = blockIdx.z;
    const int j0 = blockIdx.x * 32, c0 = blockIdx.y * 32;
    const int tx = threadIdx.x & 31, ty = threadIdx.x >> 5;
    for (int cc = ty; cc < 32; cc += 8) {
        const int j = j0 + tx;
        tile[cc][tx] = (j < NLM_N) ? h2f[((size_t)b * NLM_C + c0 + cc) * NLM_N + j] : 0.f;
    }
    __syncthreads();
    for (int jj = ty; jj < 32; jj += 8) {
        const int j = j0 + jj;
        if (j < NLM_N)
            xTp[((size_t)b * NLM_N + j) * NLM_C + c0 + tx] = splitpack(tile[tx][jj]);
    }
}

__global__ void nlm_sq2(const float* __restrict__ h2f, float* __restrict__ sq) {
    const int b = blockIdx.y;
    const int j = blockIdx.x * 256 + threadIdx.x;
    if (j >= NLM_N) return;
    const float* p = h2f + (size_t)b * NLM_C * NLM_N + j;
    float s0 = 0.f, s1 = 0.f, s2 = 0.f, s3 = 0.f;
    for (int c = 0; c < NLM_C; c += 4) {
        float v0 = p[(size_t)c * NLM_N];
        float v1 = p[(size_t)(c + 1) * NLM_N];
        float v2 = p[(size_t)(c + 2) * NLM_N];
        float v3 = p[(size_t)(c + 3) * NLM_N];
        s0 = fmaf(v0, v0, s0); s1 = fmaf(v1, v1, s1);
        s2 = fmaf(v2, v2, s2); s3 = fmaf(v3, v3, s3);
    }
    sq[b * NLM_N + j] = (s0 + s1) + (s2 + s3);
}

__global__ void nlm_compact(const float* __restrict__ nm2, int* __restrict__ list,
                            int* __restrict__ cnt) {
    const int b = blockIdx.x;
    for (int j = threadIdx.x; j < NLM_N; j += 256) {
        if (nm2[(size_t)b * NLM_N + j] == 0.f) {
            int pos = atomicAdd(&cnt[b], 1);
            if (pos < NLM_MAXM) list[b * NLM_MAXM + pos] = j;
        }
    }
}

__global__ void nlm_gather(const unsigned* __restrict__ xTp, const int* __restrict__ list,
                           const int* __restrict__ cnt,
                           short* __restrict__ Phi, short* __restrict__ Plo) {
    const int b = blockIdx.y;
    const int id = blockIdx.x * 256 + threadIdx.x;
    const int i  = id >> 6;
    const int rem = id & 63;
    const int kb = rem >> 2, kg = rem & 3;
    const int lane = kg * 16 + (i & 15), rt = i >> 4;
    const size_t f = (size_t)b * NLM_PFRAG + ((size_t)(kb * NLM_RT + rt) * 64 + lane) * 8;
    if (i < cnt[b]) {
        const int pix = list[b * NLM_MAXM + i];
        const unsigned* s = xTp + ((size_t)b * NLM_N + pix) * NLM_C + kb * 32 + kg * 8;
#pragma unroll
        for (int jj = 0; jj < 8; ++jj) {
            unsigned v = s[jj];
            Phi[f + jj] = (short)(v & 0xFFFFu);
            Plo[f + jj] = (short)(v >> 16);
        }
    } else {
#pragma unroll
        for (int jj = 0; jj < 8; ++jj) { Phi[f + jj] = 0; Plo[f + jj] = 0; }
    }
}

__global__ __launch_bounds__(512) void nlm_gemm1(
    const unsigned* __restrict__ xTp, const short* __restrict__ Phi,
    const short* __restrict__ Plo, const int* __restrict__ cnt,
    float* __restrict__ S) {
    const int img = blockIdx.z, mt = blockIdx.y, nt = blockIdx.x;
    if (mt * 128 >= cnt[img]) return;
    __shared__ __align__(16) unsigned BH[4 * 128 * 4];
    __shared__ __align__(16) unsigned BL[4 * 128 * 4];
    const int t = threadIdx.x, lane = t & 63, wv = t >> 6, wm = wv >> 1, wn = wv & 1;
    const int j0 = nt * 128;
    const int spx = t & 127, sg = t >> 7;
    f32x4 acc[2][4] = {};
#pragma unroll 1
    for (int kb = 0; kb < NLM_KB1; ++kb) {
        unsigned v[8];
#pragma unroll
        for (int jj = 0; jj < 8; ++jj) v[jj] = 0u;
        const int j = j0 + spx;
        if (j < NLM_N) {
            const unsigned* s = xTp + ((size_t)img * NLM_N + j) * NLM_C + kb * 32 + sg * 8;
#pragma unroll
            for (int jj = 0; jj < 8; ++jj) v[jj] = s[jj];
        }
        uint4v hd, ld;
#pragma unroll
        for (int jj = 0; jj < 4; ++jj) {
            hd[jj] = (v[2 * jj] & 0xFFFFu) | (v[2 * jj + 1] << 16);
            ld[jj] = (v[2 * jj] >> 16) | (v[2 * jj + 1] & 0xFFFF0000u);
        }
        *(uint4v*)&BH[(sg * 128 + spx) * 4] = hd;
        *(uint4v*)&BL[(sg * 128 + spx) * 4] = ld;
        __syncthreads();
        const size_t ab = (size_t)img * NLM_PFRAG
                        + (size_t)(kb * NLM_RT + mt * 8 + wm * 2) * 512 + (size_t)lane * 8;
        short8 ah0 = *(const short8*)(Phi + ab);
        short8 ah1 = *(const short8*)(Phi + ab + 512);
        short8 al0 = *(const short8*)(Plo + ab);
        short8 al1 = *(const short8*)(Plo + ab + 512);
        const int g = lane >> 4, pl = lane & 15;
#pragma unroll
        for (int fn = 0; fn < 4; ++fn) {
            const int px = wn * 64 + fn * 16 + pl;
            short8 bh = *(const short8*)&BH[(g * 128 + px) * 4];
            short8 bl = *(const short8*)&BL[(g * 128 + px) * 4];
            acc[0][fn] = mfma16(ah0, bh, acc[0][fn]);
            acc[1][fn] = mfma16(ah1, bh, acc[1][fn]);
            acc[0][fn] = mfma16(al0, bh, acc[0][fn]);
            acc[1][fn] = mfma16(al1, bh, acc[1][fn]);
            acc[0][fn] = mfma16(ah0, bl, acc[0][fn]);
            acc[1][fn] = mfma16(ah1, bl, acc[1][fn]);
        }
        __syncthreads();
    }
#pragma unroll
    for (int fm = 0; fm < 2; ++fm)
#pragma unroll
    for (int fn = 0; fn < 4; ++fn) {
        const int row = mt * 128 + (wm * 2 + fm) * 16 + (lane >> 4) * 4;
        const int j = j0 + wn * 64 + fn * 16 + (lane & 15);
        if (j >= NLM_N) continue;
        f32x4 a = acc[fm][fn];
#pragma unroll
        for (int r = 0; r < 4; ++r)
            S[((size_t)img * NLM_MAXM + row + r) * NLM_N + j] = a[r];
    }
}

__global__ __launch_bounds__(256) void nlm_row(
    const float* __restrict__ S, const float* __restrict__ sq,
    const float* __restrict__ nm2, const int* __restrict__ list,
    const int* __restrict__ cnt,
    short* __restrict__ W2hi, short* __restrict__ W2lo,
    float* __restrict__ sumw, float inv_h2) {
    const int img = blockIdx.y, i = blockIdx.x;
    if (i >= cnt[img] || i >= NLM_MAXM) return;
    __shared__ float Drow[NLM_N];
    __shared__ float red[256];
    const int tid = threadIdx.x;
    const int pix = list[img * NLM_MAXM + i];
    const float sqi = sq[img * NLM_N + pix];
    const float BIG = 3.4e38f;
    float lmin = BIG;
    for (int j = tid; j < NLM_N; j += 256) {
        float d = BIG;
        if (nm2[(size_t)img * NLM_N + j] != 0.f) {
            float dot = S[((size_t)img * NLM_MAXM + i) * NLM_N + j];
            d = sqi + sq[img * NLM_N + j] - 2.f * dot;
            d = d > 0.f ? d : 0.f;
            lmin = d < lmin ? d : lmin;
        }
        Drow[j] = d;
    }
    red[tid] = lmin;
    __syncthreads();
    for (int o = 128; o > 0; o >>= 1) {
        if (tid < o) red[tid] = fminf(red[tid], red[tid + o]);
        __syncthreads();
    }
    const float dmin = red[0];
    __syncthreads();

    const int rt = i >> 4, lr = i & 15;
    float lsum = 0.f;
    for (int j = tid; j < NLM_KB2 * 32; j += 256) {
        float w = 0.f;
        if (j < NLM_N && Drow[j] < 3.3e38f) {
            w = expf(-(Drow[j] - dmin) * inv_h2);
            lsum += w;
        }
        const unsigned u = splitpack(w);
        const int kb = j >> 5, kg = (j & 31) >> 3, jj = j & 7;
        const int lane = kg * 16 + lr;
        const size_t f = (size_t)img * NLM_WFRAG
                       + ((size_t)(kb * NLM_RT + rt) * 64 + lane) * 8 + jj;
        W2hi[f] = (short)(u & 0xFFFFu);
        W2lo[f] = (short)(u >> 16);
    }
    red[tid] = lsum;
    __syncthreads();
    for (int o = 128; o > 0; o >>= 1) {
        if (tid < o) red[tid] += red[tid + o];
        __syncthreads();
    }
    if (tid == 0) sumw[img * NLM_MAXM + i] = red[0];
}

__global__ __launch_bounds__(512) void nlm_gemm2(
    const unsigned* __restrict__ xTp, const short* __restrict__ W2hi,
    const short* __restrict__ W2lo, const int* __restrict__ cnt,
    const float* __restrict__ sumw, const int* __restrict__ list,
    short* __restrict__ outHi, short* __restrict__ outLo) {
    const int img = blockIdx.z, mt = blockIdx.y, ct = blockIdx.x;
    const int cN = cnt[img] < NLM_MAXM ? cnt[img] : NLM_MAXM;
    if (mt * 128 >= cN) return;
    __shared__ __align__(16) unsigned BH[4 * 128 * 4];
    __shared__ __align__(16) unsigned BL[4 * 128 * 4];
    const int t = threadIdx.x, lane = t & 63, wv = t >> 6, wm = wv >> 1, wn = wv & 1;
    const int c0 = ct * 128;
    const int sc = t & 127, sg = t >> 7;
    f32x4 acc[2][4] = {};
#pragma unroll 1
    for (int kb = 0; kb < NLM_KB2; ++kb) {
        unsigned v[8];
#pragma unroll
        for (int jj = 0; jj < 8; ++jj) {
            const int j = kb * 32 + sg * 8 + jj;
            v[jj] = (j < NLM_N)
                  ? xTp[((size_t)img * NLM_N + j) * NLM_C + c0 + sc] : 0u;
        }
        uint4v hd, ld;
#pragma unroll
        for (int jj = 0; jj < 4; ++jj) {
            hd[jj] = (v[2 * jj] & 0xFFFFu) | (v[2 * jj + 1] << 16);
            ld[jj] = (v[2 * jj] >> 16) | (v[2 * jj + 1] & 0xFFFF0000u);
        }
        *(uint4v*)&BH[(sg * 128 + sc) * 4] = hd;
        *(uint4v*)&BL[(sg * 128 + sc) * 4] = ld;
        __syncthreads();
        const size_t ab = (size_t)img * NLM_WFRAG
                        + (size_t)(kb * NLM_RT + mt * 8 + wm * 2) * 512 + (size_t)lane * 8;
        short8 ah0 = *(const short8*)(W2hi + ab);
        short8 ah1 = *(const short8*)(W2hi + ab + 512);
        short8 al0 = *(const short8*)(W2lo + ab);
        short8 al1 = *(const short8*)(W2lo + ab + 512);
        const int g = lane >> 4, pl = lane & 15;
#pragma unroll
        for (int fn = 0; fn < 4; ++fn) {
            const int px = wn * 64 + fn * 16 + pl;
            short8 bh = *(const short8*)&BH[(g * 128 + px) * 4];
            short8 bl = *(const short8*)&BL[(g * 128 + px) * 4];
            acc[0][fn] = mfma16(ah0, bh, acc[0][fn]);
            acc[1][fn] = mfma16(ah1, bh, acc[1][fn]);
            acc[0][fn] = mfma16(al0, bh, acc[0][fn]);
            acc[1][fn] = mfma16(al1, bh, acc[1][fn]);
            acc[0][fn] = mfma16(ah0, bl, acc[0][fn]);
            acc[1][fn] = mfma16(ah1, bl, acc[1][fn]);
        }
        __syncthreads();
    }
#pragma unroll
    for (int fm = 0; fm < 2; ++fm)
#pragma unroll
    for (int fn = 0; fn < 4; ++fn) {
        const int row = mt * 128 + (wm * 2 + fm) * 16 + (lane >> 4) * 4;
        const int c = c0 + wn * 64 + fn * 16 + (lane & 15);
        f32x4 a = acc[fm][fn];
#pragma unroll
        for (int r = 0; r < 4; ++r) {
            const int ri = row + r;
            if (ri < cN) {
                const float y = a[r] / sumw[img * NLM_MAXM + ri];
                const int pix = list[img * NLM_MAXM + ri];
                const size_t pa = (((size_t)img * (NLM_C >> 5) + (c >> 5)) * NLM_N + pix) * 32
                                + (c & 31);
                unsigned h16 = f2bf_rne(y);
                float rr = y - bf2f(h16);
                outHi[pa] = (short)h16;
                outLo[pa] = (short)f2bf_rne(rr);
            }
        }
    }
}

// ---------------------------------------------------------------------------
// Driver
// ---------------------------------------------------------------------------
extern "C" void kernel_launch(void* const* d_in, const int* in_sizes, int n_in,
                              void* d_out, int out_size, void* d_ws, size_t ws_size,
                              hipStream_t stream) {
    const float* x0    = (const float*)d_in[0];
    const float* m0    = (const float*)d_in[1];
    const float* Wsrc[8] = {
        (const float*)d_in[2], (const float*)d_in[3], (const float*)d_in[4],
        (const float*)d_in[5], (const float*)d_in[6], (const float*)d_in[7],
        (const float*)d_in[8], (const float*)d_in[9]
    };
    const float* dec1b = (const float*)d_in[10];
    const float* enc2g = (const float*)d_in[11];
    const float* enc2b = (const float*)d_in[12];
    const float* enc3g = (const float*)d_in[13];
    const float* enc3b = (const float*)d_in[14];
    const float* enc4g = (const float*)d_in[15];
    const float* enc4b = (const float*)d_in[16];
    const float* dec4g = (const float*)d_in[17];
    const float* dec4b = (const float*)d_in[18];
    const float* dec3g = (const float*)d_in[19];
    const float* dec3b = (const float*)d_in[20];
    const float* dec2g = (const float*)d_in[21];
    const float* dec2b = (const float*)d_in[22];
    float* outp = (float*)d_out;

    const int N = 8;
    float* ws = (float*)d_ws;
    size_t off = 0;
    auto alloc = [&](size_t nf) {
        size_t o = off;
        off += ((nf + 63) / 64) * 64;
        return ws + o;
    };
    auto allocPair = [&](size_t E, short** hi, short** lo) {
        float* p = alloc(E);
        *hi = (short*)p;
        *lo = (short*)p + E;
    };

    short *h1hi, *h1lo, *h2shi, *h2slo, *h3hi, *h3lo, *h4hi, *h4lo, *d4hi, *d4lo;
    allocPair(10616832, &h1hi, &h1lo);   // 8x256x72x72  (later d2 planes)
    allocPair(5308416, &h2shi, &h2slo);  // 8x512x36x36  (later d3 planes)
    allocPair(1327104, &h3hi, &h3lo);    // 8x512x18x18
    allocPair(331776, &h4hi, &h4lo);     // 8x512x9x9
    allocPair(1327104, &d4hi, &d4lo);
    float* ybuf = alloc(10616832);
    float* h2f  = alloc(5308416);
    unsigned* xTp = (unsigned*)alloc(5308416);
    float* sqb  = alloc(10368);
    float* mc   = alloc(165888);
    float* nm1  = alloc(41472);
    float* nm2  = alloc(10368);
    float* nm3  = alloc(2592);
    float* nm4  = alloc(648);
    float* nmd4 = alloc(2592);
    float* nmd3 = alloc(10368);
    float* nmd2 = alloc(41472);
    float* nmx  = alloc(165888);
    float* bmean = alloc(512);
    float* bistd = alloc(512);
    short* Whi = (short*)alloc(10625024);
    short* Wlo = (short*)alloc(10625024);
    float* Smat = alloc((size_t)8 * NLM_MAXM * NLM_N);
    float* Phi_  = alloc((size_t)8 * NLM_PFRAG / 2);
    float* Plo_  = alloc((size_t)8 * NLM_PFRAG / 2);
    float* W2hi_ = alloc((size_t)8 * NLM_WFRAG / 2);
    float* W2lo_ = alloc((size_t)8 * NLM_WFRAG / 2);
    short* Phi = (short*)Phi_;  short* Plo = (short*)Plo_;
    short* W2hi = (short*)W2hi_; short* W2lo = (short*)W2lo_;
    int*   mlist = (int*)alloc(8 * NLM_MAXM);
    int*   mcnt  = (int*)alloc(64);
    float* sumw  = alloc(8 * NLM_MAXM);
    short* d3hi = h2shi; short* d3lo = h2slo;
    short* d2hi = h1hi;  short* d2lo = h1lo;

    if (ws_size < off * sizeof(float)) return;

    auto cdiv = [](size_t a, size_t b) { return (int)((a + b - 1) / b); };

    // ---- weight transforms ----
    struct WLay { int Cout, Cin, K; size_t ofs; };
    const WLay WL[8] = {
        {256, 128, 7, 0},         // enc1
        {512, 256, 5, 1605632},   // enc2
        {512, 512, 3, 4882432},   // enc3
        {512, 512, 3, 7241728},   // enc4
        {512, 1024, 3, 9601024},  // dec4
        {512, 1024, 3, 14319616}, // dec3
        {256, 768, 3, 19038208},  // dec2
        {128, 384, 3, 20807680},  // dec1
    };
    for (int i = 0; i < 8; ++i) {
        size_t tot = (size_t)WL[i].Cout * WL[i].Cin * WL[i].K * WL[i].K;
        wtransform<<<cdiv(tot, 256), 256, 0, stream>>>(
            Wsrc[i], Whi + WL[i].ofs, Wlo + WL[i].ofs, WL[i].Cout, WL[i].Cin,
            WL[i].K * WL[i].K, tot);
    }

    // ---- x0 planes live in d_out (free scratch until dec1 overwrites it) ----
    short* x0hi = (short*)d_out;
    short* x0lo = x0hi + 21233664;
    split_planes<<<dim3(324, 4, N), 256, 0, stream>>>(x0, x0hi, x0lo, 128, 20736);

    // ---------------- enc1: x0 planes -> h1 planes, relu ----------------
    maskconv_kernel<7, 2, false><<<cdiv(N * 72 * 72, 256), 256, 0, stream>>>(
        m0, 144, 144, mc, nm1, N, 144, 144, 72, 72);
    conv_enc<7, 2, 8, 8, 2, false, EPI_PAIR_RELU><<<dim3(81, 1, N), 512, 0, stream>>>(
        x0hi, x0lo, 128, 144, 144, m0,
        Whi + WL[0].ofs, Wlo + WL[0].ofs, mc, nullptr, h1hi, h1lo,
        72, 72, 256, 9);

    // ---------------- enc2 ----------------
    maskconv_kernel<5, 2, false><<<cdiv(N * 36 * 36, 256), 256, 0, stream>>>(
        nm1, 72, 72, mc, nm2, N, 72, 72, 36, 36);
    conv_enc<5, 2, 8, 8, 2, false, EPI_F32><<<dim3(25, 2, N), 512, 0, stream>>>(
        h1hi, h1lo, 256, 72, 72, nm1,
        Whi + WL[1].ofs, Wlo + WL[1].ofs, mc, nullptr, ybuf, nullptr,
        36, 36, 512, 5);
    bn_stats_kernel<<<512, 256, 0, stream>>>(ybuf, N, 512, 1296, bmean, bistd);
    bn_apply_blk<<<dim3(cdiv(1296, 64), 16, N), 256, 0, stream>>>(
        ybuf, bmean, bistd, enc2g, enc2b, h2shi, h2slo, h2f, 512, 1296, ACT_RELU);

    // ---------------- NLM swap ----------------
    nlm_trans<<<dim3(41, 16, N), 256, 0, stream>>>(h2f, xTp);
    nlm_sq2<<<dim3(6, N), 256, 0, stream>>>(h2f, sqb);
    hipMemsetAsync(mcnt, 0, 8 * sizeof(int), stream);
    nlm_compact<<<N, 256, 0, stream>>>(nm2, mlist, mcnt);
    nlm_gather<<<dim3(64, N), 256, 0, stream>>>(xTp, mlist, mcnt, Phi, Plo);
    nlm_gemm1<<<dim3(11, 2, N), 512, 0, stream>>>(xTp, Phi, Plo, mcnt, Smat);
    nlm_row<<<dim3(NLM_MAXM, N), 256, 0, stream>>>(Smat, sqb, nm2, mlist, mcnt,
                                                   W2hi, W2lo, sumw, 1.f / 25.f);
    nlm_gemm2<<<dim3(4, 2, N), 512, 0, stream>>>(xTp, W2hi, W2lo, mcnt, sumw,
                                                 mlist, h2shi, h2slo);

    // ---------------- enc3 ----------------
    maskconv_kernel<3, 2, false><<<cdiv(N * 18 * 18, 256), 256, 0, stream>>>(
        nm2, 36, 36, mc, nm3, N, 36, 36, 18, 18);
    conv_enc<3, 2, 4, 8, 1, false, EPI_F32><<<dim3(15, 2, N), 512, 0, stream>>>(
        h2shi, h2slo, 512, 36, 36, nm2,
        Whi + WL[2].ofs, Wlo + WL[2].ofs, mc, nullptr, ybuf, nullptr,
        18, 18, 512, 3);
    bn_stats_kernel<<<512, 256, 0, stream>>>(ybuf, N, 512, 324, bmean, bistd);
    bn_apply_blk<<<dim3(cdiv(324, 64), 16, N), 256, 0, stream>>>(
        ybuf, bmean, bistd, enc3g, enc3b, h3hi, h3lo, nullptr, 512, 324, ACT_RELU);

    // ---------------- enc4 ----------------
    maskconv_kernel<3, 2, false><<<cdiv(N * 9 * 9, 256), 256, 0, stream>>>(
        nm3, 18, 18, mc, nm4, N, 18, 18, 9, 9);
    conv_enc<3, 2, 4, 8, 1, false, EPI_F32><<<dim3(6, 2, N), 512, 0, stream>>>(
        h3hi, h3lo, 512, 18, 18, nm3,
        Whi + WL[3].ofs, Wlo + WL[3].ofs, mc, nullptr, ybuf, nullptr,
        9, 9, 512, 2);
    bn_stats_kernel<<<512, 256, 0, stream>>>(ybuf, N, 512, 81, bmean, bistd);
    bn_apply_blk<<<dim3(cdiv(81, 64), 16, N), 256, 0, stream>>>(
        ybuf, bmean, bistd, enc4g, enc4b, h4hi, h4lo, nullptr, 512, 81, ACT_RELU);

    // ---------------- dec4 ----------------
    maskconv_kernel<3, 1, true><<<cdiv(N * 18 * 18, 256), 256, 0, stream>>>(
        nm4, 9, 9, mc, nmd4, N, 18, 18, 18, 18);
    conv3x3<8, 8, 2, false, EPI_F32><<<dim3(9, 4, N), 512, 0, stream>>>(
        h4hi, h4lo, 512, 9, 9, h3hi, h3lo, 512, nm4,
        Whi + WL[4].ofs, Wlo + WL[4].ofs, mc, nullptr, ybuf,
        18, 18, 512, 3);
    bn_stats_kernel<<<512, 256, 0, stream>>>(ybuf, N, 512, 324, bmean, bistd);
    bn_apply_blk<<<dim3(cdiv(324, 64), 16, N), 256, 0, stream>>>(
        ybuf, bmean, bistd, dec4g, dec4b, d4hi, d4lo, nullptr, 512, 324, ACT_LEAKY);

    // ---------------- dec3 ----------------
    maskconv_kernel<3, 1, true><<<cdiv(N * 36 * 36, 256), 256, 0, stream>>>(
        nmd4, 18, 18, mc, nmd3, N, 36, 36, 36, 36);
    conv3x3<8, 12, 3, false, EPI_F32><<<dim3(15, 4, N), 512, 0, stream>>>(
        d4hi, d4lo, 512, 18, 18, h2shi, h2slo, 512, nmd4,
        Whi + WL[5].ofs, Wlo + WL[5].ofs, mc, nullptr, ybuf,
        36, 36, 512, 3);
    bn_stats_kernel<<<512, 256, 0, stream>>>(ybuf, N, 512, 1296, bmean, bistd);
    bn_apply_blk<<<dim3(cdiv(1296, 64), 16, N), 256, 0, stream>>>(
        ybuf, bmean, bistd, dec3g, dec3b, d3hi, d3lo, nullptr, 512, 1296, ACT_LEAKY);

    // ---------------- dec2 ----------------
    maskconv_kernel<3, 1, true><<<cdiv(N * 72 * 72, 256), 256, 0, stream>>>(
        nmd3, 36, 36, mc, nmd2, N, 72, 72, 72, 72);
    conv3x3<8, 16, 4, false, EPI_F32><<<dim3(45, 2, N), 512, 0, stream>>>(
        d3hi, d3lo, 512, 36, 36, h1hi, h1lo, 256, nmd3,
        Whi + WL[6].ofs, Wlo + WL[6].ofs, mc, nullptr, ybuf,
        72, 72, 256, 5);
    bn_stats_kernel<<<256, 256, 0, stream>>>(ybuf, N, 256, 5184, bmean, bistd);
    bn_apply_blk<<<dim3(cdiv(5184, 64), 8, N), 256, 0, stream>>>(
        ybuf, bmean, bistd, dec2g, dec2b, d2hi, d2lo, nullptr, 256, 5184, ACT_LEAKY);

    // ---------------- dec1: cat[up2(d2), x0] -> d_out (x0 planes now dead) ----------------
    maskconv_kernel<3, 1, true><<<cdiv(N * 144 * 144, 256), 256, 0, stream>>>(
        nmd2, 72, 72, mc, nmx, N, 144, 144, 144, 144);
    conv3x3<8, 16, 4, true, EPI_F32_BIAS><<<dim3(162, 1, N), 512, 0, stream>>>(
        d2hi, d2lo, 256, 72, 72, x0, nullptr, 128, nmd2,
        Whi + WL[7].ofs, Wlo + WL[7].ofs, mc, dec1b, outp,
        144, 144, 128, 9);
}

// Round 14
// 2752.348 us; speedup vs baseline: 1.0211x; 1.0016x over previous
//
#include <hip/hip_runtime.h>
#include <math.h>

#define ACT_NONE 0
#define ACT_RELU 1
#define ACT_LEAKY 2

#define EPI_F32 0
#define EPI_PAIR_RELU 1
#define EPI_F32_BIAS 2

typedef __attribute__((ext_vector_type(8))) short short8;
typedef __attribute__((ext_vector_type(8))) __bf16 bf16x8;
typedef __attribute__((ext_vector_type(4))) float f32x4;
typedef __attribute__((ext_vector_type(4))) unsigned uint4v;

__device__ __forceinline__ float actf(float y, int act) {
    if (act == ACT_RELU)  return y > 0.f ? y : 0.f;
    if (act == ACT_LEAKY) return y >= 0.f ? y : 0.2f * y;
    return y;
}

// ---- bf16 split helpers ----
__device__ __forceinline__ unsigned f2bf_rne(float f) {
    unsigned u = __float_as_uint(f);
    return (u + 0x7FFFu + ((u >> 16) & 1u)) >> 16;
}
__device__ __forceinline__ float bf2f(unsigned h) { return __uint_as_float(h << 16); }
__device__ __forceinline__ unsigned splitpack(float f) {
    unsigned hi = f2bf_rne(f);
    float r = f - bf2f(hi);
    unsigned lo = f2bf_rne(r);
    return (hi & 0xFFFFu) | (lo << 16);
}

__device__ __forceinline__ f32x4 mfma16(short8 a, short8 b, f32x4 c) {
    return __builtin_amdgcn_mfma_f32_16x16x32_bf16(
        __builtin_bit_cast(bf16x8, a), __builtin_bit_cast(bf16x8, b), c, 0, 0, 0);
}

// blocked-plane address (u16 units): [img][c/32][HW pix][c%32]
__device__ __forceinline__ size_t paddr(int img, int KBc, size_t HW, size_t pix) {
    return ((size_t)img * KBc * HW + pix) * 32;
}

// ---------------------------------------------------------------------------
// Mask convolution
// ---------------------------------------------------------------------------
template<int K, int S, bool MHALF>
__global__ void maskconv_kernel(const float* __restrict__ M, int HM, int WM,
                                float* __restrict__ mc, float* __restrict__ nm,
                                int N, int Hin, int Win, int Hout, int Wout) {
    constexpr int P = (K - 1) / 2;
    int idx = blockIdx.x * blockDim.x + threadIdx.x;
    int total = N * Hout * Wout;
    if (idx >= total) return;
    int wo = idx % Wout;
    int t  = idx / Wout;
    int ho = t % Hout;
    int n  = t / Hout;
    float s = 0.f;
    for (int kh = 0; kh < K; ++kh) {
        int ih = ho * S - P + kh;
        if ((unsigned)ih >= (unsigned)Hin) continue;
        const float* mrow = M + ((size_t)n * HM + (MHALF ? (ih >> 1) : ih)) * WM;
        for (int kw = 0; kw < K; ++kw) {
            int iw = wo * S - P + kw;
            if ((unsigned)iw < (unsigned)Win)
                s += mrow[MHALF ? (iw >> 1) : iw];
        }
    }
    mc[idx] = s;
    nm[idx] = (s == 0.f) ? 0.f : 1.f;
}

// ---------------------------------------------------------------------------
// Weight transform (A-fragment layout bf16 hi/lo)
// ---------------------------------------------------------------------------
__global__ void wtransform(const float* __restrict__ W, short* __restrict__ Whi,
                           short* __restrict__ Wlo, int Cout, int Cin, int Ksz,
                           size_t total) {
    size_t idx = (size_t)blockIdx.x * blockDim.x + threadIdx.x;
    if (idx >= total) return;
    int j = (int)(idx & 7);
    int lane = (int)((idx >> 3) & 63);
    size_t r = idx >> 9;
    int COB = Cout >> 4, KB = Cin >> 5;
    int cob = (int)(r % COB); r /= COB;
    int kb = (int)(r % KB);
    int tap = (int)(r / KB);
    int co = cob * 16 + (lane & 15);
    int ci = kb * 32 + (lane >> 4) * 8 + j;
    float f = W[((size_t)co * Cin + ci) * Ksz + tap];
    unsigned hi = f2bf_rne(f);
    float rr = f - bf2f(hi);
    unsigned lo = f2bf_rne(rr);
    Whi[idx] = (short)hi;
    Wlo[idx] = (short)lo;
}

// ---------------------------------------------------------------------------
// f32 NCHW -> blocked hi/lo planes (LDS-tiled transpose, both sides coalesced)
// grid: (cdiv(HW,64), C/32, N), 256 threads
// ---------------------------------------------------------------------------
__global__ __launch_bounds__(256) void split_planes(
    const float* __restrict__ x, short* __restrict__ hi, short* __restrict__ lo,
    int C, int HW) {
    __shared__ float tile[32][65];
    const int img = blockIdx.z, kb = blockIdx.y;
    const int px0 = blockIdx.x * 64;
    const int tid = threadIdx.x;
    const int KBc = C >> 5;
    for (int i = tid; i < 32 * 64; i += 256) {
        const int ch = i >> 6, px = i & 63;
        float v = 0.f;
        if (px0 + px < HW)
            v = x[((size_t)img * C + kb * 32 + ch) * HW + px0 + px];
        tile[ch][px] = v;
    }
    __syncthreads();
    const int px = tid >> 2, sg = tid & 3;
    if (px0 + px < HW) {
        short8 h8, l8;
#pragma unroll
        for (int j = 0; j < 8; ++j) {
            float v = tile[sg * 8 + j][px];
            unsigned h16 = f2bf_rne(v);
            float rr = v - bf2f(h16);
            h8[j] = (short)h16;
            l8[j] = (short)f2bf_rne(rr);
        }
        const size_t a = (((size_t)img * KBc + kb) * HW + px0 + px) * 32 + sg * 8;
        *(short8*)&hi[a] = h8;
        *(short8*)&lo[a] = l8;
    }
}

// ---------------------------------------------------------------------------
// Encoder halo-staged stride-2 conv. A-source: blocked planes (or f32 if AF32).
// ---------------------------------------------------------------------------
template<int K, int S, int TH, int TW, int NFW, bool AF32, int EPI>
__global__ __launch_bounds__(512) void conv_enc(
    const void* __restrict__ Ahi, const void* __restrict__ Alo,
    int Cin, int Hin, int Win,
    const float* __restrict__ M,
    const short* __restrict__ Whi, const short* __restrict__ Wlo,
    const float* __restrict__ mc, const float* __restrict__ bias,
    void* __restrict__ outp, void* __restrict__ outp2,
    int Hout, int Wout, int Cout, int TX)
{
    static_assert(S == 2, "parity layout assumes stride 2");
    constexpr int P = (K - 1) / 2;
    constexpr int HH  = (TH - 1) * S + K;
    constexpr int HWC = (TW - 1) * S + K;
    constexpr int PXC = HH * HWC;
    static_assert(PXC <= 512, "one halo pixel per thread");
    constexpr int PW  = (HWC + 1) / 2;
    constexpr int PXC2 = HH * PW * 2;
    constexpr int PXC2P = PXC2 + ((2 - (PXC2 % 8) + 8) % 8);   // bank-phase pad
    __shared__ __align__(16) short BHs[4 * PXC2P * 8];
    __shared__ __align__(16) short BLs[4 * PXC2P * 8];

    const int t    = threadIdx.x;
    const int lane = t & 63;
    const int wv   = t >> 6;
    const int wm   = wv >> 1;
    const int wn   = wv & 1;
    const int img  = blockIdx.z;
    const int coB  = blockIdx.y * 256;
    const int tile = blockIdx.x;
    const int ty   = tile / TX, tx = tile - ty * TX;
    const int oy0  = ty * TH, ox0 = tx * TW;
    const int KB   = Cin >> 5;
    const int COB  = Cout >> 4;
    const size_t HW = (size_t)Hin * Win;
    const int g  = lane >> 4;
    const int pl = lane & 15;

    // staging descriptor (once)
    bool sel = false;
    size_t basef = 0, basep = 0;
    int qq = 0;
    if (t < PXC) {
        const int r = t / HWC, c = t - r * HWC;
        qq = r * PW + (c >> 1) + (c & 1) * (HH * PW);
        const int iy = oy0 * S - P + r;
        const int ix = ox0 * S - P + c;
        if ((unsigned)iy < (unsigned)Hin && (unsigned)ix < (unsigned)Win) {
            const size_t pix = (size_t)iy * Win + ix;
            if (M[(size_t)img * HW + pix] != 0.f) {
                sel = true;
                basef = (size_t)img * Cin * HW + pix;
                basep = paddr(img, KB, HW, pix);
            }
        }
    }

    short8 hv[4], lv[4];
    auto prefetch = [&](int kb) {
#pragma unroll
        for (int gg = 0; gg < 4; ++gg) {
            if (sel) {
                if (AF32) {
                    const float* s = (const float*)Ahi + basef + (size_t)(kb * 32 + gg * 8) * HW;
#pragma unroll
                    for (int j = 0; j < 8; ++j) {
                        float f = s[(size_t)j * HW];
                        unsigned h16 = f2bf_rne(f);
                        float rr = f - bf2f(h16);
                        hv[gg][j] = (short)h16;
                        lv[gg][j] = (short)f2bf_rne(rr);
                    }
                } else {
                    const size_t a = basep + (size_t)kb * HW * 32 + gg * 8;
                    hv[gg] = *(const short8*)((const short*)Ahi + a);
                    lv[gg] = *(const short8*)((const short*)Alo + a);
                }
            } else {
#pragma unroll
                for (int j = 0; j < 8; ++j) { hv[gg][j] = 0; lv[gg][j] = 0; }
            }
        }
    };

    f32x4 acc[4][NFW] = {};
    if (t < PXC) prefetch(0);

#pragma unroll 1
    for (int kb = 0; kb < KB; ++kb) {
        if (t < PXC) {
#pragma unroll
            for (int gg = 0; gg < 4; ++gg) {
                *(short8*)&BHs[(gg * PXC2P + qq) * 8] = hv[gg];
                *(short8*)&BLs[(gg * PXC2P + qq) * 8] = lv[gg];
            }
        }
        __syncthreads();
        if (t < PXC && kb + 1 < KB) prefetch(kb + 1);

#pragma unroll 1
        for (int kh = 0; kh < K; ++kh)
#pragma unroll 1
        for (int kw = 0; kw < K; ++kw) {
            const int tap = kh * K + kw;
            const size_t wb = (((size_t)tap * KB + kb) * COB + (coB >> 4) + wm * 4) * 512
                            + (size_t)lane * 8;
            short8 ah[4], al[4];
#pragma unroll
            for (int fm = 0; fm < 4; ++fm) {
                ah[fm] = *(const short8*)(Whi + wb + (size_t)fm * 512);
                al[fm] = *(const short8*)(Wlo + wb + (size_t)fm * 512);
            }
            __builtin_amdgcn_s_setprio(1);
#pragma unroll
            for (int fn = 0; fn < NFW; ++fn) {
                const int pxf = (wn * NFW + fn) * 16 + pl;
                const int oy = pxf / TW, ox = pxf - oy * TW;
                const int q2 = (oy * S + kh) * PW + ox + (kw >> 1) + (kw & 1) * (HH * PW);
                short8 bh = *(const short8*)&BHs[(g * PXC2P + q2) * 8];
                short8 bl = *(const short8*)&BLs[(g * PXC2P + q2) * 8];
#pragma unroll
                for (int fm = 0; fm < 4; ++fm) {
                    acc[fm][fn] = mfma16(ah[fm], bh, acc[fm][fn]);
                    acc[fm][fn] = mfma16(al[fm], bh, acc[fm][fn]);
                    acc[fm][fn] = mfma16(ah[fm], bl, acc[fm][fn]);
                }
            }
            __builtin_amdgcn_s_setprio(0);
        }
        __syncthreads();
    }

    const int Npix = Hout * Wout;
    const float* mcb = mc + (size_t)img * Npix;
#pragma unroll
    for (int fm = 0; fm < 4; ++fm)
#pragma unroll
    for (int fn = 0; fn < NFW; ++fn) {
        const int co = coB + (wm * 4 + fm) * 16 + (lane >> 4) * 4;
        const int pxf = (wn * NFW + fn) * 16 + (lane & 15);
        const int oy = pxf / TW, ox = pxf - oy * TW;
        const int gy = oy0 + oy, gx = ox0 + ox;
        if (gy >= Hout || gx >= Wout) continue;
        const size_t pix = (size_t)gy * Wout + gx;
        const float m = mcb[pix];
        f32x4 a = acc[fm][fn];
#pragma unroll
        for (int r = 0; r < 4; ++r) {
            float y = a[r];
            if (EPI == EPI_F32_BIAS) {
                const float bv = bias[co + r];
                y = (m == 0.f) ? 0.f : (y - bv) / m + bv;
            } else {
                y = (m == 0.f) ? 0.f : y / m;
            }
            if (EPI == EPI_PAIR_RELU) {
                y = y > 0.f ? y : 0.f;
                const size_t pa = paddr(img, Cout >> 5, Npix, pix)
                                + (size_t)(co >> 5) * Npix * 32 + (co & 31) + r;
                unsigned h16 = f2bf_rne(y);
                float rr = y - bf2f(h16);
                ((short*)outp)[pa]  = (short)h16;
                ((short*)outp2)[pa] = (short)f2bf_rne(rr);
            } else {
                ((float*)outp)[((size_t)img * Cout + co + r) * Npix + pix] = y;
            }
        }
    }
}

// ---------------------------------------------------------------------------
// Decoder 3x3 s1 p1: 8 waves, MFW=2 (4m x 2n), NPIX=32*NFW, blocked-plane IO.
// ---------------------------------------------------------------------------
template<int TH, int TW, int NFW, bool BF32, int EPI>
__global__ __launch_bounds__(512) void conv3x3(
    const void* __restrict__ Ahi, const void* __restrict__ Alo,
    int CA, int HA, int WA,
    const void* __restrict__ Bhi, const void* __restrict__ Blo, int CB,
    const float* __restrict__ M,
    const short* __restrict__ Whi, const short* __restrict__ Wlo,
    const float* __restrict__ mc, const float* __restrict__ bias,
    void* __restrict__ outp,
    int Hout, int Wout, int Cout, int TX)
{
    constexpr int HALO_H = TH + 2, HALO_W = TW + 2, HALO = HALO_H * HALO_W;
    constexpr int HALOP = HALO + ((2 - (HALO % 8) + 8) % 8);   // bank-phase pad
    constexpr int NPIX = TH * TW;
    constexpr int SITER = (HALO + 127) / 128;
    static_assert(NPIX == 32 * NFW, "tile must be exactly 32*NFW pixels");
    __shared__ __align__(16) short BHs[4 * HALOP * 8];
    __shared__ __align__(16) short BLs[4 * HALOP * 8];

    const int t    = threadIdx.x;
    const int lane = t & 63;
    const int wv   = t >> 6;
    const int wm   = wv >> 1;
    const int wn   = wv & 1;
    const int img  = blockIdx.z;
    const int coB  = blockIdx.y * 128;
    const int tile = blockIdx.x;
    const int ty   = tile / TX;
    const int tx   = tile - ty * TX;
    const int oy0  = ty * TH, ox0 = tx * TW;
    const int Cin  = CA + CB;
    const int KB   = Cin >> 5;
    const int KBA  = CA >> 5;
    const int KBB  = CB >> 5;
    const int COB  = Cout >> 4;
    const int WM   = Wout >> 1;
    const size_t HWA = (size_t)HA * WA;
    const size_t HWB = (size_t)Hout * Wout;

    const int sg = t >> 7;
    const int st = t & 127;
    const int g  = lane >> 4;
    const int pl = lane & 15;

    // staging descriptors (once)
    bool ssel[SITER];
    size_t aoff[SITER], boff[SITER];
#pragma unroll
    for (int i = 0; i < SITER; ++i) {
        ssel[i] = false; aoff[i] = 0; boff[i] = 0;
        const int q = st + i * 128;
        if (q < HALO) {
            const int hy = q / HALO_W, hx = q - hy * HALO_W;
            const int iy = oy0 - 1 + hy, ix = ox0 - 1 + hx;
            if ((unsigned)iy < (unsigned)Hout && (unsigned)ix < (unsigned)Wout) {
                if (M[((size_t)img * (Hout >> 1) + (iy >> 1)) * WM + (ix >> 1)] != 0.f) {
                    ssel[i] = true;
                    const size_t pixA = (size_t)(iy >> 1) * WA + (ix >> 1);
                    const size_t pixB = (size_t)iy * Wout + ix;
                    aoff[i] = paddr(img, KBA, HWA, pixA) + sg * 8;
                    if (BF32) boff[i] = (size_t)img * CB * HWB + pixB;     // f32 elem base
                    else      boff[i] = paddr(img, KBB, HWB, pixB) + sg * 8;
                }
            }
        }
    }

    short8 hv[SITER], lv[SITER];
    auto prefetch = [&](int kb) {
        const int c = kb * 32 + sg * 8;
#pragma unroll
        for (int i = 0; i < SITER; ++i) {
            const int q = st + i * 128;
            bool ok = (q < HALO) && ssel[i];
            if (ok) {
                if (c < CA) {
                    const size_t a = aoff[i] + (size_t)kb * HWA * 32;
                    hv[i] = *(const short8*)((const short*)Ahi + a);
                    lv[i] = *(const short8*)((const short*)Alo + a);
                } else {
                    if (BF32) {
                        const float* s = (const float*)Bhi + boff[i] + (size_t)(c - CA) * HWB;
#pragma unroll
                        for (int j = 0; j < 8; ++j) {
                            float f = s[(size_t)j * HWB];
                            unsigned h16 = f2bf_rne(f);
                            float rr = f - bf2f(h16);
                            hv[i][j] = (short)h16;
                            lv[i][j] = (short)f2bf_rne(rr);
                        }
                    } else {
                        const size_t a = boff[i] + (size_t)(kb - KBA) * HWB * 32;
                        hv[i] = *(const short8*)((const short*)Bhi + a);
                        lv[i] = *(const short8*)((const short*)Blo + a);
                    }
                }
            } else {
#pragma unroll
                for (int j = 0; j < 8; ++j) { hv[i][j] = 0; lv[i][j] = 0; }
            }
        }
    };

    f32x4 acc[2][NFW] = {};
    const size_t wstride = (size_t)KB * COB * 512;
    prefetch(0);

#pragma unroll 1
    for (int kb = 0; kb < KB; ++kb) {
#pragma unroll
        for (int i = 0; i < SITER; ++i) {
            const int q = st + i * 128;
            if (q < HALO) {
                *(short8*)&BHs[(sg * HALOP + q) * 8] = hv[i];
                *(short8*)&BLs[(sg * HALOP + q) * 8] = lv[i];
            }
        }
        __syncthreads();
        if (kb + 1 < KB) prefetch(kb + 1);

        size_t wb = ((size_t)kb * COB + (coB >> 4) + wm * 2) * 512 + lane * 8;
#pragma unroll 1
        for (int tap = 0; tap < 9; ++tap) {
            const int dh = tap / 3, dw = tap - dh * 3;
            short8 ah0 = *(const short8*)(Whi + wb);
            short8 ah1 = *(const short8*)(Whi + wb + 512);
            short8 al0 = *(const short8*)(Wlo + wb);
            short8 al1 = *(const short8*)(Wlo + wb + 512);
            __builtin_amdgcn_s_setprio(1);
#pragma unroll
            for (int fn = 0; fn < NFW; ++fn) {
                const int pxf = (wn * NFW + fn) * 16 + pl;
                const int oy = pxf / TW, ox = pxf - oy * TW;
                const int hpx = (oy + dh) * HALO_W + (ox + dw);
                short8 bh = *(const short8*)&BHs[(g * HALOP + hpx) * 8];
                short8 bl = *(const short8*)&BLs[(g * HALOP + hpx) * 8];
                acc[0][fn] = mfma16(ah0, bh, acc[0][fn]);
                acc[1][fn] = mfma16(ah1, bh, acc[1][fn]);
                acc[0][fn] = mfma16(al0, bh, acc[0][fn]);
                acc[1][fn] = mfma16(al1, bh, acc[1][fn]);
                acc[0][fn] = mfma16(ah0, bl, acc[0][fn]);
                acc[1][fn] = mfma16(ah1, bl, acc[1][fn]);
            }
            __builtin_amdgcn_s_setprio(0);
            wb += wstride;
        }
        __syncthreads();
    }

    const float* mcb = mc + (size_t)img * HWB;
#pragma unroll
    for (int fm = 0; fm < 2; ++fm)
#pragma unroll
    for (int fn = 0; fn < NFW; ++fn) {
        const int co = coB + (wm * 2 + fm) * 16 + (lane >> 4) * 4;
        const int pxf = (wn * NFW + fn) * 16 + (lane & 15);
        const int oy = pxf / TW, ox = pxf - oy * TW;
        const int gy = oy0 + oy, gx = ox0 + ox;
        if (gy >= Hout || gx >= Wout) continue;
        const float m = mcb[(size_t)gy * Wout + gx];
        f32x4 a = acc[fm][fn];
#pragma unroll
        for (int r = 0; r < 4; ++r) {
            float y = a[r];
            if (EPI == EPI_F32_BIAS) {
                const float bv = bias[co + r];
                y = (m == 0.f) ? 0.f : (y - bv) / m + bv;
            } else {
                y = (m == 0.f) ? 0.f : y / m;
            }
            ((float*)outp)[((size_t)img * Cout + co + r) * HWB + (size_t)gy * Wout + gx] = y;
        }
    }
}

// ---------------------------------------------------------------------------
// BatchNorm stats
// ---------------------------------------------------------------------------
__global__ __launch_bounds__(256) void bn_stats_kernel(const float* __restrict__ y,
                                                       int N, int C, int HW,
                                                       float* __restrict__ mean,
                                                       float* __restrict__ istd) {
    const int c = blockIdx.x;
    double s = 0.0, s2 = 0.0;
    const int tot = N * HW;
    for (int i = threadIdx.x; i < tot; i += blockDim.x) {
        int n = i / HW, hw = i - n * HW;
        float v = y[((size_t)n * C + c) * HW + hw];
        s += v;
        s2 += (double)v * v;
    }
    __shared__ double sh[256], sh2[256];
    sh[threadIdx.x] = s; sh2[threadIdx.x] = s2;
    __syncthreads();
    for (int o = 128; o > 0; o >>= 1) {
        if (threadIdx.x < o) { sh[threadIdx.x] += sh[threadIdx.x + o]; sh2[threadIdx.x] += sh2[threadIdx.x + o]; }
        __syncthreads();
    }
    if (threadIdx.x == 0) {
        double mu = sh[0] / tot;
        double var = sh2[0] / tot - mu * mu;
        mean[c] = (float)mu;
        istd[c] = (float)(1.0 / sqrt(var + 1e-5));
    }
}

// ---------------------------------------------------------------------------
// BN apply + act -> blocked hi/lo planes (LDS-tiled transpose)
// ---------------------------------------------------------------------------
__global__ __launch_bounds__(256) void bn_apply_blk(
    const float* __restrict__ y,
    const float* __restrict__ mean, const float* __restrict__ istd,
    const float* __restrict__ g, const float* __restrict__ b,
    short* __restrict__ hi, short* __restrict__ lo, float* __restrict__ fout,
    int C, int HW, int act) {
    __shared__ float tile[32][65];
    const int img = blockIdx.z, kb = blockIdx.y;
    const int px0 = blockIdx.x * 64;
    const int tid = threadIdx.x;
    const int KBc = C >> 5;

    for (int i = tid; i < 32 * 64; i += 256) {
        const int ch = i >> 6, px = i & 63;
        float v = 0.f;
        if (px0 + px < HW)
            v = y[((size_t)img * C + kb * 32 + ch) * HW + px0 + px];
        tile[ch][px] = v;
    }
    __syncthreads();

    const int px = tid >> 2, sg = tid & 3;
    if (px0 + px < HW) {
        short8 h8, l8;
        float f8[8];
#pragma unroll
        for (int j = 0; j < 8; ++j) {
            const int c = kb * 32 + sg * 8 + j;
            float v = tile[sg * 8 + j][px];
            v = (v - mean[c]) * istd[c] * g[c] + b[c];
            v = actf(v, act);
            f8[j] = v;
            unsigned h16 = f2bf_rne(v);
            float rr = v - bf2f(h16);
            h8[j] = (short)h16;
            l8[j] = (short)f2bf_rne(rr);
        }
        const size_t a = (((size_t)img * KBc + kb) * HW + px0 + px) * 32 + sg * 8;
        *(short8*)&hi[a] = h8;
        *(short8*)&lo[a] = l8;
        if (fout) {
#pragma unroll
            for (int j = 0; j < 8; ++j)
                fout[((size_t)img * C + kb * 32 + sg * 8 + j) * HW + px0 + px] = f8[j];
        }
    }
}

// ---------------------------------------------------------------------------
// NLM (MFMA formulation; xTp stays packed-u32; gemm2 writes blocked planes)
// ---------------------------------------------------------------------------
#define NLM_C 512
#define NLM_N 1296
#define NLM_MAXM 256
#define NLM_RT 16
#define NLM_KB1 16
#define NLM_KB2 41
#define NLM_PFRAG (NLM_KB1 * NLM_RT * 512)
#define NLM_WFRAG (NLM_KB2 * NLM_RT * 512)

__global__ __launch_bounds__(256) void nlm_trans(const float* __restrict__ h2f,
                                                 unsigned* __restrict__ xTp) {
    __shared__ float tile[32][33];
    const int b = blockIdx.z;
    const int j0 = blockIdx.x * 32, c0 = blockIdx.y * 32;
    const int tx = threadIdx.x & 31, ty = threadIdx.x >> 5;
    for (int cc = ty; cc < 32; cc += 8) {
        const int j = j0 + tx;
        tile[cc][tx] = (j < NLM_N) ? h2f[((size_t)b * NLM_C + c0 + cc) * NLM_N + j] : 0.f;
    }
    __syncthreads();
    for (int jj = ty; jj < 32; jj += 8) {
        const int j = j0 + jj;
        if (j < NLM_N)
            xTp[((size_t)b * NLM_N + j) * NLM_C + c0 + tx] = splitpack(tile[tx][jj]);
    }
}

__global__ void nlm_sq2(const float* __restrict__ h2f, float* __restrict__ sq) {
    const int b = blockIdx.y;
    const int j = blockIdx.x * 256 + threadIdx.x;
    if (j >= NLM_N) return;
    const float* p = h2f + (size_t)b * NLM_C * NLM_N + j;
    float s0 = 0.f, s1 = 0.f, s2 = 0.f, s3 = 0.f;
    for (int c = 0; c < NLM_C; c += 4) {
        float v0 = p[(size_t)c * NLM_N];
        float v1 = p[(size_t)(c + 1) * NLM_N];
        float v2 = p[(size_t)(c + 2) * NLM_N];
        float v3 = p[(size_t)(c + 3) * NLM_N];
        s0 = fmaf(v0, v0, s0); s1 = fmaf(v1, v1, s1);
        s2 = fmaf(v2, v2, s2); s3 = fmaf(v3, v3, s3);
    }
    sq[b * NLM_N + j] = (s0 + s1) + (s2 + s3);
}

__global__ void nlm_compact(const float* __restrict__ nm2, int* __restrict__ list,
                            int* __restrict__ cnt) {
    const int b = blockIdx.x;
    for (int j = threadIdx.x; j < NLM_N; j += 256) {
        if (nm2[(size_t)b * NLM_N + j] == 0.f) {
            int pos = atomicAdd(&cnt[b], 1);
            if (pos < NLM_MAXM) list[b * NLM_MAXM + pos] = j;
        }
    }
}

__global__ void nlm_gather(const unsigned* __restrict__ xTp, const int* __restrict__ list,
                           const int* __restrict__ cnt,
                           short* __restrict__ Phi, short* __restrict__ Plo) {
    const int b = blockIdx.y;
    const int id = blockIdx.x * 256 + threadIdx.x;
    const int i  = id >> 6;
    const int rem = id & 63;
    const int kb = rem >> 2, kg = rem & 3;
    const int lane = kg * 16 + (i & 15), rt = i >> 4;
    const size_t f = (size_t)b * NLM_PFRAG + ((size_t)(kb * NLM_RT + rt) * 64 + lane) * 8;
    if (i < cnt[b]) {
        const int pix = list[b * NLM_MAXM + i];
        const unsigned* s = xTp + ((size_t)b * NLM_N + pix) * NLM_C + kb * 32 + kg * 8;
#pragma unroll
        for (int jj = 0; jj < 8; ++jj) {
            unsigned v = s[jj];
            Phi[f + jj] = (short)(v & 0xFFFFu);
            Plo[f + jj] = (short)(v >> 16);
        }
    } else {
#pragma unroll
        for (int jj = 0; jj < 8; ++jj) { Phi[f + jj] = 0; Plo[f + jj] = 0; }
    }
}

__global__ __launch_bounds__(512) void nlm_gemm1(
    const unsigned* __restrict__ xTp, const short* __restrict__ Phi,
    const short* __restrict__ Plo, const int* __restrict__ cnt,
    float* __restrict__ S) {
    const int img = blockIdx.z, mt = blockIdx.y, nt = blockIdx.x;
    if (mt * 128 >= cnt[img]) return;
    __shared__ __align__(16) unsigned BH[4 * 128 * 4];
    __shared__ __align__(16) unsigned BL[4 * 128 * 4];
    const int t = threadIdx.x, lane = t & 63, wv = t >> 6, wm = wv >> 1, wn = wv & 1;
    const int j0 = nt * 128;
    const int spx = t & 127, sg = t >> 7;
    f32x4 acc[2][4] = {};
#pragma unroll 1
    for (int kb = 0; kb < NLM_KB1; ++kb) {
        unsigned v[8];
#pragma unroll
        for (int jj = 0; jj < 8; ++jj) v[jj] = 0u;
        const int j = j0 + spx;
        if (j < NLM_N) {
            const unsigned* s = xTp + ((size_t)img * NLM_N + j) * NLM_C + kb * 32 + sg * 8;
#pragma unroll
            for (int jj = 0; jj < 8; ++jj) v[jj] = s[jj];
        }
        uint4v hd, ld;
#pragma unroll
        for (int jj = 0; jj < 4; ++jj) {
            hd[jj] = (v[2 * jj] & 0xFFFFu) | (v[2 * jj + 1] << 16);
            ld[jj] = (v[2 * jj] >> 16) | (v[2 * jj + 1] & 0xFFFF0000u);
        }
        *(uint4v*)&BH[(sg * 128 + spx) * 4] = hd;
        *(uint4v*)&BL[(sg * 128 + spx) * 4] = ld;
        __syncthreads();
        const size_t ab = (size_t)img * NLM_PFRAG
                        + (size_t)(kb * NLM_RT + mt * 8 + wm * 2) * 512 + (size_t)lane * 8;
        short8 ah0 = *(const short8*)(Phi + ab);
        short8 ah1 = *(const short8*)(Phi + ab + 512);
        short8 al0 = *(const short8*)(Plo + ab);
        short8 al1 = *(const short8*)(Plo + ab + 512);
        const int g = lane >> 4, pl = lane & 15;
#pragma unroll
        for (int fn = 0; fn < 4; ++fn) {
            const int px = wn * 64 + fn * 16 + pl;
            short8 bh = *(const short8*)&BH[(g * 128 + px) * 4];
            short8 bl = *(const short8*)&BL[(g * 128 + px) * 4];
            acc[0][fn] = mfma16(ah0, bh, acc[0][fn]);
            acc[1][fn] = mfma16(ah1, bh, acc[1][fn]);
            acc[0][fn] = mfma16(al0, bh, acc[0][fn]);
            acc[1][fn] = mfma16(al1, bh, acc[1][fn]);
            acc[0][fn] = mfma16(ah0, bl, acc[0][fn]);
            acc[1][fn] = mfma16(ah1, bl, acc[1][fn]);
        }
        __syncthreads();
    }
#pragma unroll
    for (int fm = 0; fm < 2; ++fm)
#pragma unroll
    for (int fn = 0; fn < 4; ++fn) {
        const int row = mt * 128 + (wm * 2 + fm) * 16 + (lane >> 4) * 4;
        const int j = j0 + wn * 64 + fn * 16 + (lane & 15);
        if (j >= NLM_N) continue;
        f32x4 a = acc[fm][fn];
#pragma unroll
        for (int r = 0; r < 4; ++r)
            S[((size_t)img * NLM_MAXM + row + r) * NLM_N + j] = a[r];
    }
}

__global__ __launch_bounds__(256) void nlm_row(
    const float* __restrict__ S, const float* __restrict__ sq,
    const float* __restrict__ nm2, const int* __restrict__ list,
    const int* __restrict__ cnt,
    short* __restrict__ W2hi, short* __restrict__ W2lo,
    float* __restrict__ sumw, float inv_h2) {
    const int img = blockIdx.y, i = blockIdx.x;
    if (i >= cnt[img] || i >= NLM_MAXM) return;
    __shared__ float Drow[NLM_N];
    __shared__ float red[256];
    const int tid = threadIdx.x;
    const int pix = list[img * NLM_MAXM + i];
    const float sqi = sq[img * NLM_N + pix];
    const float BIG = 3.4e38f;
    float lmin = BIG;
    for (int j = tid; j < NLM_N; j += 256) {
        float d = BIG;
        if (nm2[(size_t)img * NLM_N + j] != 0.f) {
            float dot = S[((size_t)img * NLM_MAXM + i) * NLM_N + j];
            d = sqi + sq[img * NLM_N + j] - 2.f * dot;
            d = d > 0.f ? d : 0.f;
            lmin = d < lmin ? d : lmin;
        }
        Drow[j] = d;
    }
    red[tid] = lmin;
    __syncthreads();
    for (int o = 128; o > 0; o >>= 1) {
        if (tid < o) red[tid] = fminf(red[tid], red[tid + o]);
        __syncthreads();
    }
    const float dmin = red[0];
    __syncthreads();

    const int rt = i >> 4, lr = i & 15;
    float lsum = 0.f;
    for (int j = tid; j < NLM_KB2 * 32; j += 256) {
        float w = 0.f;
        if (j < NLM_N && Drow[j] < 3.3e38f) {
            w = expf(-(Drow[j] - dmin) * inv_h2);
            lsum += w;
        }
        const unsigned u = splitpack(w);
        const int kb = j >> 5, kg = (j & 31) >> 3, jj = j & 7;
        const int lane = kg * 16 + lr;
        const size_t f = (size_t)img * NLM_WFRAG
                       + ((size_t)(kb * NLM_RT + rt) * 64 + lane) * 8 + jj;
        W2hi[f] = (short)(u & 0xFFFFu);
        W2lo[f] = (short)(u >> 16);
    }
    red[tid] = lsum;
    __syncthreads();
    for (int o = 128; o > 0; o >>= 1) {
        if (tid < o) red[tid] += red[tid + o];
        __syncthreads();
    }
    if (tid == 0) sumw[img * NLM_MAXM + i] = red[0];
}

__global__ __launch_bounds__(512) void nlm_gemm2(
    const unsigned* __restrict__ xTp, const short* __restrict__ W2hi,
    const short* __restrict__ W2lo, const int* __restrict__ cnt,
    const float* __restrict__ sumw, const int* __restrict__ list,
    short* __restrict__ outHi, short* __restrict__ outLo) {
    const int img = blockIdx.z, mt = blockIdx.y, ct = blockIdx.x;
    const int cN = cnt[img] < NLM_MAXM ? cnt[img] : NLM_MAXM;
    if (mt * 128 >= cN) return;
    __shared__ __align__(16) unsigned BH[4 * 128 * 4];
    __shared__ __align__(16) unsigned BL[4 * 128 * 4];
    const int t = threadIdx.x, lane = t & 63, wv = t >> 6, wm = wv >> 1, wn = wv & 1;
    const int c0 = ct * 128;
    const int sc = t & 127, sg = t >> 7;
    f32x4 acc[2][4] = {};
#pragma unroll 1
    for (int kb = 0; kb < NLM_KB2; ++kb) {
        unsigned v[8];
#pragma unroll
        for (int jj = 0; jj < 8; ++jj) {
            const int j = kb * 32 + sg * 8 + jj;
            v[jj] = (j < NLM_N)
                  ? xTp[((size_t)img * NLM_N + j) * NLM_C + c0 + sc] : 0u;
        }
        uint4v hd, ld;
#pragma unroll
        for (int jj = 0; jj < 4; ++jj) {
            hd[jj] = (v[2 * jj] & 0xFFFFu) | (v[2 * jj + 1] << 16);
            ld[jj] = (v[2 * jj] >> 16) | (v[2 * jj + 1] & 0xFFFF0000u);
        }
        *(uint4v*)&BH[(sg * 128 + sc) * 4] = hd;
        *(uint4v*)&BL[(sg * 128 + sc) * 4] = ld;
        __syncthreads();
        const size_t ab = (size_t)img * NLM_WFRAG
                        + (size_t)(kb * NLM_RT + mt * 8 + wm * 2) * 512 + (size_t)lane * 8;
        short8 ah0 = *(const short8*)(W2hi + ab);
        short8 ah1 = *(const short8*)(W2hi + ab + 512);
        short8 al0 = *(const short8*)(W2lo + ab);
        short8 al1 = *(const short8*)(W2lo + ab + 512);
        const int g = lane >> 4, pl = lane & 15;
#pragma unroll
        for (int fn = 0; fn < 4; ++fn) {
            const int px = wn * 64 + fn * 16 + pl;
            short8 bh = *(const short8*)&BH[(g * 128 + px) * 4];
            short8 bl = *(const short8*)&BL[(g * 128 + px) * 4];
            acc[0][fn] = mfma16(ah0, bh, acc[0][fn]);
            acc[1][fn] = mfma16(ah1, bh, acc[1][fn]);
            acc[0][fn] = mfma16(al0, bh, acc[0][fn]);
            acc[1][fn] = mfma16(al1, bh, acc[1][fn]);
            acc[0][fn] = mfma16(ah0, bl, acc[0][fn]);
            acc[1][fn] = mfma16(ah1, bl, acc[1][fn]);
        }
        __syncthreads();
    }
#pragma unroll
    for (int fm = 0; fm < 2; ++fm)
#pragma unroll
    for (int fn = 0; fn < 4; ++fn) {
        const int row = mt * 128 + (wm * 2 + fm) * 16 + (lane >> 4) * 4;
        const int c = c0 + wn * 64 + fn * 16 + (lane & 15);
        f32x4 a = acc[fm][fn];
#pragma unroll
        for (int r = 0; r < 4; ++r) {
            const int ri = row + r;
            if (ri < cN) {
                const float y = a[r] / sumw[img * NLM_MAXM + ri];
                const int pix = list[img * NLM_MAXM + ri];
                const size_t pa = (((size_t)img * (NLM_C >> 5) + (c >> 5)) * NLM_N + pix) * 32
                                + (c & 31);
                unsigned h16 = f2bf_rne(y);
                float rr = y - bf2f(h16);
                outHi[pa] = (short)h16;
                outLo[pa] = (short)f2bf_rne(rr);
            }
        }
    }
}

// ---------------------------------------------------------------------------
// Driver
// ---------------------------------------------------------------------------
extern "C" void kernel_launch(void* const* d_in, const int* in_sizes, int n_in,
                              void* d_out, int out_size, void* d_ws, size_t ws_size,
                              hipStream_t stream) {
    const float* x0    = (const float*)d_in[0];
    const float* m0    = (const float*)d_in[1];
    const float* Wsrc[8] = {
        (const float*)d_in[2], (const float*)d_in[3], (const float*)d_in[4],
        (const float*)d_in[5], (const float*)d_in[6], (const float*)d_in[7],
        (const float*)d_in[8], (const float*)d_in[9]
    };
    const float* dec1b = (const float*)d_in[10];
    const float* enc2g = (const float*)d_in[11];
    const float* enc2b = (const float*)d_in[12];
    const float* enc3g = (const float*)d_in[13];
    const float* enc3b = (const float*)d_in[14];
    const float* enc4g = (const float*)d_in[15];
    const float* enc4b = (const float*)d_in[16];
    const float* dec4g = (const float*)d_in[17];
    const float* dec4b = (const float*)d_in[18];
    const float* dec3g = (const float*)d_in[19];
    const float* dec3b = (const float*)d_in[20];
    const float* dec2g = (const float*)d_in[21];
    const float* dec2b = (const float*)d_in[22];
    float* outp = (float*)d_out;

    const int N = 8;
    float* ws = (float*)d_ws;
    size_t off = 0;
    auto alloc = [&](size_t nf) {
        size_t o = off;
        off += ((nf + 63) / 64) * 64;
        return ws + o;
    };
    auto allocPair = [&](size_t E, short** hi, short** lo) {
        float* p = alloc(E);
        *hi = (short*)p;
        *lo = (short*)p + E;
    };

    short *h1hi, *h1lo, *h2shi, *h2slo, *h3hi, *h3lo, *h4hi, *h4lo, *d4hi, *d4lo;
    allocPair(10616832, &h1hi, &h1lo);   // 8x256x72x72  (later d2 planes)
    allocPair(5308416, &h2shi, &h2slo);  // 8x512x36x36  (later d3 planes)
    allocPair(1327104, &h3hi, &h3lo);    // 8x512x18x18
    allocPair(331776, &h4hi, &h4lo);     // 8x512x9x9
    allocPair(1327104, &d4hi, &d4lo);
    float* ybuf = alloc(10616832);
    float* h2f  = alloc(5308416);
    unsigned* xTp = (unsigned*)alloc(5308416);
    float* sqb  = alloc(10368);
    float* mc   = alloc(165888);
    float* nm1  = alloc(41472);
    float* nm2  = alloc(10368);
    float* nm3  = alloc(2592);
    float* nm4  = alloc(648);
    float* nmd4 = alloc(2592);
    float* nmd3 = alloc(10368);
    float* nmd2 = alloc(41472);
    float* nmx  = alloc(165888);
    float* bmean = alloc(512);
    float* bistd = alloc(512);
    short* Whi = (short*)alloc(10625024);
    short* Wlo = (short*)alloc(10625024);
    float* Smat = alloc((size_t)8 * NLM_MAXM * NLM_N);
    float* Phi_  = alloc((size_t)8 * NLM_PFRAG / 2);
    float* Plo_  = alloc((size_t)8 * NLM_PFRAG / 2);
    float* W2hi_ = alloc((size_t)8 * NLM_WFRAG / 2);
    float* W2lo_ = alloc((size_t)8 * NLM_WFRAG / 2);
    short* Phi = (short*)Phi_;  short* Plo = (short*)Plo_;
    short* W2hi = (short*)W2hi_; short* W2lo = (short*)W2lo_;
    int*   mlist = (int*)alloc(8 * NLM_MAXM);
    int*   mcnt  = (int*)alloc(64);
    float* sumw  = alloc(8 * NLM_MAXM);
    short* d3hi = h2shi; short* d3lo = h2slo;
    short* d2hi = h1hi;  short* d2lo = h1lo;

    if (ws_size < off * sizeof(float)) return;

    auto cdiv = [](size_t a, size_t b) { return (int)((a + b - 1) / b); };

    // ---- weight transforms ----
    struct WLay { int Cout, Cin, K; size_t ofs; };
    const WLay WL[8] = {
        {256, 128, 7, 0},         // enc1
        {512, 256, 5, 1605632},   // enc2
        {512, 512, 3, 4882432},   // enc3
        {512, 512, 3, 7241728},   // enc4
        {512, 1024, 3, 9601024},  // dec4
        {512, 1024, 3, 14319616}, // dec3
        {256, 768, 3, 19038208},  // dec2
        {128, 384, 3, 20807680},  // dec1
    };
    for (int i = 0; i < 8; ++i) {
        size_t tot = (size_t)WL[i].Cout * WL[i].Cin * WL[i].K * WL[i].K;
        wtransform<<<cdiv(tot, 256), 256, 0, stream>>>(
            Wsrc[i], Whi + WL[i].ofs, Wlo + WL[i].ofs, WL[i].Cout, WL[i].Cin,
            WL[i].K * WL[i].K, tot);
    }

    // ---- x0 planes live in d_out (free scratch until dec1 overwrites it) ----
    short* x0hi = (short*)d_out;
    short* x0lo = x0hi + 21233664;
    split_planes<<<dim3(324, 4, N), 256, 0, stream>>>(x0, x0hi, x0lo, 128, 20736);

    // ---------------- enc1: x0 planes -> h1 planes, relu ----------------
    maskconv_kernel<7, 2, false><<<cdiv(N * 72 * 72, 256), 256, 0, stream>>>(
        m0, 144, 144, mc, nm1, N, 144, 144, 72, 72);
    conv_enc<7, 2, 8, 8, 2, false, EPI_PAIR_RELU><<<dim3(81, 1, N), 512, 0, stream>>>(
        x0hi, x0lo, 128, 144, 144, m0,
        Whi + WL[0].ofs, Wlo + WL[0].ofs, mc, nullptr, h1hi, h1lo,
        72, 72, 256, 9);

    // ---------------- enc2 ----------------
    maskconv_kernel<5, 2, false><<<cdiv(N * 36 * 36, 256), 256, 0, stream>>>(
        nm1, 72, 72, mc, nm2, N, 72, 72, 36, 36);
    conv_enc<5, 2, 8, 8, 2, false, EPI_F32><<<dim3(25, 2, N), 512, 0, stream>>>(
        h1hi, h1lo, 256, 72, 72, nm1,
        Whi + WL[1].ofs, Wlo + WL[1].ofs, mc, nullptr, ybuf, nullptr,
        36, 36, 512, 5);
    bn_stats_kernel<<<512, 256, 0, stream>>>(ybuf, N, 512, 1296, bmean, bistd);
    bn_apply_blk<<<dim3(cdiv(1296, 64), 16, N), 256, 0, stream>>>(
        ybuf, bmean, bistd, enc2g, enc2b, h2shi, h2slo, h2f, 512, 1296, ACT_RELU);

    // ---------------- NLM swap ----------------
    nlm_trans<<<dim3(41, 16, N), 256, 0, stream>>>(h2f, xTp);
    nlm_sq2<<<dim3(6, N), 256, 0, stream>>>(h2f, sqb);
    hipMemsetAsync(mcnt, 0, 8 * sizeof(int), stream);
    nlm_compact<<<N, 256, 0, stream>>>(nm2, mlist, mcnt);
    nlm_gather<<<dim3(64, N), 256, 0, stream>>>(xTp, mlist, mcnt, Phi, Plo);
    nlm_gemm1<<<dim3(11, 2, N), 512, 0, stream>>>(xTp, Phi, Plo, mcnt, Smat);
    nlm_row<<<dim3(NLM_MAXM, N), 256, 0, stream>>>(Smat, sqb, nm2, mlist, mcnt,
                                                   W2hi, W2lo, sumw, 1.f / 25.f);
    nlm_gemm2<<<dim3(4, 2, N), 512, 0, stream>>>(xTp, W2hi, W2lo, mcnt, sumw,
                                                 mlist, h2shi, h2slo);

    // ---------------- enc3 ----------------
    maskconv_kernel<3, 2, false><<<cdiv(N * 18 * 18, 256), 256, 0, stream>>>(
        nm2, 36, 36, mc, nm3, N, 36, 36, 18, 18);
    conv_enc<3, 2, 4, 8, 1, false, EPI_F32><<<dim3(15, 2, N), 512, 0, stream>>>(
        h2shi, h2slo, 512, 36, 36, nm2,
        Whi + WL[2].ofs, Wlo + WL[2].ofs, mc, nullptr, ybuf, nullptr,
        18, 18, 512, 3);
    bn_stats_kernel<<<512, 256, 0, stream>>>(ybuf, N, 512, 324, bmean, bistd);
    bn_apply_blk<<<dim3(cdiv(324, 64), 16, N), 256, 0, stream>>>(
        ybuf, bmean, bistd, enc3g, enc3b, h3hi, h3lo, nullptr, 512, 324, ACT_RELU);

    // ---------------- enc4 ----------------
    maskconv_kernel<3, 2, false><<<cdiv(N * 9 * 9, 256), 256, 0, stream>>>(
        nm3, 18, 18, mc, nm4, N, 18, 18, 9, 9);
    conv_enc<3, 2, 4, 8, 1, false, EPI_F32><<<dim3(6, 2, N), 512, 0, stream>>>(
        h3hi, h3lo, 512, 18, 18, nm3,
        Whi + WL[3].ofs, Wlo + WL[3].ofs, mc, nullptr, ybuf, nullptr,
        9, 9, 512, 2);
    bn_stats_kernel<<<512, 256, 0, stream>>>(ybuf, N, 512, 81, bmean, bistd);
    bn_apply_blk<<<dim3(cdiv(81, 64), 16, N), 256, 0, stream>>>(
        ybuf, bmean, bistd, enc4g, enc4b, h4hi, h4lo, nullptr, 512, 81, ACT_RELU);

    // ---------------- dec4 ----------------
    maskconv_kernel<3, 1, true><<<cdiv(N * 18 * 18, 256), 256, 0, stream>>>(
        nm4, 9, 9, mc, nmd4, N, 18, 18, 18, 18);
    conv3x3<8, 8, 2, false, EPI_F32><<<dim3(9, 4, N), 512, 0, stream>>>(
        h4hi, h4lo, 512, 9, 9, h3hi, h3lo, 512, nm4,
        Whi + WL[4].ofs, Wlo + WL[4].ofs, mc, nullptr, ybuf,
        18, 18, 512, 3);
    bn_stats_kernel<<<512, 256, 0, stream>>>(ybuf, N, 512, 324, bmean, bistd);
    bn_apply_blk<<<dim3(cdiv(324, 64), 16, N), 256, 0, stream>>>(
        ybuf, bmean, bistd, dec4g, dec4b, d4hi, d4lo, nullptr, 512, 324, ACT_LEAKY);

    // ---------------- dec3 ----------------
    maskconv_kernel<3, 1, true><<<cdiv(N * 36 * 36, 256), 256, 0, stream>>>(
        nmd4, 18, 18, mc, nmd3, N, 36, 36, 36, 36);
    conv3x3<8, 12, 3, false, EPI_F32><<<dim3(15, 4, N), 512, 0, stream>>>(
        d4hi, d4lo, 512, 18, 18, h2shi, h2slo, 512, nmd4,
        Whi + WL[5].ofs, Wlo + WL[5].ofs, mc, nullptr, ybuf,
        36, 36, 512, 3);
    bn_stats_kernel<<<512, 256, 0, stream>>>(ybuf, N, 512, 1296, bmean, bistd);
    bn_apply_blk<<<dim3(cdiv(1296, 64), 16, N), 256, 0, stream>>>(
        ybuf, bmean, bistd, dec3g, dec3b, d3hi, d3lo, nullptr, 512, 1296, ACT_LEAKY);

    // ---------------- dec2 ----------------
    maskconv_kernel<3, 1, true><<<cdiv(N * 72 * 72, 256), 256, 0, stream>>>(
        nmd3, 36, 36, mc, nmd2, N, 72, 72, 72, 72);
    conv3x3<8, 16, 4, false, EPI_F32><<<dim3(45, 2, N), 512, 0, stream>>>(
        d3hi, d3lo, 512, 36, 36, h1hi, h1lo, 256, nmd3,
        Whi + WL[6].ofs, Wlo + WL[6].ofs, mc, nullptr, ybuf,
        72, 72, 256, 5);
    bn_stats_kernel<<<256, 256, 0, stream>>>(ybuf, N, 256, 5184, bmean, bistd);
    bn_apply_blk<<<dim3(cdiv(5184, 64), 8, N), 256, 0, stream>>>(
        ybuf, bmean, bistd, dec2g, dec2b, d2hi, d2lo, nullptr, 256, 5184, ACT_LEAKY);

    // ---------------- dec1: cat[up2(d2), x0] -> d_out (x0 planes now dead) ----------------
    maskconv_kernel<3, 1, true><<<cdiv(N * 144 * 144, 256), 256, 0, stream>>>(
        nmd2, 72, 72, mc, nmx, N, 144, 144, 144, 144);
    conv3x3<8, 16, 4, true, EPI_F32_BIAS><<<dim3(162, 1, N), 512, 0, stream>>>(
        d2hi, d2lo, 256, 72, 72, x0, nullptr, 128, nmd2,
        Whi + WL[7].ofs, Wlo + WL[7].ofs, mc, dec1b, outp,
        144, 144, 128, 9);
}

// Round 15
// 2701.926 us; speedup vs baseline: 1.0401x; 1.0187x over previous
//
#include <hip/hip_runtime.h>
#include <math.h>

#define ACT_NONE 0
#define ACT_RELU 1
#define ACT_LEAKY 2

#define EPI_F32 0
#define EPI_PAIR_RELU 1
#define EPI_F32_BIAS 2

typedef __attribute__((ext_vector_type(8))) short short8;
typedef __attribute__((ext_vector_type(8))) __bf16 bf16x8;
typedef __attribute__((ext_vector_type(4))) float f32x4;
typedef __attribute__((ext_vector_type(4))) unsigned uint4v;

__device__ __forceinline__ float actf(float y, int act) {
    if (act == ACT_RELU)  return y > 0.f ? y : 0.f;
    if (act == ACT_LEAKY) return y >= 0.f ? y : 0.2f * y;
    return y;
}

// ---- bf16 split helpers ----
__device__ __forceinline__ unsigned f2bf_rne(float f) {
    unsigned u = __float_as_uint(f);
    return (u + 0x7FFFu + ((u >> 16) & 1u)) >> 16;
}
__device__ __forceinline__ float bf2f(unsigned h) { return __uint_as_float(h << 16); }
__device__ __forceinline__ unsigned splitpack(float f) {
    unsigned hi = f2bf_rne(f);
    float r = f - bf2f(hi);
    unsigned lo = f2bf_rne(r);
    return (hi & 0xFFFFu) | (lo << 16);
}

__device__ __forceinline__ f32x4 mfma16(short8 a, short8 b, f32x4 c) {
    return __builtin_amdgcn_mfma_f32_16x16x32_bf16(
        __builtin_bit_cast(bf16x8, a), __builtin_bit_cast(bf16x8, b), c, 0, 0, 0);
}

// blocked-plane address (u16 units): [img][c/32][HW pix][c%32]
__device__ __forceinline__ size_t paddr(int img, int KBc, size_t HW, size_t pix) {
    return ((size_t)img * KBc * HW + pix) * 32;
}

// ---------------------------------------------------------------------------
// Mask convolution
// ---------------------------------------------------------------------------
template<int K, int S, bool MHALF>
__global__ void maskconv_kernel(const float* __restrict__ M, int HM, int WM,
                                float* __restrict__ mc, float* __restrict__ nm,
                                int N, int Hin, int Win, int Hout, int Wout) {
    constexpr int P = (K - 1) / 2;
    int idx = blockIdx.x * blockDim.x + threadIdx.x;
    int total = N * Hout * Wout;
    if (idx >= total) return;
    int wo = idx % Wout;
    int t  = idx / Wout;
    int ho = t % Hout;
    int n  = t / Hout;
    float s = 0.f;
    for (int kh = 0; kh < K; ++kh) {
        int ih = ho * S - P + kh;
        if ((unsigned)ih >= (unsigned)Hin) continue;
        const float* mrow = M + ((size_t)n * HM + (MHALF ? (ih >> 1) : ih)) * WM;
        for (int kw = 0; kw < K; ++kw) {
            int iw = wo * S - P + kw;
            if ((unsigned)iw < (unsigned)Win)
                s += mrow[MHALF ? (iw >> 1) : iw];
        }
    }
    mc[idx] = s;
    nm[idx] = (s == 0.f) ? 0.f : 1.f;
}

// ---------------------------------------------------------------------------
// Weight transform (A-fragment layout bf16 hi/lo)
// ---------------------------------------------------------------------------
__global__ void wtransform(const float* __restrict__ W, short* __restrict__ Whi,
                           short* __restrict__ Wlo, int Cout, int Cin, int Ksz,
                           size_t total) {
    size_t idx = (size_t)blockIdx.x * blockDim.x + threadIdx.x;
    if (idx >= total) return;
    int j = (int)(idx & 7);
    int lane = (int)((idx >> 3) & 63);
    size_t r = idx >> 9;
    int COB = Cout >> 4, KB = Cin >> 5;
    int cob = (int)(r % COB); r /= COB;
    int kb = (int)(r % KB);
    int tap = (int)(r / KB);
    int co = cob * 16 + (lane & 15);
    int ci = kb * 32 + (lane >> 4) * 8 + j;
    float f = W[((size_t)co * Cin + ci) * Ksz + tap];
    unsigned hi = f2bf_rne(f);
    float rr = f - bf2f(hi);
    unsigned lo = f2bf_rne(rr);
    Whi[idx] = (short)hi;
    Wlo[idx] = (short)lo;
}

// ---------------------------------------------------------------------------
// f32 NCHW -> blocked hi/lo planes (LDS-tiled transpose, both sides coalesced)
// grid: (cdiv(HW,64), C/32, N), 256 threads
// ---------------------------------------------------------------------------
__global__ __launch_bounds__(256) void split_planes(
    const float* __restrict__ x, short* __restrict__ hi, short* __restrict__ lo,
    int C, int HW) {
    __shared__ float tile[32][65];
    const int img = blockIdx.z, kb = blockIdx.y;
    const int px0 = blockIdx.x * 64;
    const int tid = threadIdx.x;
    const int KBc = C >> 5;
    for (int i = tid; i < 32 * 64; i += 256) {
        const int ch = i >> 6, px = i & 63;
        float v = 0.f;
        if (px0 + px < HW)
            v = x[((size_t)img * C + kb * 32 + ch) * HW + px0 + px];
        tile[ch][px] = v;
    }
    __syncthreads();
    const int px = tid >> 2, sg = tid & 3;
    if (px0 + px < HW) {
        short8 h8, l8;
#pragma unroll
        for (int j = 0; j < 8; ++j) {
            float v = tile[sg * 8 + j][px];
            unsigned h16 = f2bf_rne(v);
            float rr = v - bf2f(h16);
            h8[j] = (short)h16;
            l8[j] = (short)f2bf_rne(rr);
        }
        const size_t a = (((size_t)img * KBc + kb) * HW + px0 + px) * 32 + sg * 8;
        *(short8*)&hi[a] = h8;
        *(short8*)&lo[a] = l8;
    }
}

// ---------------------------------------------------------------------------
// Encoder halo-staged stride-2 conv. A-source: blocked planes (or f32 if AF32).
// Direct stage per kb; A-fragment double-buffer across flattened tap loop
// (next tap's weights in flight under current tap's MFMA cluster).
// ---------------------------------------------------------------------------
template<int K, int S, int TH, int TW, int NFW, bool AF32, int EPI>
__global__ __launch_bounds__(512) void conv_enc(
    const void* __restrict__ Ahi, const void* __restrict__ Alo,
    int Cin, int Hin, int Win,
    const float* __restrict__ M,
    const short* __restrict__ Whi, const short* __restrict__ Wlo,
    const float* __restrict__ mc, const float* __restrict__ bias,
    void* __restrict__ outp, void* __restrict__ outp2,
    int Hout, int Wout, int Cout, int TX)
{
    static_assert(S == 2, "parity layout assumes stride 2");
    constexpr int P = (K - 1) / 2;
    constexpr int HH  = (TH - 1) * S + K;
    constexpr int HWC = (TW - 1) * S + K;
    constexpr int PXC = HH * HWC;
    static_assert(PXC <= 512, "one halo pixel per thread");
    constexpr int PW  = (HWC + 1) / 2;
    constexpr int PXC2 = HH * PW * 2;
    constexpr int PXC2P = PXC2 + ((2 - (PXC2 % 8) + 8) % 8);   // bank-phase pad
    constexpr int NTAP = K * K;
    __shared__ __align__(16) short BHs[4 * PXC2P * 8];
    __shared__ __align__(16) short BLs[4 * PXC2P * 8];

    const int t    = threadIdx.x;
    const int lane = t & 63;
    const int wv   = t >> 6;
    const int wm   = wv >> 1;
    const int wn   = wv & 1;
    const int img  = blockIdx.z;
    const int coB  = blockIdx.y * 256;
    const int tile = blockIdx.x;
    const int ty   = tile / TX, tx = tile - ty * TX;
    const int oy0  = ty * TH, ox0 = tx * TW;
    const int KB   = Cin >> 5;
    const int COB  = Cout >> 4;
    const size_t HW = (size_t)Hin * Win;
    const int g  = lane >> 4;
    const int pl = lane & 15;

    // staging descriptor (once)
    bool sel = false;
    size_t basef = 0, basep = 0;
    int qq = 0;
    if (t < PXC) {
        const int r = t / HWC, c = t - r * HWC;
        qq = r * PW + (c >> 1) + (c & 1) * (HH * PW);
        const int iy = oy0 * S - P + r;
        const int ix = ox0 * S - P + c;
        if ((unsigned)iy < (unsigned)Hin && (unsigned)ix < (unsigned)Win) {
            const size_t pix = (size_t)iy * Win + ix;
            if (M[(size_t)img * HW + pix] != 0.f) {
                sel = true;
                basef = (size_t)img * Cin * HW + pix;
                basep = paddr(img, KB, HW, pix);
            }
        }
    }

    f32x4 acc[4][NFW] = {};
    const size_t tstride = (size_t)KB * COB * 512;

#pragma unroll 1
    for (int kb = 0; kb < KB; ++kb) {
        // ---- direct stage ----
        if (t < PXC) {
#pragma unroll
            for (int gg = 0; gg < 4; ++gg) {
                short8 h8, l8;
                if (sel) {
                    if (AF32) {
                        const float* s = (const float*)Ahi + basef + (size_t)(kb * 32 + gg * 8) * HW;
#pragma unroll
                        for (int j = 0; j < 8; ++j) {
                            float f = s[(size_t)j * HW];
                            unsigned h16 = f2bf_rne(f);
                            float rr = f - bf2f(h16);
                            h8[j] = (short)h16;
                            l8[j] = (short)f2bf_rne(rr);
                        }
                    } else {
                        const size_t a = basep + (size_t)kb * HW * 32 + gg * 8;
                        h8 = *(const short8*)((const short*)Ahi + a);
                        l8 = *(const short8*)((const short*)Alo + a);
                    }
                } else {
#pragma unroll
                    for (int j = 0; j < 8; ++j) { h8[j] = 0; l8[j] = 0; }
                }
                *(short8*)&BHs[(gg * PXC2P + qq) * 8] = h8;
                *(short8*)&BLs[(gg * PXC2P + qq) * 8] = l8;
            }
        }
        __syncthreads();

        // ---- taps with A double-buffer ----
        size_t wb = ((size_t)kb * COB + (coB >> 4) + wm * 4) * 512 + (size_t)lane * 8;
        short8 ah[4], al[4];
#pragma unroll
        for (int fm = 0; fm < 4; ++fm) {
            ah[fm] = *(const short8*)(Whi + wb + (size_t)fm * 512);
            al[fm] = *(const short8*)(Wlo + wb + (size_t)fm * 512);
        }
#pragma unroll 1
        for (int tap = 0; tap < NTAP; ++tap) {
            const int kh = tap / K, kw = tap - kh * K;
            const size_t wbn = wb + ((tap + 1 < NTAP) ? tstride : 0);
            short8 nh[4], nl[4];
#pragma unroll
            for (int fm = 0; fm < 4; ++fm) {
                nh[fm] = *(const short8*)(Whi + wbn + (size_t)fm * 512);
                nl[fm] = *(const short8*)(Wlo + wbn + (size_t)fm * 512);
            }
            __builtin_amdgcn_s_setprio(1);
#pragma unroll
            for (int fn = 0; fn < NFW; ++fn) {
                const int pxf = (wn * NFW + fn) * 16 + pl;
                const int oy = pxf / TW, ox = pxf - oy * TW;
                const int q2 = (oy * S + kh) * PW + ox + (kw >> 1) + (kw & 1) * (HH * PW);
                short8 bh = *(const short8*)&BHs[(g * PXC2P + q2) * 8];
                short8 bl = *(const short8*)&BLs[(g * PXC2P + q2) * 8];
#pragma unroll
                for (int fm = 0; fm < 4; ++fm) {
                    acc[fm][fn] = mfma16(ah[fm], bh, acc[fm][fn]);
                    acc[fm][fn] = mfma16(al[fm], bh, acc[fm][fn]);
                    acc[fm][fn] = mfma16(ah[fm], bl, acc[fm][fn]);
                }
            }
            __builtin_amdgcn_s_setprio(0);
#pragma unroll
            for (int fm = 0; fm < 4; ++fm) { ah[fm] = nh[fm]; al[fm] = nl[fm]; }
            wb = wbn;
        }
        __syncthreads();
    }

    const int Npix = Hout * Wout;
    const float* mcb = mc + (size_t)img * Npix;
#pragma unroll
    for (int fm = 0; fm < 4; ++fm)
#pragma unroll
    for (int fn = 0; fn < NFW; ++fn) {
        const int co = coB + (wm * 4 + fm) * 16 + (lane >> 4) * 4;
        const int pxf = (wn * NFW + fn) * 16 + (lane & 15);
        const int oy = pxf / TW, ox = pxf - oy * TW;
        const int gy = oy0 + oy, gx = ox0 + ox;
        if (gy >= Hout || gx >= Wout) continue;
        const size_t pix = (size_t)gy * Wout + gx;
        const float m = mcb[pix];
        f32x4 a = acc[fm][fn];
#pragma unroll
        for (int r = 0; r < 4; ++r) {
            float y = a[r];
            if (EPI == EPI_F32_BIAS) {
                const float bv = bias[co + r];
                y = (m == 0.f) ? 0.f : (y - bv) / m + bv;
            } else {
                y = (m == 0.f) ? 0.f : y / m;
            }
            if (EPI == EPI_PAIR_RELU) {
                y = y > 0.f ? y : 0.f;
                const size_t pa = paddr(img, Cout >> 5, Npix, pix)
                                + (size_t)(co >> 5) * Npix * 32 + (co & 31) + r;
                unsigned h16 = f2bf_rne(y);
                float rr = y - bf2f(h16);
                ((short*)outp)[pa]  = (short)h16;
                ((short*)outp2)[pa] = (short)f2bf_rne(rr);
            } else {
                ((float*)outp)[((size_t)img * Cout + co + r) * Npix + pix] = y;
            }
        }
    }
}

// ---------------------------------------------------------------------------
// Decoder 3x3 s1 p1: 8 waves, MFW=2 (4m x 2n), NPIX=32*NFW, blocked-plane IO.
// ---------------------------------------------------------------------------
template<int TH, int TW, int NFW, bool BF32, int EPI>
__global__ __launch_bounds__(512) void conv3x3(
    const void* __restrict__ Ahi, const void* __restrict__ Alo,
    int CA, int HA, int WA,
    const void* __restrict__ Bhi, const void* __restrict__ Blo, int CB,
    const float* __restrict__ M,
    const short* __restrict__ Whi, const short* __restrict__ Wlo,
    const float* __restrict__ mc, const float* __restrict__ bias,
    void* __restrict__ outp,
    int Hout, int Wout, int Cout, int TX)
{
    constexpr int HALO_H = TH + 2, HALO_W = TW + 2, HALO = HALO_H * HALO_W;
    constexpr int HALOP = HALO + ((2 - (HALO % 8) + 8) % 8);   // bank-phase pad
    constexpr int NPIX = TH * TW;
    constexpr int SITER = (HALO + 127) / 128;
    static_assert(NPIX == 32 * NFW, "tile must be exactly 32*NFW pixels");
    __shared__ __align__(16) short BHs[4 * HALOP * 8];
    __shared__ __align__(16) short BLs[4 * HALOP * 8];

    const int t    = threadIdx.x;
    const int lane = t & 63;
    const int wv   = t >> 6;
    const int wm   = wv >> 1;
    const int wn   = wv & 1;
    const int img  = blockIdx.z;
    const int coB  = blockIdx.y * 128;
    const int tile = blockIdx.x;
    const int ty   = tile / TX;
    const int tx   = tile - ty * TX;
    const int oy0  = ty * TH, ox0 = tx * TW;
    const int Cin  = CA + CB;
    const int KB   = Cin >> 5;
    const int KBA  = CA >> 5;
    const int KBB  = CB >> 5;
    const int COB  = Cout >> 4;
    const int WM   = Wout >> 1;
    const size_t HWA = (size_t)HA * WA;
    const size_t HWB = (size_t)Hout * Wout;

    const int sg = t >> 7;
    const int st = t & 127;
    const int g  = lane >> 4;
    const int pl = lane & 15;

    // staging descriptors (once)
    bool ssel[SITER];
    size_t aoff[SITER], boff[SITER];
#pragma unroll
    for (int i = 0; i < SITER; ++i) {
        ssel[i] = false; aoff[i] = 0; boff[i] = 0;
        const int q = st + i * 128;
        if (q < HALO) {
            const int hy = q / HALO_W, hx = q - hy * HALO_W;
            const int iy = oy0 - 1 + hy, ix = ox0 - 1 + hx;
            if ((unsigned)iy < (unsigned)Hout && (unsigned)ix < (unsigned)Wout) {
                if (M[((size_t)img * (Hout >> 1) + (iy >> 1)) * WM + (ix >> 1)] != 0.f) {
                    ssel[i] = true;
                    const size_t pixA = (size_t)(iy >> 1) * WA + (ix >> 1);
                    const size_t pixB = (size_t)iy * Wout + ix;
                    aoff[i] = paddr(img, KBA, HWA, pixA) + sg * 8;
                    if (BF32) boff[i] = (size_t)img * CB * HWB + pixB;     // f32 elem base
                    else      boff[i] = paddr(img, KBB, HWB, pixB) + sg * 8;
                }
            }
        }
    }

    short8 hv[SITER], lv[SITER];
    auto prefetch = [&](int kb) {
        const int c = kb * 32 + sg * 8;
#pragma unroll
        for (int i = 0; i < SITER; ++i) {
            const int q = st + i * 128;
            bool ok = (q < HALO) && ssel[i];
            if (ok) {
                if (c < CA) {
                    const size_t a = aoff[i] + (size_t)kb * HWA * 32;
                    hv[i] = *(const short8*)((const short*)Ahi + a);
                    lv[i] = *(const short8*)((const short*)Alo + a);
                } else {
                    if (BF32) {
                        const float* s = (const float*)Bhi + boff[i] + (size_t)(c - CA) * HWB;
#pragma unroll
                        for (int j = 0; j < 8; ++j) {
                            float f = s[(size_t)j * HWB];
                            unsigned h16 = f2bf_rne(f);
                            float rr = f - bf2f(h16);
                            hv[i][j] = (short)h16;
                            lv[i][j] = (short)f2bf_rne(rr);
                        }
                    } else {
                        const size_t a = boff[i] + (size_t)(kb - KBA) * HWB * 32;
                        hv[i] = *(const short8*)((const short*)Bhi + a);
                        lv[i] = *(const short8*)((const short*)Blo + a);
                    }
                }
            } else {
#pragma unroll
                for (int j = 0; j < 8; ++j) { hv[i][j] = 0; lv[i][j] = 0; }
            }
        }
    };

    f32x4 acc[2][NFW] = {};
    const size_t wstride = (size_t)KB * COB * 512;
    prefetch(0);

#pragma unroll 1
    for (int kb = 0; kb < KB; ++kb) {
#pragma unroll
        for (int i = 0; i < SITER; ++i) {
            const int q = st + i * 128;
            if (q < HALO) {
                *(short8*)&BHs[(sg * HALOP + q) * 8] = hv[i];
                *(short8*)&BLs[(sg * HALOP + q) * 8] = lv[i];
            }
        }
        __syncthreads();
        if (kb + 1 < KB) prefetch(kb + 1);

        size_t wb = ((size_t)kb * COB + (coB >> 4) + wm * 2) * 512 + lane * 8;
#pragma unroll 1
        for (int tap = 0; tap < 9; ++tap) {
            const int dh = tap / 3, dw = tap - dh * 3;
            short8 ah0 = *(const short8*)(Whi + wb);
            short8 ah1 = *(const short8*)(Whi + wb + 512);
            short8 al0 = *(const short8*)(Wlo + wb);
            short8 al1 = *(const short8*)(Wlo + wb + 512);
            __builtin_amdgcn_s_setprio(1);
#pragma unroll
            for (int fn = 0; fn < NFW; ++fn) {
                const int pxf = (wn * NFW + fn) * 16 + pl;
                const int oy = pxf / TW, ox = pxf - oy * TW;
                const int hpx = (oy + dh) * HALO_W + (ox + dw);
                short8 bh = *(const short8*)&BHs[(g * HALOP + hpx) * 8];
                short8 bl = *(const short8*)&BLs[(g * HALOP + hpx) * 8];
                acc[0][fn] = mfma16(ah0, bh, acc[0][fn]);
                acc[1][fn] = mfma16(ah1, bh, acc[1][fn]);
                acc[0][fn] = mfma16(al0, bh, acc[0][fn]);
                acc[1][fn] = mfma16(al1, bh, acc[1][fn]);
                acc[0][fn] = mfma16(ah0, bl, acc[0][fn]);
                acc[1][fn] = mfma16(ah1, bl, acc[1][fn]);
            }
            __builtin_amdgcn_s_setprio(0);
            wb += wstride;
        }
        __syncthreads();
    }

    const float* mcb = mc + (size_t)img * HWB;
#pragma unroll
    for (int fm = 0; fm < 2; ++fm)
#pragma unroll
    for (int fn = 0; fn < NFW; ++fn) {
        const int co = coB + (wm * 2 + fm) * 16 + (lane >> 4) * 4;
        const int pxf = (wn * NFW + fn) * 16 + (lane & 15);
        const int oy = pxf / TW, ox = pxf - oy * TW;
        const int gy = oy0 + oy, gx = ox0 + ox;
        if (gy >= Hout || gx >= Wout) continue;
        const float m = mcb[(size_t)gy * Wout + gx];
        f32x4 a = acc[fm][fn];
#pragma unroll
        for (int r = 0; r < 4; ++r) {
            float y = a[r];
            if (EPI == EPI_F32_BIAS) {
                const float bv = bias[co + r];
                y = (m == 0.f) ? 0.f : (y - bv) / m + bv;
            } else {
                y = (m == 0.f) ? 0.f : y / m;
            }
            ((float*)outp)[((size_t)img * Cout + co + r) * HWB + (size_t)gy * Wout + gx] = y;
        }
    }
}

// ---------------------------------------------------------------------------
// BatchNorm stats
// ---------------------------------------------------------------------------
__global__ __launch_bounds__(256) void bn_stats_kernel(const float* __restrict__ y,
                                                       int N, int C, int HW,
                                                       float* __restrict__ mean,
                                                       float* __restrict__ istd) {
    const int c = blockIdx.x;
    double s = 0.0, s2 = 0.0;
    const int tot = N * HW;
    for (int i = threadIdx.x; i < tot; i += blockDim.x) {
        int n = i / HW, hw = i - n * HW;
        float v = y[((size_t)n * C + c) * HW + hw];
        s += v;
        s2 += (double)v * v;
    }
    __shared__ double sh[256], sh2[256];
    sh[threadIdx.x] = s; sh2[threadIdx.x] = s2;
    __syncthreads();
    for (int o = 128; o > 0; o >>= 1) {
        if (threadIdx.x < o) { sh[threadIdx.x] += sh[threadIdx.x + o]; sh2[threadIdx.x] += sh2[threadIdx.x + o]; }
        __syncthreads();
    }
    if (threadIdx.x == 0) {
        double mu = sh[0] / tot;
        double var = sh2[0] / tot - mu * mu;
        mean[c] = (float)mu;
        istd[c] = (float)(1.0 / sqrt(var + 1e-5));
    }
}

// ---------------------------------------------------------------------------
// BN apply + act -> blocked hi/lo planes (LDS-tiled transpose)
// ---------------------------------------------------------------------------
__global__ __launch_bounds__(256) void bn_apply_blk(
    const float* __restrict__ y,
    const float* __restrict__ mean, const float* __restrict__ istd,
    const float* __restrict__ g, const float* __restrict__ b,
    short* __restrict__ hi, short* __restrict__ lo, float* __restrict__ fout,
    int C, int HW, int act) {
    __shared__ float tile[32][65];
    const int img = blockIdx.z, kb = blockIdx.y;
    const int px0 = blockIdx.x * 64;
    const int tid = threadIdx.x;
    const int KBc = C >> 5;

    for (int i = tid; i < 32 * 64; i += 256) {
        const int ch = i >> 6, px = i & 63;
        float v = 0.f;
        if (px0 + px < HW)
            v = y[((size_t)img * C + kb * 32 + ch) * HW + px0 + px];
        tile[ch][px] = v;
    }
    __syncthreads();

    const int px = tid >> 2, sg = tid & 3;
    if (px0 + px < HW) {
        short8 h8, l8;
        float f8[8];
#pragma unroll
        for (int j = 0; j < 8; ++j) {
            const int c = kb * 32 + sg * 8 + j;
            float v = tile[sg * 8 + j][px];
            v = (v - mean[c]) * istd[c] * g[c] + b[c];
            v = actf(v, act);
            f8[j] = v;
            unsigned h16 = f2bf_rne(v);
            float rr = v - bf2f(h16);
            h8[j] = (short)h16;
            l8[j] = (short)f2bf_rne(rr);
        }
        const size_t a = (((size_t)img * KBc + kb) * HW + px0 + px) * 32 + sg * 8;
        *(short8*)&hi[a] = h8;
        *(short8*)&lo[a] = l8;
        if (fout) {
#pragma unroll
            for (int j = 0; j < 8; ++j)
                fout[((size_t)img * C + kb * 32 + sg * 8 + j) * HW + px0 + px] = f8[j];
        }
    }
}

// ---------------------------------------------------------------------------
// NLM (MFMA formulation; xTp stays packed-u32; gemm2 writes blocked planes)
// ---------------------------------------------------------------------------
#define NLM_C 512
#define NLM_N 1296
#define NLM_MAXM 256
#define NLM_RT 16
#define NLM_KB1 16
#define NLM_KB2 41
#define NLM_PFRAG (NLM_KB1 * NLM_RT * 512)
#define NLM_WFRAG (NLM_KB2 * NLM_RT * 512)

__global__ __launch_bounds__(256) void nlm_trans(const float* __restrict__ h2f,
                                                 unsigned* __restrict__ xTp) {
    __shared__ float tile[32][33];
    const int b = blockIdx.z;
    const int j0 = blockIdx.x * 32, c0 = blockIdx.y * 32;
    const int tx = threadIdx.x & 31, ty = threadIdx.x >> 5;
    for (int cc = ty; cc < 32; cc += 8) {
        const int j = j0 + tx;
        tile[cc][tx] = (j < NLM_N) ? h2f[((size_t)b * NLM_C + c0 + cc) * NLM_N + j] : 0.f;
    }
    __syncthreads();
    for (int jj = ty; jj < 32; jj += 8) {
        const int j = j0 + jj;
        if (j < NLM_N)
            xTp[((size_t)b * NLM_N + j) * NLM_C + c0 + tx] = splitpack(tile[tx][jj]);
    }
}

__global__ void nlm_sq2(const float* __restrict__ h2f, float* __restrict__ sq) {
    const int b = blockIdx.y;
    const int j = blockIdx.x * 256 + threadIdx.x;
    if (j >= NLM_N) return;
    const float* p = h2f + (size_t)b * NLM_C * NLM_N + j;
    float s0 = 0.f, s1 = 0.f, s2 = 0.f, s3 = 0.f;
    for (int c = 0; c < NLM_C; c += 4) {
        float v0 = p[(size_t)c * NLM_N];
        float v1 = p[(size_t)(c + 1) * NLM_N];
        float v2 = p[(size_t)(c + 2) * NLM_N];
        float v3 = p[(size_t)(c + 3) * NLM_N];
        s0 = fmaf(v0, v0, s0); s1 = fmaf(v1, v1, s1);
        s2 = fmaf(v2, v2, s2); s3 = fmaf(v3, v3, s3);
    }
    sq[b * NLM_N + j] = (s0 + s1) + (s2 + s3);
}

__global__ void nlm_compact(const float* __restrict__ nm2, int* __restrict__ list,
                            int* __restrict__ cnt) {
    const int b = blockIdx.x;
    for (int j = threadIdx.x; j < NLM_N; j += 256) {
        if (nm2[(size_t)b * NLM_N + j] == 0.f) {
            int pos = atomicAdd(&cnt[b], 1);
            if (pos < NLM_MAXM) list[b * NLM_MAXM + pos] = j;
        }
    }
}

__global__ void nlm_gather(const unsigned* __restrict__ xTp, const int* __restrict__ list,
                           const int* __restrict__ cnt,
                           short* __restrict__ Phi, short* __restrict__ Plo) {
    const int b = blockIdx.y;
    const int id = blockIdx.x * 256 + threadIdx.x;
    const int i  = id >> 6;
    const int rem = id & 63;
    const int kb = rem >> 2, kg = rem & 3;
    const int lane = kg * 16 + (i & 15), rt = i >> 4;
    const size_t f = (size_t)b * NLM_PFRAG + ((size_t)(kb * NLM_RT + rt) * 64 + lane) * 8;
    if (i < cnt[b]) {
        const int pix = list[b * NLM_MAXM + i];
        const unsigned* s = xTp + ((size_t)b * NLM_N + pix) * NLM_C + kb * 32 + kg * 8;
#pragma unroll
        for (int jj = 0; jj < 8; ++jj) {
            unsigned v = s[jj];
            Phi[f + jj] = (short)(v & 0xFFFFu);
            Plo[f + jj] = (short)(v >> 16);
        }
    } else {
#pragma unroll
        for (int jj = 0; jj < 8; ++jj) { Phi[f + jj] = 0; Plo[f + jj] = 0; }
    }
}

__global__ __launch_bounds__(512) void nlm_gemm1(
    const unsigned* __restrict__ xTp, const short* __restrict__ Phi,
    const short* __restrict__ Plo, const int* __restrict__ cnt,
    float* __restrict__ S) {
    const int img = blockIdx.z, mt = blockIdx.y, nt = blockIdx.x;
    if (mt * 128 >= cnt[img]) return;
    __shared__ __align__(16) unsigned BH[4 * 128 * 4];
    __shared__ __align__(16) unsigned BL[4 * 128 * 4];
    const int t = threadIdx.x, lane = t & 63, wv = t >> 6, wm = wv >> 1, wn = wv & 1;
    const int j0 = nt * 128;
    const int spx = t & 127, sg = t >> 7;
    f32x4 acc[2][4] = {};
#pragma unroll 1
    for (int kb = 0; kb < NLM_KB1; ++kb) {
        unsigned v[8];
#pragma unroll
        for (int jj = 0; jj < 8; ++jj) v[jj] = 0u;
        const int j = j0 + spx;
        if (j < NLM_N) {
            const unsigned* s = xTp + ((size_t)img * NLM_N + j) * NLM_C + kb * 32 + sg * 8;
#pragma unroll
            for (int jj = 0; jj < 8; ++jj) v[jj] = s[jj];
        }
        uint4v hd, ld;
#pragma unroll
        for (int jj = 0; jj < 4; ++jj) {
            hd[jj] = (v[2 * jj] & 0xFFFFu) | (v[2 * jj + 1] << 16);
            ld[jj] = (v[2 * jj] >> 16) | (v[2 * jj + 1] & 0xFFFF0000u);
        }
        *(uint4v*)&BH[(sg * 128 + spx) * 4] = hd;
        *(uint4v*)&BL[(sg * 128 + spx) * 4] = ld;
        __syncthreads();
        const size_t ab = (size_t)img * NLM_PFRAG
                        + (size_t)(kb * NLM_RT + mt * 8 + wm * 2) * 512 + (size_t)lane * 8;
        short8 ah0 = *(const short8*)(Phi + ab);
        short8 ah1 = *(const short8*)(Phi + ab + 512);
        short8 al0 = *(const short8*)(Plo + ab);
        short8 al1 = *(const short8*)(Plo + ab + 512);
        const int g = lane >> 4, pl = lane & 15;
#pragma unroll
        for (int fn = 0; fn < 4; ++fn) {
            const int px = wn * 64 + fn * 16 + pl;
            short8 bh = *(const short8*)&BH[(g * 128 + px) * 4];
            short8 bl = *(const short8*)&BL[(g * 128 + px) * 4];
            acc[0][fn] = mfma16(ah0, bh, acc[0][fn]);
            acc[1][fn] = mfma16(ah1, bh, acc[1][fn]);
            acc[0][fn] = mfma16(al0, bh, acc[0][fn]);
            acc[1][fn] = mfma16(al1, bh, acc[1][fn]);
            acc[0][fn] = mfma16(ah0, bl, acc[0][fn]);
            acc[1][fn] = mfma16(ah1, bl, acc[1][fn]);
        }
        __syncthreads();
    }
#pragma unroll
    for (int fm = 0; fm < 2; ++fm)
#pragma unroll
    for (int fn = 0; fn < 4; ++fn) {
        const int row = mt * 128 + (wm * 2 + fm) * 16 + (lane >> 4) * 4;
        const int j = j0 + wn * 64 + fn * 16 + (lane & 15);
        if (j >= NLM_N) continue;
        f32x4 a = acc[fm][fn];
#pragma unroll
        for (int r = 0; r < 4; ++r)
            S[((size_t)img * NLM_MAXM + row + r) * NLM_N + j] = a[r];
    }
}

__global__ __launch_bounds__(256) void nlm_row(
    const float* __restrict__ S, const float* __restrict__ sq,
    const float* __restrict__ nm2, const int* __restrict__ list,
    const int* __restrict__ cnt,
    short* __restrict__ W2hi, short* __restrict__ W2lo,
    float* __restrict__ sumw, float inv_h2) {
    const int img = blockIdx.y, i = blockIdx.x;
    if (i >= cnt[img] || i >= NLM_MAXM) return;
    __shared__ float Drow[NLM_N];
    __shared__ float red[256];
    const int tid = threadIdx.x;
    const int pix = list[img * NLM_MAXM + i];
    const float sqi = sq[img * NLM_N + pix];
    const float BIG = 3.4e38f;
    float lmin = BIG;
    for (int j = tid; j < NLM_N; j += 256) {
        float d = BIG;
        if (nm2[(size_t)img * NLM_N + j] != 0.f) {
            float dot = S[((size_t)img * NLM_MAXM + i) * NLM_N + j];
            d = sqi + sq[img * NLM_N + j] - 2.f * dot;
            d = d > 0.f ? d : 0.f;
            lmin = d < lmin ? d : lmin;
        }
        Drow[j] = d;
    }
    red[tid] = lmin;
    __syncthreads();
    for (int o = 128; o > 0; o >>= 1) {
        if (tid < o) red[tid] = fminf(red[tid], red[tid + o]);
        __syncthreads();
    }
    const float dmin = red[0];
    __syncthreads();

    const int rt = i >> 4, lr = i & 15;
    float lsum = 0.f;
    for (int j = tid; j < NLM_KB2 * 32; j += 256) {
        float w = 0.f;
        if (j < NLM_N && Drow[j] < 3.3e38f) {
            w = expf(-(Drow[j] - dmin) * inv_h2);
            lsum += w;
        }
        const unsigned u = splitpack(w);
        const int kb = j >> 5, kg = (j & 31) >> 3, jj = j & 7;
        const int lane = kg * 16 + lr;
        const size_t f = (size_t)img * NLM_WFRAG
                       + ((size_t)(kb * NLM_RT + rt) * 64 + lane) * 8 + jj;
        W2hi[f] = (short)(u & 0xFFFFu);
        W2lo[f] = (short)(u >> 16);
    }
    red[tid] = lsum;
    __syncthreads();
    for (int o = 128; o > 0; o >>= 1) {
        if (tid < o) red[tid] += red[tid + o];
        __syncthreads();
    }
    if (tid == 0) sumw[img * NLM_MAXM + i] = red[0];
}

__global__ __launch_bounds__(512) void nlm_gemm2(
    const unsigned* __restrict__ xTp, const short* __restrict__ W2hi,
    const short* __restrict__ W2lo, const int* __restrict__ cnt,
    const float* __restrict__ sumw, const int* __restrict__ list,
    short* __restrict__ outHi, short* __restrict__ outLo) {
    const int img = blockIdx.z, mt = blockIdx.y, ct = blockIdx.x;
    const int cN = cnt[img] < NLM_MAXM ? cnt[img] : NLM_MAXM;
    if (mt * 128 >= cN) return;
    __shared__ __align__(16) unsigned BH[4 * 128 * 4];
    __shared__ __align__(16) unsigned BL[4 * 128 * 4];
    const int t = threadIdx.x, lane = t & 63, wv = t >> 6, wm = wv >> 1, wn = wv & 1;
    const int c0 = ct * 128;
    const int sc = t & 127, sg = t >> 7;
    f32x4 acc[2][4] = {};
#pragma unroll 1
    for (int kb = 0; kb < NLM_KB2; ++kb) {
        unsigned v[8];
#pragma unroll
        for (int jj = 0; jj < 8; ++jj) {
            const int j = kb * 32 + sg * 8 + jj;
            v[jj] = (j < NLM_N)
                  ? xTp[((size_t)img * NLM_N + j) * NLM_C + c0 + sc] : 0u;
        }
        uint4v hd, ld;
#pragma unroll
        for (int jj = 0; jj < 4; ++jj) {
            hd[jj] = (v[2 * jj] & 0xFFFFu) | (v[2 * jj + 1] << 16);
            ld[jj] = (v[2 * jj] >> 16) | (v[2 * jj + 1] & 0xFFFF0000u);
        }
        *(uint4v*)&BH[(sg * 128 + sc) * 4] = hd;
        *(uint4v*)&BL[(sg * 128 + sc) * 4] = ld;
        __syncthreads();
        const size_t ab = (size_t)img * NLM_WFRAG
                        + (size_t)(kb * NLM_RT + mt * 8 + wm * 2) * 512 + (size_t)lane * 8;
        short8 ah0 = *(const short8*)(W2hi + ab);
        short8 ah1 = *(const short8*)(W2hi + ab + 512);
        short8 al0 = *(const short8*)(W2lo + ab);
        short8 al1 = *(const short8*)(W2lo + ab + 512);
        const int g = lane >> 4, pl = lane & 15;
#pragma unroll
        for (int fn = 0; fn < 4; ++fn) {
            const int px = wn * 64 + fn * 16 + pl;
            short8 bh = *(const short8*)&BH[(g * 128 + px) * 4];
            short8 bl = *(const short8*)&BL[(g * 128 + px) * 4];
            acc[0][fn] = mfma16(ah0, bh, acc[0][fn]);
            acc[1][fn] = mfma16(ah1, bh, acc[1][fn]);
            acc[0][fn] = mfma16(al0, bh, acc[0][fn]);
            acc[1][fn] = mfma16(al1, bh, acc[1][fn]);
            acc[0][fn] = mfma16(ah0, bl, acc[0][fn]);
            acc[1][fn] = mfma16(ah1, bl, acc[1][fn]);
        }
        __syncthreads();
    }
#pragma unroll
    for (int fm = 0; fm < 2; ++fm)
#pragma unroll
    for (int fn = 0; fn < 4; ++fn) {
        const int row = mt * 128 + (wm * 2 + fm) * 16 + (lane >> 4) * 4;
        const int c = c0 + wn * 64 + fn * 16 + (lane & 15);
        f32x4 a = acc[fm][fn];
#pragma unroll
        for (int r = 0; r < 4; ++r) {
            const int ri = row + r;
            if (ri < cN) {
                const float y = a[r] / sumw[img * NLM_MAXM + ri];
                const int pix = list[img * NLM_MAXM + ri];
                const size_t pa = (((size_t)img * (NLM_C >> 5) + (c >> 5)) * NLM_N + pix) * 32
                                + (c & 31);
                unsigned h16 = f2bf_rne(y);
                float rr = y - bf2f(h16);
                outHi[pa] = (short)h16;
                outLo[pa] = (short)f2bf_rne(rr);
            }
        }
    }
}

// ---------------------------------------------------------------------------
// Driver
// ---------------------------------------------------------------------------
extern "C" void kernel_launch(void* const* d_in, const int* in_sizes, int n_in,
                              void* d_out, int out_size, void* d_ws, size_t ws_size,
                              hipStream_t stream) {
    const float* x0    = (const float*)d_in[0];
    const float* m0    = (const float*)d_in[1];
    const float* Wsrc[8] = {
        (const float*)d_in[2], (const float*)d_in[3], (const float*)d_in[4],
        (const float*)d_in[5], (const float*)d_in[6], (const float*)d_in[7],
        (const float*)d_in[8], (const float*)d_in[9]
    };
    const float* dec1b = (const float*)d_in[10];
    const float* enc2g = (const float*)d_in[11];
    const float* enc2b = (const float*)d_in[12];
    const float* enc3g = (const float*)d_in[13];
    const float* enc3b = (const float*)d_in[14];
    const float* enc4g = (const float*)d_in[15];
    const float* enc4b = (const float*)d_in[16];
    const float* dec4g = (const float*)d_in[17];
    const float* dec4b = (const float*)d_in[18];
    const float* dec3g = (const float*)d_in[19];
    const float* dec3b = (const float*)d_in[20];
    const float* dec2g = (const float*)d_in[21];
    const float* dec2b = (const float*)d_in[22];
    float* outp = (float*)d_out;

    const int N = 8;
    float* ws = (float*)d_ws;
    size_t off = 0;
    auto alloc = [&](size_t nf) {
        size_t o = off;
        off += ((nf + 63) / 64) * 64;
        return ws + o;
    };
    auto allocPair = [&](size_t E, short** hi, short** lo) {
        float* p = alloc(E);
        *hi = (short*)p;
        *lo = (short*)p + E;
    };

    short *h1hi, *h1lo, *h2shi, *h2slo, *h3hi, *h3lo, *h4hi, *h4lo, *d4hi, *d4lo;
    allocPair(10616832, &h1hi, &h1lo);   // 8x256x72x72  (later d2 planes)
    allocPair(5308416, &h2shi, &h2slo);  // 8x512x36x36  (later d3 planes)
    allocPair(1327104, &h3hi, &h3lo);    // 8x512x18x18
    allocPair(331776, &h4hi, &h4lo);     // 8x512x9x9
    allocPair(1327104, &d4hi, &d4lo);
    float* ybuf = alloc(10616832);
    float* h2f  = alloc(5308416);
    unsigned* xTp = (unsigned*)alloc(5308416);
    float* sqb  = alloc(10368);
    float* mc   = alloc(165888);
    float* nm1  = alloc(41472);
    float* nm2  = alloc(10368);
    float* nm3  = alloc(2592);
    float* nm4  = alloc(648);
    float* nmd4 = alloc(2592);
    float* nmd3 = alloc(10368);
    float* nmd2 = alloc(41472);
    float* nmx  = alloc(165888);
    float* bmean = alloc(512);
    float* bistd = alloc(512);
    short* Whi = (short*)alloc(10625024);
    short* Wlo = (short*)alloc(10625024);
    float* Smat = alloc((size_t)8 * NLM_MAXM * NLM_N);
    float* Phi_  = alloc((size_t)8 * NLM_PFRAG / 2);
    float* Plo_  = alloc((size_t)8 * NLM_PFRAG / 2);
    float* W2hi_ = alloc((size_t)8 * NLM_WFRAG / 2);
    float* W2lo_ = alloc((size_t)8 * NLM_WFRAG / 2);
    short* Phi = (short*)Phi_;  short* Plo = (short*)Plo_;
    short* W2hi = (short*)W2hi_; short* W2lo = (short*)W2lo_;
    int*   mlist = (int*)alloc(8 * NLM_MAXM);
    int*   mcnt  = (int*)alloc(64);
    float* sumw  = alloc(8 * NLM_MAXM);
    short* d3hi = h2shi; short* d3lo = h2slo;
    short* d2hi = h1hi;  short* d2lo = h1lo;

    if (ws_size < off * sizeof(float)) return;

    auto cdiv = [](size_t a, size_t b) { return (int)((a + b - 1) / b); };

    // ---- weight transforms ----
    struct WLay { int Cout, Cin, K; size_t ofs; };
    const WLay WL[8] = {
        {256, 128, 7, 0},         // enc1
        {512, 256, 5, 1605632},   // enc2
        {512, 512, 3, 4882432},   // enc3
        {512, 512, 3, 7241728},   // enc4
        {512, 1024, 3, 9601024},  // dec4
        {512, 1024, 3, 14319616}, // dec3
        {256, 768, 3, 19038208},  // dec2
        {128, 384, 3, 20807680},  // dec1
    };
    for (int i = 0; i < 8; ++i) {
        size_t tot = (size_t)WL[i].Cout * WL[i].Cin * WL[i].K * WL[i].K;
        wtransform<<<cdiv(tot, 256), 256, 0, stream>>>(
            Wsrc[i], Whi + WL[i].ofs, Wlo + WL[i].ofs, WL[i].Cout, WL[i].Cin,
            WL[i].K * WL[i].K, tot);
    }

    // ---- x0 planes live in d_out (free scratch until dec1 overwrites it) ----
    short* x0hi = (short*)d_out;
    short* x0lo = x0hi + 21233664;
    split_planes<<<dim3(324, 4, N), 256, 0, stream>>>(x0, x0hi, x0lo, 128, 20736);

    // ---------------- enc1: x0 planes -> h1 planes, relu ----------------
    maskconv_kernel<7, 2, false><<<cdiv(N * 72 * 72, 256), 256, 0, stream>>>(
        m0, 144, 144, mc, nm1, N, 144, 144, 72, 72);
    conv_enc<7, 2, 8, 8, 2, false, EPI_PAIR_RELU><<<dim3(81, 1, N), 512, 0, stream>>>(
        x0hi, x0lo, 128, 144, 144, m0,
        Whi + WL[0].ofs, Wlo + WL[0].ofs, mc, nullptr, h1hi, h1lo,
        72, 72, 256, 9);

    // ---------------- enc2 ----------------
    maskconv_kernel<5, 2, false><<<cdiv(N * 36 * 36, 256), 256, 0, stream>>>(
        nm1, 72, 72, mc, nm2, N, 72, 72, 36, 36);
    conv_enc<5, 2, 8, 8, 2, false, EPI_F32><<<dim3(25, 2, N), 512, 0, stream>>>(
        h1hi, h1lo, 256, 72, 72, nm1,
        Whi + WL[1].ofs, Wlo + WL[1].ofs, mc, nullptr, ybuf, nullptr,
        36, 36, 512, 5);
    bn_stats_kernel<<<512, 256, 0, stream>>>(ybuf, N, 512, 1296, bmean, bistd);
    bn_apply_blk<<<dim3(cdiv(1296, 64), 16, N), 256, 0, stream>>>(
        ybuf, bmean, bistd, enc2g, enc2b, h2shi, h2slo, h2f, 512, 1296, ACT_RELU);

    // ---------------- NLM swap ----------------
    nlm_trans<<<dim3(41, 16, N), 256, 0, stream>>>(h2f, xTp);
    nlm_sq2<<<dim3(6, N), 256, 0, stream>>>(h2f, sqb);
    hipMemsetAsync(mcnt, 0, 8 * sizeof(int), stream);
    nlm_compact<<<N, 256, 0, stream>>>(nm2, mlist, mcnt);
    nlm_gather<<<dim3(64, N), 256, 0, stream>>>(xTp, mlist, mcnt, Phi, Plo);
    nlm_gemm1<<<dim3(11, 2, N), 512, 0, stream>>>(xTp, Phi, Plo, mcnt, Smat);
    nlm_row<<<dim3(NLM_MAXM, N), 256, 0, stream>>>(Smat, sqb, nm2, mlist, mcnt,
                                                   W2hi, W2lo, sumw, 1.f / 25.f);
    nlm_gemm2<<<dim3(4, 2, N), 512, 0, stream>>>(xTp, W2hi, W2lo, mcnt, sumw,
                                                 mlist, h2shi, h2slo);

    // ---------------- enc3 ----------------
    maskconv_kernel<3, 2, false><<<cdiv(N * 18 * 18, 256), 256, 0, stream>>>(
        nm2, 36, 36, mc, nm3, N, 36, 36, 18, 18);
    conv_enc<3, 2, 4, 8, 1, false, EPI_F32><<<dim3(15, 2, N), 512, 0, stream>>>(
        h2shi, h2slo, 512, 36, 36, nm2,
        Whi + WL[2].ofs, Wlo + WL[2].ofs, mc, nullptr, ybuf, nullptr,
        18, 18, 512, 3);
    bn_stats_kernel<<<512, 256, 0, stream>>>(ybuf, N, 512, 324, bmean, bistd);
    bn_apply_blk<<<dim3(cdiv(324, 64), 16, N), 256, 0, stream>>>(
        ybuf, bmean, bistd, enc3g, enc3b, h3hi, h3lo, nullptr, 512, 324, ACT_RELU);

    // ---------------- enc4 ----------------
    maskconv_kernel<3, 2, false><<<cdiv(N * 9 * 9, 256), 256, 0, stream>>>(
        nm3, 18, 18, mc, nm4, N, 18, 18, 9, 9);
    conv_enc<3, 2, 4, 8, 1, false, EPI_F32><<<dim3(6, 2, N), 512, 0, stream>>>(
        h3hi, h3lo, 512, 18, 18, nm3,
        Whi + WL[3].ofs, Wlo + WL[3].ofs, mc, nullptr, ybuf, nullptr,
        9, 9, 512, 2);
    bn_stats_kernel<<<512, 256, 0, stream>>>(ybuf, N, 512, 81, bmean, bistd);
    bn_apply_blk<<<dim3(cdiv(81, 64), 16, N), 256, 0, stream>>>(
        ybuf, bmean, bistd, enc4g, enc4b, h4hi, h4lo, nullptr, 512, 81, ACT_RELU);

    // ---------------- dec4 ----------------
    maskconv_kernel<3, 1, true><<<cdiv(N * 18 * 18, 256), 256, 0, stream>>>(
        nm4, 9, 9, mc, nmd4, N, 18, 18, 18, 18);
    conv3x3<8, 8, 2, false, EPI_F32><<<dim3(9, 4, N), 512, 0, stream>>>(
        h4hi, h4lo, 512, 9, 9, h3hi, h3lo, 512, nm4,
        Whi + WL[4].ofs, Wlo + WL[4].ofs, mc, nullptr, ybuf,
        18, 18, 512, 3);
    bn_stats_kernel<<<512, 256, 0, stream>>>(ybuf, N, 512, 324, bmean, bistd);
    bn_apply_blk<<<dim3(cdiv(324, 64), 16, N), 256, 0, stream>>>(
        ybuf, bmean, bistd, dec4g, dec4b, d4hi, d4lo, nullptr, 512, 324, ACT_LEAKY);

    // ---------------- dec3 ----------------
    maskconv_kernel<3, 1, true><<<cdiv(N * 36 * 36, 256), 256, 0, stream>>>(
        nmd4, 18, 18, mc, nmd3, N, 36, 36, 36, 36);
    conv3x3<8, 12, 3, false, EPI_F32><<<dim3(15, 4, N), 512, 0, stream>>>(
        d4hi, d4lo, 512, 18, 18, h2shi, h2slo, 512, nmd4,
        Whi + WL[5].ofs, Wlo + WL[5].ofs, mc, nullptr, ybuf,
        36, 36, 512, 3);
    bn_stats_kernel<<<512, 256, 0, stream>>>(ybuf, N, 512, 1296, bmean, bistd);
    bn_apply_blk<<<dim3(cdiv(1296, 64), 16, N), 256, 0, stream>>>(
        ybuf, bmean, bistd, dec3g, dec3b, d3hi, d3lo, nullptr, 512, 1296, ACT_LEAKY);

    // ---------------- dec2 ----------------
    maskconv_kernel<3, 1, true><<<cdiv(N * 72 * 72, 256), 256, 0, stream>>>(
        nmd3, 36, 36, mc, nmd2, N, 72, 72, 72, 72);
    conv3x3<8, 16, 4, false, EPI_F32><<<dim3(45, 2, N), 512, 0, stream>>>(
        d3hi, d3lo, 512, 36, 36, h1hi, h1lo, 256, nmd3,
        Whi + WL[6].ofs, Wlo + WL[6].ofs, mc, nullptr, ybuf,
        72, 72, 256, 5);
    bn_stats_kernel<<<256, 256, 0, stream>>>(ybuf, N, 256, 5184, bmean, bistd);
    bn_apply_blk<<<dim3(cdiv(5184, 64), 8, N), 256, 0, stream>>>(
        ybuf, bmean, bistd, dec2g, dec2b, d2hi, d2lo, nullptr, 256, 5184, ACT_LEAKY);

    // ---------------- dec1: cat[up2(d2), x0] -> d_out (x0 planes now dead) ----------------
    maskconv_kernel<3, 1, true><<<cdiv(N * 144 * 144, 256), 256, 0, stream>>>(
        nmd2, 72, 72, mc, nmx, N, 144, 144, 144, 144);
    conv3x3<8, 16, 4, true, EPI_F32_BIAS><<<dim3(162, 1, N), 512, 0, stream>>>(
        d2hi, d2lo, 256, 72, 72, x0, nullptr, 128, nmd2,
        Whi + WL[7].ofs, Wlo + WL[7].ofs, mc, dec1b, outp,
        144, 144, 128, 9);
}